// Round 1
// baseline (1622.817 us; speedup 1.0000x reference)
//
#include <hip/hip_runtime.h>
#include <math.h>

#define H 768
#define SEQ 2048
#define NSP 4096
#define HIDD 150
#define TOPK 128

// d_out layout (floats): [0,512) mention_scores | [512,66048) ant | [66048,66560) f_starts | [66560,67072) f_ends
#define OFS_ANT 512
#define OFS_FS 66048
#define OFS_FE 66560

// workspace layout (float offsets)
static const size_t OFF_SR  = 0ull;          // 16384*768
static const size_t OFF_A   = 12582912ull;   // 768*768
static const size_t OFF_C   = 13172736ull;   // 768*768
static const size_t OFF_T   = 13762560ull;   // 11*768
static const size_t OFF_SC  = 13771008ull;   // 16384
static const size_t OFF_IDX = 13787392ull;   // 512 ints
static const size_t OFF_RK  = 13787904ull;   // 512*768
static const size_t OFF_U   = 14181120ull;   // 512*150
static const size_t OFF_V   = 14257920ull;   // 512*150

// T[w][j] = b_out[j] + b_start@Wo1 + b_end@Wo2 + width_emb[w]@Wo3
__global__ void k_prep(const float* __restrict__ b_start, const float* __restrict__ b_end,
                       const float* __restrict__ b_out, const float* __restrict__ width_emb,
                       const float* __restrict__ W_out, float* __restrict__ T) {
    int j = blockIdx.x * 256 + threadIdx.x;
    if (j >= H) return;
    float p0 = 0.f, p1 = 0.f, p2 = 0.f, p3 = 0.f;
#pragma unroll 8
    for (int k = 0; k < H; k += 2) {
        p0 += b_start[k]     * W_out[(size_t)k * H + j];
        p1 += b_start[k + 1] * W_out[(size_t)(k + 1) * H + j];
        p2 += b_end[k]       * W_out[(size_t)(H + k) * H + j];
        p3 += b_end[k + 1]   * W_out[(size_t)(H + k + 1) * H + j];
    }
    float bias = b_out[j] + p0 + p1 + p2 + p3;
    for (int w = 0; w <= 10; ++w) {
        float acc = bias;
#pragma unroll
        for (int k = 0; k < 30; ++k)
            acc += width_emb[w * 30 + k] * W_out[(size_t)(2 * H + k) * H + j];
        T[w * H + j] = acc;
    }
}

// Ac = W_start @ W_out[0:768], Cc = W_end @ W_out[768:1536]. 64x64 tiles.
__global__ __launch_bounds__(256) void k_combine(const float* __restrict__ W_start,
    const float* __restrict__ W_end, const float* __restrict__ W_out,
    float* __restrict__ Ac, float* __restrict__ Cc) {
    __shared__ float sA[16][68];
    __shared__ float sB[16][68];
    const int z = blockIdx.z;
    const float* Wsrc = z ? W_end : W_start;
    const float* Wo = W_out + (z ? (size_t)H * H : 0);
    float* dst = z ? Cc : Ac;
    const int tid = threadIdx.x;
    const int m0 = blockIdx.y * 64, n0 = blockIdx.x * 64;
    const int tr = tid >> 4, tc = tid & 15;
    const int rr = tid >> 2, kg = (tid & 3) * 4;
    const int kb = tid >> 4, jc = (tid & 15) * 4;
    float acc[4][4];
#pragma unroll
    for (int i = 0; i < 4; ++i)
#pragma unroll
        for (int j = 0; j < 4; ++j) acc[i][j] = 0.f;
    for (int k0 = 0; k0 < H; k0 += 16) {
        float4 va = *(const float4*)(Wsrc + (size_t)(m0 + rr) * H + k0 + kg);
        float4 vb = *(const float4*)(Wo + (size_t)(k0 + kb) * H + n0 + jc);
        sA[kg + 0][rr] = va.x; sA[kg + 1][rr] = va.y;
        sA[kg + 2][rr] = va.z; sA[kg + 3][rr] = va.w;
        *(float4*)&sB[kb][jc] = vb;
        __syncthreads();
#pragma unroll
        for (int kk = 0; kk < 16; ++kk) {
            float a[4], b[4];
            *(float4*)a = *(const float4*)&sA[kk][tr * 4];
            *(float4*)b = *(const float4*)&sB[kk][tc * 4];
#pragma unroll
            for (int i = 0; i < 4; ++i)
#pragma unroll
                for (int j = 0; j < 4; ++j) acc[i][j] += a[i] * b[j];
        }
        __syncthreads();
    }
#pragma unroll
    for (int i = 0; i < 4; ++i) {
        float4 o = make_float4(acc[i][0], acc[i][1], acc[i][2], acc[i][3]);
        *(float4*)(dst + (size_t)(m0 + tr * 4 + i) * H + n0 + tc * 4) = o;
    }
}

// SR[r][j] = st_r@Ac + en_r@Cc + T[width_r]. 128x128 tiles, 8x8 micro, fused gather.
__global__ __launch_bounds__(256) void k_spanrepr(const float* __restrict__ seq,
    const int* __restrict__ starts, const int* __restrict__ ends,
    const float* __restrict__ Ac, const float* __restrict__ Cc,
    const float* __restrict__ T, float* __restrict__ SR) {
    __shared__ float sA[16][132];
    __shared__ float sB[16][132];
    __shared__ int sRow[2][128];
    __shared__ int sWid[128];
    const int tid = threadIdx.x;
    const int r0 = blockIdx.y * 128, n0 = blockIdx.x * 128;
    if (tid < 128) {
        int s = starts[r0 + tid], e = ends[r0 + tid];
        sRow[0][tid] = s;
        sRow[1][tid] = e;
        int w = e - s;
        sWid[tid] = w < 0 ? 0 : (w > 10 ? 10 : w);
    }
    __syncthreads();
    const int bb = r0 >> 12;
    const int tr = tid >> 4, tc = tid & 15;
    const int rr = tid >> 1, kh = (tid & 1) * 8;
    const int kb = tid >> 4, jc = (tid & 15) * 8;
    float acc[8][8];
#pragma unroll
    for (int i = 0; i < 8; ++i)
#pragma unroll
        for (int j = 0; j < 8; ++j) acc[i][j] = 0.f;
    for (int ph = 0; ph < 2; ++ph) {
        const float* W = ph ? Cc : Ac;
        const int* rowp = sRow[ph];
        for (int k0 = 0; k0 < H; k0 += 16) {
            const float* asrc = seq + (size_t)(bb * SEQ + rowp[rr]) * H + k0 + kh;
            float4 a0 = *(const float4*)asrc;
            float4 a1 = *(const float4*)(asrc + 4);
            const float* bsrc = W + (size_t)(k0 + kb) * H + n0 + jc;
            float4 b0 = *(const float4*)bsrc;
            float4 b1v = *(const float4*)(bsrc + 4);
            sA[kh + 0][rr] = a0.x; sA[kh + 1][rr] = a0.y;
            sA[kh + 2][rr] = a0.z; sA[kh + 3][rr] = a0.w;
            sA[kh + 4][rr] = a1.x; sA[kh + 5][rr] = a1.y;
            sA[kh + 6][rr] = a1.z; sA[kh + 7][rr] = a1.w;
            *(float4*)&sB[kb][jc] = b0;
            *(float4*)&sB[kb][jc + 4] = b1v;
            __syncthreads();
#pragma unroll
            for (int kk = 0; kk < 16; ++kk) {
                float a[8], b[8];
                *(float4*)a       = *(const float4*)&sA[kk][tr * 8];
                *(float4*)(a + 4) = *(const float4*)&sA[kk][tr * 8 + 4];
                *(float4*)b       = *(const float4*)&sB[kk][tc * 8];
                *(float4*)(b + 4) = *(const float4*)&sB[kk][tc * 8 + 4];
#pragma unroll
                for (int i = 0; i < 8; ++i)
#pragma unroll
                    for (int j = 0; j < 8; ++j) acc[i][j] += a[i] * b[j];
            }
            __syncthreads();
        }
    }
#pragma unroll
    for (int i = 0; i < 8; ++i) {
        const int r = r0 + tr * 8 + i;
        const float* Tr = T + (size_t)sWid[tr * 8 + i] * H + n0 + tc * 8;
        float4 t0 = *(const float4*)Tr;
        float4 t1 = *(const float4*)(Tr + 4);
        float4 o0 = make_float4(acc[i][0] + t0.x, acc[i][1] + t0.y,
                                acc[i][2] + t0.z, acc[i][3] + t0.w);
        float4 o1 = make_float4(acc[i][4] + t1.x, acc[i][5] + t1.y,
                                acc[i][6] + t1.z, acc[i][7] + t1.w);
        float* dsty = SR + (size_t)r * H + n0 + tc * 8;
        *(float4*)dsty = o0;
        *(float4*)(dsty + 4) = o1;
    }
}

// scores[r] = SR[r]·w_ment + b_ment ; one wave per row
__global__ void k_scores(const float* __restrict__ SR, const float* __restrict__ w_ment,
                         const float* __restrict__ b_ment, float* __restrict__ SC) {
    const int wid = threadIdx.x >> 6, lane = threadIdx.x & 63;
    const int r = blockIdx.x * 4 + wid;
    const float* row = SR + (size_t)r * H;
    float s = 0.f;
#pragma unroll
    for (int q = 0; q < 12; ++q) s += row[lane + 64 * q] * w_ment[lane + 64 * q];
#pragma unroll
    for (int off = 32; off; off >>= 1) s += __shfl_down(s, off, 64);
    if (lane == 0) SC[r] = s + b_ment[0];
}

// iterative top-128 per batch; key = (score desc, idx asc) packed in u64
__global__ void k_topk(const float* __restrict__ SC, const int* __restrict__ starts,
                       const int* __restrict__ ends, float* __restrict__ out,
                       int* __restrict__ idxbuf) {
    const int b = blockIdx.x, tid = threadIdx.x;
    const int lane = tid & 63, wid = tid >> 6;
    float sc[16];
    int id[16];
#pragma unroll
    for (int q = 0; q < 16; ++q) {
        int i = q * 256 + tid;
        sc[q] = SC[b * NSP + i];
        id[q] = i;
    }
    __shared__ unsigned long long red[4];
    for (int it = 0; it < TOPK; ++it) {
        unsigned long long best = 0ull;
#pragma unroll
        for (int q = 0; q < 16; ++q) {
            unsigned u = __float_as_uint(sc[q]);
            u = (u & 0x80000000u) ? ~u : (u | 0x80000000u);
            unsigned long long key =
                ((unsigned long long)u << 32) | (unsigned)(0xFFFFFFFFu - (unsigned)id[q]);
            best = key > best ? key : best;
        }
#pragma unroll
        for (int off = 32; off; off >>= 1) {
            unsigned long long o = __shfl_down(best, off, 64);
            best = o > best ? o : best;
        }
        if (lane == 0) red[wid] = best;
        __syncthreads();
        if (tid == 0) {
            unsigned long long m = red[0];
            for (int w = 1; w < 4; ++w) m = red[w] > m ? red[w] : m;
            red[0] = m;
        }
        __syncthreads();
        const unsigned long long win = red[0];
        const int widx = (int)(0xFFFFFFFFu - (unsigned)(win & 0xFFFFFFFFu));
        if (tid == 0) {
            unsigned hu = (unsigned)(win >> 32);
            float sval = __uint_as_float((hu & 0x80000000u) ? (hu & 0x7FFFFFFFu) : ~hu);
            out[b * TOPK + it] = sval;
            idxbuf[b * TOPK + it] = widx;
            out[OFS_FS + b * TOPK + it] = (float)starts[b * NSP + widx];
            out[OFS_FE + b * TOPK + it] = (float)ends[b * NSP + widx];
        }
        if ((widx & 255) == tid) sc[widx >> 8] = -INFINITY;
        __syncthreads();
    }
}

__global__ void k_gather(const float* __restrict__ SR, const int* __restrict__ idxbuf,
                         float* __restrict__ RK) {
    const int p = blockIdx.x;
    const int b = p >> 7;
    const int g = idxbuf[p];
    const float* src = SR + (size_t)(b * NSP + g) * H;
    float* dst = RK + (size_t)p * H;
    for (int k = threadIdx.x; k < H; k += 256) dst[k] = src[k];
}

// u = r@(Wa+Wc), v = r@(Wb-Wc)
__global__ void k_uv(const float* __restrict__ RK, const float* __restrict__ W1,
                     float* __restrict__ U, float* __restrict__ V) {
    __shared__ float r[H];
    const int p = blockIdx.x, tid = threadIdx.x;
    for (int k = tid; k < H; k += 192) r[k] = RK[(size_t)p * H + k];
    __syncthreads();
    if (tid < HIDD) {
        float u = 0.f, v = 0.f;
        for (int h = 0; h < H; ++h) {
            float rv = r[h];
            float wa = W1[(size_t)h * HIDD + tid];
            float wb = W1[(size_t)(H + h) * HIDD + tid];
            float wc = W1[(size_t)(2 * H + h) * HIDD + tid];
            u += rv * (wa + wc);
            v += rv * (wb - wc);
        }
        U[(size_t)p * HIDD + tid] = u;
        V[(size_t)p * HIDD + tid] = v;
    }
}

// per (b, i, j-tile of 32): pw + u + v + b1 -> relu -> LN(150) -> ·W2 -> tril store
__global__ __launch_bounds__(256) void k_pair(const float* __restrict__ RK,
    const float* __restrict__ W1, const float* __restrict__ U, const float* __restrict__ V,
    const float* __restrict__ b1, const float* __restrict__ ln_g,
    const float* __restrict__ ln_b, const float* __restrict__ W2,
    const float* __restrict__ b2, float* __restrict__ ant) {
    const int b = blockIdx.z, ii = blockIdx.y, j0 = blockIdx.x * 32;
    float* arow = ant + ((size_t)b * TOPK + ii) * TOPK;
    if (j0 >= ii) {  // whole tile is in the zeroed (upper) triangle
        if (threadIdx.x < 32) arow[j0 + threadIdx.x] = 0.f;
        return;
    }
    __shared__ float sW[HIDD][68];   // Wd chunk transposed: [d][h]
    __shared__ float sRj[32][68];
    __shared__ float sRi[H];
    const int tid = threadIdx.x;
    const int dt = tid & 31, jt = tid >> 5;
    int drow[5];
#pragma unroll
    for (int m = 0; m < 5; ++m) {
        int d = dt + 32 * m;
        drow[m] = d < HIDD ? d : (HIDD - 1);  // clamp: m=4 lanes dt>=22 are dead
    }
    for (int k = tid; k < H; k += 256) sRi[k] = RK[((size_t)b * TOPK + ii) * H + k];
    float acc[4][5];
#pragma unroll
    for (int n = 0; n < 4; ++n)
#pragma unroll
        for (int m = 0; m < 5; ++m) acc[n][m] = 0.f;
    for (int k0 = 0; k0 < H; k0 += 64) {
        for (int e = tid; e < 64 * HIDD; e += 256) {
            int hh = e / HIDD, d = e - hh * HIDD;
            sW[d][hh] = W1[(size_t)(3 * H + k0 + hh) * HIDD + d];
        }
        for (int e = tid; e < 32 * 64; e += 256) {
            int j = e >> 6, hh = e & 63;
            sRj[j][hh] = RK[((size_t)b * TOPK + j0 + j) * H + k0 + hh];
        }
        __syncthreads();
#pragma unroll
        for (int hg = 0; hg < 16; ++hg) {
            float4 ri = *(const float4*)&sRi[k0 + hg * 4];
            float4 pr[4];
#pragma unroll
            for (int n = 0; n < 4; ++n) {
                float4 rj = *(const float4*)&sRj[jt + 8 * n][hg * 4];
                pr[n].x = ri.x * rj.x; pr[n].y = ri.y * rj.y;
                pr[n].z = ri.z * rj.z; pr[n].w = ri.w * rj.w;
            }
#pragma unroll
            for (int m = 0; m < 5; ++m) {
                float4 w = *(const float4*)&sW[drow[m]][hg * 4];
#pragma unroll
                for (int n = 0; n < 4; ++n)
                    acc[n][m] += pr[n].x * w.x + pr[n].y * w.y + pr[n].z * w.z + pr[n].w * w.w;
            }
        }
        __syncthreads();
    }
    // epilogue: z = pw + u_i + v_j + b1; relu; LN over d; dot W2; tril mask
    const int ib = b * TOPK + ii;
    float uu[5], g5[5], be5[5], w25[5], bb5[5];
#pragma unroll
    for (int m = 0; m < 5; ++m) {
        int d = dt + 32 * m;
        if (d < HIDD) {
            uu[m] = U[(size_t)ib * HIDD + d];
            g5[m] = ln_g[d]; be5[m] = ln_b[d]; w25[m] = W2[d]; bb5[m] = b1[d];
        } else { uu[m] = 0.f; g5[m] = 0.f; be5[m] = 0.f; w25[m] = 0.f; bb5[m] = 0.f; }
    }
    const float b2v = b2[0];
#pragma unroll
    for (int n = 0; n < 4; ++n) {
        const int j = j0 + jt + 8 * n;
        float hv[5];
        float s1 = 0.f, s2 = 0.f;
#pragma unroll
        for (int m = 0; m < 5; ++m) {
            int d = dt + 32 * m;
            if (d < HIDD) {
                float z = acc[n][m] + uu[m] + V[(size_t)(b * TOPK + j) * HIDD + d] + bb5[m];
                float h = z > 0.f ? z : 0.f;
                hv[m] = h;
                s1 += h;
                s2 += h * h;
            } else hv[m] = 0.f;
        }
#pragma unroll
        for (int off = 16; off; off >>= 1) {
            s1 += __shfl_xor(s1, off, 32);
            s2 += __shfl_xor(s2, off, 32);
        }
        const float mu = s1 * (1.f / HIDD);
        const float var = s2 * (1.f / HIDD) - mu * mu;
        const float rstd = rsqrtf(var + 1e-5f);
        float part = 0.f;
#pragma unroll
        for (int m = 0; m < 5; ++m) {
            int d = dt + 32 * m;
            if (d < HIDD) part += ((hv[m] - mu) * rstd * g5[m] + be5[m]) * w25[m];
        }
#pragma unroll
        for (int off = 16; off; off >>= 1) part += __shfl_xor(part, off, 32);
        if (dt == 0) arow[j] = (j < ii) ? (part + b2v) : 0.f;
    }
}

extern "C" void kernel_launch(void* const* d_in, const int* in_sizes, int n_in,
                              void* d_out, int out_size, void* d_ws, size_t ws_size,
                              hipStream_t stream) {
    const float* seq      = (const float*)d_in[0];
    const int*   starts   = (const int*)d_in[1];
    const int*   ends     = (const int*)d_in[2];
    const float* W_start  = (const float*)d_in[3];
    const float* b_start  = (const float*)d_in[4];
    const float* W_end    = (const float*)d_in[5];
    const float* b_end    = (const float*)d_in[6];
    const float* width_e  = (const float*)d_in[7];
    const float* W_out    = (const float*)d_in[8];
    const float* b_out    = (const float*)d_in[9];
    const float* w_ment   = (const float*)d_in[10];
    const float* b_ment   = (const float*)d_in[11];
    const float* W1       = (const float*)d_in[12];
    const float* b1       = (const float*)d_in[13];
    const float* ln_g     = (const float*)d_in[14];
    const float* ln_b     = (const float*)d_in[15];
    const float* W2       = (const float*)d_in[16];
    const float* b2       = (const float*)d_in[17];
    float* out = (float*)d_out;
    float* ws  = (float*)d_ws;

    float* SR = ws + OFF_SR;
    float* Ac = ws + OFF_A;
    float* Cc = ws + OFF_C;
    float* Tt = ws + OFF_T;
    float* SC = ws + OFF_SC;
    int*   idxb = (int*)(ws + OFF_IDX);
    float* RKp = ws + OFF_RK;
    float* Up  = ws + OFF_U;
    float* Vp  = ws + OFF_V;

    k_prep<<<3, 256, 0, stream>>>(b_start, b_end, b_out, width_e, W_out, Tt);
    k_combine<<<dim3(12, 12, 2), 256, 0, stream>>>(W_start, W_end, W_out, Ac, Cc);
    k_spanrepr<<<dim3(6, 128), 256, 0, stream>>>(seq, starts, ends, Ac, Cc, Tt, SR);
    k_scores<<<4096, 256, 0, stream>>>(SR, w_ment, b_ment, SC);
    k_topk<<<4, 256, 0, stream>>>(SC, starts, ends, out, idxb);
    k_gather<<<512, 256, 0, stream>>>(SR, idxb, RKp);
    k_uv<<<512, 192, 0, stream>>>(RKp, W1, Up, Vp);
    k_pair<<<dim3(4, 128, 4), 256, 0, stream>>>(RKp, W1, Up, Vp, b1, ln_g, ln_b, W2, b2,
                                                out + OFS_ANT);
}

// Round 2
// 886.080 us; speedup vs baseline: 1.8315x; 1.8315x over previous
//
#include <hip/hip_runtime.h>
#include <math.h>

#define H 768
#define SEQ 2048
#define NSP 4096
#define HIDD 150
#define TOPK 128
#define NPAD 160

// d_out layout (floats): [0,512) mention_scores | [512,66048) ant | [66048,66560) f_starts | [66560,67072) f_ends
#define OFS_ANT 512
#define OFS_FS 66048
#define OFS_FE 66560

// workspace layout (float offsets)
static const size_t OFF_SR  = 0ull;          // 16384*768
static const size_t OFF_A   = 12582912ull;   // 768*768 (dead after k_spanrepr; reused below)
static const size_t OFF_C   = 13172736ull;   // 768*768
static const size_t OFF_T   = 13762560ull;   // 11*768
static const size_t OFF_SC  = 13771008ull;   // 16384
static const size_t OFF_IDX = 13787392ull;   // 512 ints
static const size_t OFF_RK  = 13787904ull;   // 512*768 f32
static const size_t OFF_U   = 14181120ull;   // 512*160 f32 (u + b1, padded)
static const size_t OFF_V   = 14263040ull;   // 512*160 f32 (v, padded)
static const size_t OFF_GW  = 14344960ull;   // 160 f32 (ln_g*W2, padded)
static const size_t OFF_SCAL= 14345120ull;   // 8 f32: [0]=S_gw, [1]=C0
// aliases into dead Ac region (written only AFTER k_spanrepr):
static const size_t OFF_WF  = OFF_A;                 // 10*24*64*8 bf16 = 61440 f32 slots
static const size_t OFF_RJF = OFF_A + 61440ull;      // 512*768 bf16 = 196608 f32 slots

typedef __attribute__((ext_vector_type(8))) short bf16x8;
typedef __attribute__((ext_vector_type(4))) float f32x4;

__device__ __forceinline__ unsigned short f2bf_rne(float f) {
    unsigned u = __float_as_uint(f);
    unsigned r = u + 0x7fffu + ((u >> 16) & 1u);
    return (unsigned short)(r >> 16);
}

// T[w][j] = b_out[j] + b_start@Wo1 + b_end@Wo2 + width_emb[w]@Wo3
__global__ void k_prep(const float* __restrict__ b_start, const float* __restrict__ b_end,
                       const float* __restrict__ b_out, const float* __restrict__ width_emb,
                       const float* __restrict__ W_out, float* __restrict__ T) {
    int j = blockIdx.x * 256 + threadIdx.x;
    if (j >= H) return;
    float p0 = 0.f, p1 = 0.f, p2 = 0.f, p3 = 0.f;
#pragma unroll 8
    for (int k = 0; k < H; k += 2) {
        p0 += b_start[k]     * W_out[(size_t)k * H + j];
        p1 += b_start[k + 1] * W_out[(size_t)(k + 1) * H + j];
        p2 += b_end[k]       * W_out[(size_t)(H + k) * H + j];
        p3 += b_end[k + 1]   * W_out[(size_t)(H + k + 1) * H + j];
    }
    float bias = b_out[j] + p0 + p1 + p2 + p3;
    for (int w = 0; w <= 10; ++w) {
        float acc = bias;
#pragma unroll
        for (int k = 0; k < 30; ++k)
            acc += width_emb[w * 30 + k] * W_out[(size_t)(2 * H + k) * H + j];
        T[w * H + j] = acc;
    }
}

// Ac = W_start @ W_out[0:768], Cc = W_end @ W_out[768:1536]. 64x64 tiles.
__global__ __launch_bounds__(256) void k_combine(const float* __restrict__ W_start,
    const float* __restrict__ W_end, const float* __restrict__ W_out,
    float* __restrict__ Ac, float* __restrict__ Cc) {
    __shared__ float sA[16][68];
    __shared__ float sB[16][68];
    const int z = blockIdx.z;
    const float* Wsrc = z ? W_end : W_start;
    const float* Wo = W_out + (z ? (size_t)H * H : 0);
    float* dst = z ? Cc : Ac;
    const int tid = threadIdx.x;
    const int m0 = blockIdx.y * 64, n0 = blockIdx.x * 64;
    const int tr = tid >> 4, tc = tid & 15;
    const int rr = tid >> 2, kg = (tid & 3) * 4;
    const int kb = tid >> 4, jc = (tid & 15) * 4;
    float acc[4][4];
#pragma unroll
    for (int i = 0; i < 4; ++i)
#pragma unroll
        for (int j = 0; j < 4; ++j) acc[i][j] = 0.f;
    for (int k0 = 0; k0 < H; k0 += 16) {
        float4 va = *(const float4*)(Wsrc + (size_t)(m0 + rr) * H + k0 + kg);
        float4 vb = *(const float4*)(Wo + (size_t)(k0 + kb) * H + n0 + jc);
        sA[kg + 0][rr] = va.x; sA[kg + 1][rr] = va.y;
        sA[kg + 2][rr] = va.z; sA[kg + 3][rr] = va.w;
        *(float4*)&sB[kb][jc] = vb;
        __syncthreads();
#pragma unroll
        for (int kk = 0; kk < 16; ++kk) {
            float a[4], b[4];
            *(float4*)a = *(const float4*)&sA[kk][tr * 4];
            *(float4*)b = *(const float4*)&sB[kk][tc * 4];
#pragma unroll
            for (int i = 0; i < 4; ++i)
#pragma unroll
                for (int j = 0; j < 4; ++j) acc[i][j] += a[i] * b[j];
        }
        __syncthreads();
    }
#pragma unroll
    for (int i = 0; i < 4; ++i) {
        float4 o = make_float4(acc[i][0], acc[i][1], acc[i][2], acc[i][3]);
        *(float4*)(dst + (size_t)(m0 + tr * 4 + i) * H + n0 + tc * 4) = o;
    }
}

// SR[r][j] = st_r@Ac + en_r@Cc + T[width_r]. 128x128 tiles, 8x8 micro, fused gather.
__global__ __launch_bounds__(256) void k_spanrepr(const float* __restrict__ seq,
    const int* __restrict__ starts, const int* __restrict__ ends,
    const float* __restrict__ Ac, const float* __restrict__ Cc,
    const float* __restrict__ T, float* __restrict__ SR) {
    __shared__ float sA[16][132];
    __shared__ float sB[16][132];
    __shared__ int sRow[2][128];
    __shared__ int sWid[128];
    const int tid = threadIdx.x;
    const int r0 = blockIdx.y * 128, n0 = blockIdx.x * 128;
    if (tid < 128) {
        int s = starts[r0 + tid], e = ends[r0 + tid];
        sRow[0][tid] = s;
        sRow[1][tid] = e;
        int w = e - s;
        sWid[tid] = w < 0 ? 0 : (w > 10 ? 10 : w);
    }
    __syncthreads();
    const int bb = r0 >> 12;
    const int tr = tid >> 4, tc = tid & 15;
    const int rr = tid >> 1, kh = (tid & 1) * 8;
    const int kb = tid >> 4, jc = (tid & 15) * 8;
    float acc[8][8];
#pragma unroll
    for (int i = 0; i < 8; ++i)
#pragma unroll
        for (int j = 0; j < 8; ++j) acc[i][j] = 0.f;
    for (int ph = 0; ph < 2; ++ph) {
        const float* W = ph ? Cc : Ac;
        const int* rowp = sRow[ph];
        for (int k0 = 0; k0 < H; k0 += 16) {
            const float* asrc = seq + (size_t)(bb * SEQ + rowp[rr]) * H + k0 + kh;
            float4 a0 = *(const float4*)asrc;
            float4 a1 = *(const float4*)(asrc + 4);
            const float* bsrc = W + (size_t)(k0 + kb) * H + n0 + jc;
            float4 b0 = *(const float4*)bsrc;
            float4 b1v = *(const float4*)(bsrc + 4);
            sA[kh + 0][rr] = a0.x; sA[kh + 1][rr] = a0.y;
            sA[kh + 2][rr] = a0.z; sA[kh + 3][rr] = a0.w;
            sA[kh + 4][rr] = a1.x; sA[kh + 5][rr] = a1.y;
            sA[kh + 6][rr] = a1.z; sA[kh + 7][rr] = a1.w;
            *(float4*)&sB[kb][jc] = b0;
            *(float4*)&sB[kb][jc + 4] = b1v;
            __syncthreads();
#pragma unroll
            for (int kk = 0; kk < 16; ++kk) {
                float a[8], b[8];
                *(float4*)a       = *(const float4*)&sA[kk][tr * 8];
                *(float4*)(a + 4) = *(const float4*)&sA[kk][tr * 8 + 4];
                *(float4*)b       = *(const float4*)&sB[kk][tc * 8];
                *(float4*)(b + 4) = *(const float4*)&sB[kk][tc * 8 + 4];
#pragma unroll
                for (int i = 0; i < 8; ++i)
#pragma unroll
                    for (int j = 0; j < 8; ++j) acc[i][j] += a[i] * b[j];
            }
            __syncthreads();
        }
    }
#pragma unroll
    for (int i = 0; i < 8; ++i) {
        const int r = r0 + tr * 8 + i;
        const float* Tr = T + (size_t)sWid[tr * 8 + i] * H + n0 + tc * 8;
        float4 t0 = *(const float4*)Tr;
        float4 t1 = *(const float4*)(Tr + 4);
        float4 o0 = make_float4(acc[i][0] + t0.x, acc[i][1] + t0.y,
                                acc[i][2] + t0.z, acc[i][3] + t0.w);
        float4 o1 = make_float4(acc[i][4] + t1.x, acc[i][5] + t1.y,
                                acc[i][6] + t1.z, acc[i][7] + t1.w);
        float* dsty = SR + (size_t)r * H + n0 + tc * 8;
        *(float4*)dsty = o0;
        *(float4*)(dsty + 4) = o1;
    }
}

// Wfrag: Wd (=W1[3H:4H]) in bf16, B-fragment-major order for 16x16x32 MFMA.
// element: B[k][n], lane = (n&15) | ((k>>3 & 3)<<4), e = k&7
__global__ void k_prepw(const float* __restrict__ W1, unsigned short* __restrict__ WF) {
    const int idx = blockIdx.x * 256 + threadIdx.x;
    if (idx >= 10 * 24 * 64) return;
    const int nt = idx / 1536;
    const int rem = idx - nt * 1536;
    const int kt = rem >> 6, lane = rem & 63;
    const int n = nt * 16 + (lane & 15);
    const int kb = kt * 32 + (lane >> 4) * 8;
    unsigned short* dst = WF + (size_t)idx * 8;
#pragma unroll
    for (int e = 0; e < 8; ++e) {
        float v = (n < HIDD) ? W1[(size_t)(3 * H + kb + e) * HIDD + n] : 0.f;
        dst[e] = f2bf_rne(v);
    }
}

// gw[d]=ln_g*W2 (padded), S_gw = sum(ln_g*W2), C0 = sum(ln_b*W2)+b2
__global__ void k_prepg(const float* __restrict__ ln_g, const float* __restrict__ ln_b,
                        const float* __restrict__ W2, const float* __restrict__ b2,
                        float* __restrict__ GW, float* __restrict__ SCAL) {
    const int tid = threadIdx.x;
    if (tid < NPAD) GW[tid] = (tid < HIDD) ? ln_g[tid] * W2[tid] : 0.f;
    if (tid == 0) {
        float sg = 0.f, sb = 0.f;
        for (int d = 0; d < HIDD; ++d) { sg += ln_g[d] * W2[d]; sb += ln_b[d] * W2[d]; }
        SCAL[0] = sg;
        SCAL[1] = sb + b2[0];
    }
}

// scores[r] = SR[r]·w_ment + b_ment ; one wave per row
__global__ void k_scores(const float* __restrict__ SR, const float* __restrict__ w_ment,
                         const float* __restrict__ b_ment, float* __restrict__ SC) {
    const int wid = threadIdx.x >> 6, lane = threadIdx.x & 63;
    const int r = blockIdx.x * 4 + wid;
    const float* row = SR + (size_t)r * H;
    float s = 0.f;
#pragma unroll
    for (int q = 0; q < 12; ++q) s += row[lane + 64 * q] * w_ment[lane + 64 * q];
#pragma unroll
    for (int off = 32; off; off >>= 1) s += __shfl_down(s, off, 64);
    if (lane == 0) SC[r] = s + b_ment[0];
}

// iterative top-128 per batch; key = (score desc, idx asc) packed in u64
__global__ void k_topk(const float* __restrict__ SC, const int* __restrict__ starts,
                       const int* __restrict__ ends, float* __restrict__ out,
                       int* __restrict__ idxbuf) {
    const int b = blockIdx.x, tid = threadIdx.x;
    const int lane = tid & 63, wid = tid >> 6;
    float sc[16];
    int id[16];
#pragma unroll
    for (int q = 0; q < 16; ++q) {
        int i = q * 256 + tid;
        sc[q] = SC[b * NSP + i];
        id[q] = i;
    }
    __shared__ unsigned long long red[4];
    for (int it = 0; it < TOPK; ++it) {
        unsigned long long best = 0ull;
#pragma unroll
        for (int q = 0; q < 16; ++q) {
            unsigned u = __float_as_uint(sc[q]);
            u = (u & 0x80000000u) ? ~u : (u | 0x80000000u);
            unsigned long long key =
                ((unsigned long long)u << 32) | (unsigned)(0xFFFFFFFFu - (unsigned)id[q]);
            best = key > best ? key : best;
        }
#pragma unroll
        for (int off = 32; off; off >>= 1) {
            unsigned long long o = __shfl_down(best, off, 64);
            best = o > best ? o : best;
        }
        if (lane == 0) red[wid] = best;
        __syncthreads();
        if (tid == 0) {
            unsigned long long m = red[0];
            for (int w = 1; w < 4; ++w) m = red[w] > m ? red[w] : m;
            red[0] = m;
        }
        __syncthreads();
        const unsigned long long win = red[0];
        const int widx = (int)(0xFFFFFFFFu - (unsigned)(win & 0xFFFFFFFFu));
        if (tid == 0) {
            unsigned hu = (unsigned)(win >> 32);
            float sval = __uint_as_float((hu & 0x80000000u) ? (hu & 0x7FFFFFFFu) : ~hu);
            out[b * TOPK + it] = sval;
            idxbuf[b * TOPK + it] = widx;
            out[OFS_FS + b * TOPK + it] = (float)starts[b * NSP + widx];
            out[OFS_FE + b * TOPK + it] = (float)ends[b * NSP + widx];
        }
        if ((widx & 255) == tid) sc[widx >> 8] = -INFINITY;
        __syncthreads();
    }
}

// gather top-k rows: f32 copy + bf16 A-fragment-major copy (for k_pair MFMA)
// A-frag: row m = p&15, lane = m | ((k>>3 & 3)<<4), e = k&7, tile t = p>>4
__global__ void k_gather(const float* __restrict__ SR, const int* __restrict__ idxbuf,
                         float* __restrict__ RK, unsigned short* __restrict__ RJF) {
    const int p = blockIdx.x;
    const int b = p >> 7;
    const int g = idxbuf[p];
    const int tid = threadIdx.x;
    const float* src = SR + (size_t)(b * NSP + g) * H;
    float* dst = RK + (size_t)p * H;
    for (int k = tid; k < H; k += 128) dst[k] = src[k];
    if (tid < 96) {
        const int k0 = tid * 8;
        const int kt = k0 >> 5;
        const int sub = k0 & 31;
        const int lane = (p & 15) | ((sub >> 3) << 4);
        const int t = p >> 4;
        unsigned short* d2 = RJF + ((size_t)(t * 24 + kt) * 64 + lane) * 8;
#pragma unroll
        for (int e = 0; e < 8; ++e) d2[e] = f2bf_rne(src[k0 + e]);
    }
}

// U'[p][d] = r@(Wa+Wc) + b1, V'[p][d] = r@(Wb-Wc); stride 160, zero-padded
__global__ void k_uv(const float* __restrict__ RK, const float* __restrict__ W1,
                     const float* __restrict__ b1, float* __restrict__ U,
                     float* __restrict__ V) {
    __shared__ float r[H];
    const int p = blockIdx.x, tid = threadIdx.x;
    for (int k = tid; k < H; k += 192) r[k] = RK[(size_t)p * H + k];
    __syncthreads();
    if (tid < NPAD) {
        if (tid < HIDD) {
            float u = 0.f, v = 0.f;
            for (int h = 0; h < H; ++h) {
                float rv = r[h];
                float wa = W1[(size_t)h * HIDD + tid];
                float wb = W1[(size_t)(H + h) * HIDD + tid];
                float wc = W1[(size_t)(2 * H + h) * HIDD + tid];
                u += rv * (wa + wc);
                v += rv * (wb - wc);
            }
            U[(size_t)p * NPAD + tid] = u + b1[tid];
            V[(size_t)p * NPAD + tid] = v;
        } else {
            U[(size_t)p * NPAD + tid] = 0.f;
            V[(size_t)p * NPAD + tid] = 0.f;
        }
    }
}

// Pairwise MFMA: per (b, i, 32-j tile), 2 waves, each wave M=16 pairs x N=160 x K=768.
// A = Ri(f32) * Rj(bf16 frag-major) -> bf16; B = Wfrag (frag-major bf16).
// Epilogue in C-layout (col=lane&15, row=(lane>>4)*4+reg): relu, LN(150), dot gw, tril.
__global__ __launch_bounds__(128) void k_pair(
    const unsigned short* __restrict__ RJF, const unsigned short* __restrict__ WF,
    const float* __restrict__ RK, const float* __restrict__ U, const float* __restrict__ V,
    const float* __restrict__ GW, const float* __restrict__ SCAL,
    float* __restrict__ ant) {
    const int b = blockIdx.z, ii = blockIdx.y, j0 = blockIdx.x * 32;
    float* arow = ant + ((size_t)b * TOPK + ii) * TOPK;
    const int tid = threadIdx.x;
    if (j0 >= ii) {
        if (tid < 32) arow[j0 + tid] = 0.f;
        return;
    }
    const int wave = tid >> 6, lane = tid & 63;
    const int jbase = j0 + wave * 16;
    if (jbase >= ii) {
        if (lane < 16) arow[jbase + lane] = 0.f;
        return;
    }
    const int g = lane >> 4, c = lane & 15;
    const int t = b * 8 + (jbase >> 4);
    const unsigned short* Af = RJF + (size_t)t * 24 * 64 * 8;
    const float* Ri = RK + (size_t)(b * TOPK + ii) * H;

    f32x4 acc[10];
#pragma unroll
    for (int nt = 0; nt < 10; ++nt) acc[nt] = (f32x4){0.f, 0.f, 0.f, 0.f};

    for (int kt = 0; kt < 24; ++kt) {
        uint4 rj = *(const uint4*)(Af + ((size_t)(kt * 64 + lane)) * 8);
        const float* rip = Ri + kt * 32 + g * 8;
        float4 ri0 = *(const float4*)rip;
        float4 ri1 = *(const float4*)(rip + 4);
        float p0 = ri0.x * __uint_as_float(rj.x << 16);
        float p1 = ri0.y * __uint_as_float(rj.x & 0xffff0000u);
        float p2 = ri0.z * __uint_as_float(rj.y << 16);
        float p3 = ri0.w * __uint_as_float(rj.y & 0xffff0000u);
        float p4 = ri1.x * __uint_as_float(rj.z << 16);
        float p5 = ri1.y * __uint_as_float(rj.z & 0xffff0000u);
        float p6 = ri1.z * __uint_as_float(rj.w << 16);
        float p7 = ri1.w * __uint_as_float(rj.w & 0xffff0000u);
        bf16x8 a;
        a[0] = (short)f2bf_rne(p0); a[1] = (short)f2bf_rne(p1);
        a[2] = (short)f2bf_rne(p2); a[3] = (short)f2bf_rne(p3);
        a[4] = (short)f2bf_rne(p4); a[5] = (short)f2bf_rne(p5);
        a[6] = (short)f2bf_rne(p6); a[7] = (short)f2bf_rne(p7);
#pragma unroll
        for (int nt = 0; nt < 10; ++nt) {
            bf16x8 bv = *(const bf16x8*)(WF + ((size_t)((nt * 24 + kt) * 64 + lane)) * 8);
            acc[nt] = __builtin_amdgcn_mfma_f32_16x16x32_bf16(a, bv, acc[nt], 0, 0, 0);
        }
    }

    // epilogue
    const float* Up = U + (size_t)(b * TOPK + ii) * NPAD;
    float u10[10], gw10[10];
#pragma unroll
    for (int nt = 0; nt < 10; ++nt) {
        const int d = nt * 16 + c;
        u10[nt] = Up[d];
        gw10[nt] = GW[d];
    }
    const float Sgw = SCAL[0], C0 = SCAL[1];
#pragma unroll
    for (int r = 0; r < 4; ++r) {
        const int j = jbase + g * 4 + r;
        const float* Vp = V + (size_t)(b * TOPK + j) * NPAD;
        float s1 = 0.f, s2 = 0.f, s3 = 0.f;
#pragma unroll
        for (int nt = 0; nt < 10; ++nt) {
            const int d = nt * 16 + c;
            float z = acc[nt][r] + u10[nt] + Vp[d];
            float h = (d < HIDD && z > 0.f) ? z : 0.f;
            s1 += h;
            s2 += h * h;
            s3 += h * gw10[nt];
        }
#pragma unroll
        for (int off = 1; off < 16; off <<= 1) {
            s1 += __shfl_xor(s1, off, 64);
            s2 += __shfl_xor(s2, off, 64);
            s3 += __shfl_xor(s3, off, 64);
        }
        const float mu = s1 * (1.f / HIDD);
        const float var = s2 * (1.f / HIDD) - mu * mu;
        const float rstd = rsqrtf(var + 1e-5f);
        const float val = rstd * (s3 - mu * Sgw) + C0;
        if (c == 0) arow[j] = (j < ii) ? val : 0.f;
    }
}

extern "C" void kernel_launch(void* const* d_in, const int* in_sizes, int n_in,
                              void* d_out, int out_size, void* d_ws, size_t ws_size,
                              hipStream_t stream) {
    const float* seq      = (const float*)d_in[0];
    const int*   starts   = (const int*)d_in[1];
    const int*   ends     = (const int*)d_in[2];
    const float* W_start  = (const float*)d_in[3];
    const float* b_start  = (const float*)d_in[4];
    const float* W_end    = (const float*)d_in[5];
    const float* b_end    = (const float*)d_in[6];
    const float* width_e  = (const float*)d_in[7];
    const float* W_out    = (const float*)d_in[8];
    const float* b_out    = (const float*)d_in[9];
    const float* w_ment   = (const float*)d_in[10];
    const float* b_ment   = (const float*)d_in[11];
    const float* W1       = (const float*)d_in[12];
    const float* b1       = (const float*)d_in[13];
    const float* ln_g     = (const float*)d_in[14];
    const float* ln_b     = (const float*)d_in[15];
    const float* W2       = (const float*)d_in[16];
    const float* b2       = (const float*)d_in[17];
    float* out = (float*)d_out;
    float* ws  = (float*)d_ws;

    float* SR = ws + OFF_SR;
    float* Ac = ws + OFF_A;
    float* Cc = ws + OFF_C;
    float* Tt = ws + OFF_T;
    float* SC = ws + OFF_SC;
    int*   idxb = (int*)(ws + OFF_IDX);
    float* RKp = ws + OFF_RK;
    float* Up  = ws + OFF_U;
    float* Vp  = ws + OFF_V;
    float* GWp = ws + OFF_GW;
    float* SCALp = ws + OFF_SCAL;
    unsigned short* WFp  = (unsigned short*)(ws + OFF_WF);
    unsigned short* RJFp = (unsigned short*)(ws + OFF_RJF);

    k_prep<<<3, 256, 0, stream>>>(b_start, b_end, b_out, width_e, W_out, Tt);
    k_combine<<<dim3(12, 12, 2), 256, 0, stream>>>(W_start, W_end, W_out, Ac, Cc);
    k_spanrepr<<<dim3(6, 128), 256, 0, stream>>>(seq, starts, ends, Ac, Cc, Tt, SR);
    // WF/RJF alias the (now dead) Ac region — must launch after k_spanrepr
    k_prepw<<<60, 256, 0, stream>>>(W1, WFp);
    k_prepg<<<1, 256, 0, stream>>>(ln_g, ln_b, W2, b2, GWp, SCALp);
    k_scores<<<4096, 256, 0, stream>>>(SR, w_ment, b_ment, SC);
    k_topk<<<4, 256, 0, stream>>>(SC, starts, ends, out, idxb);
    k_gather<<<512, 128, 0, stream>>>(SR, idxb, RKp, RJFp);
    k_uv<<<512, 192, 0, stream>>>(RKp, W1, b1, Up, Vp);
    k_pair<<<dim3(4, 128, 4), 128, 0, stream>>>(RJFp, WFp, RKp, Up, Vp, GWp, SCALp,
                                                out + OFS_ANT);
}

// Round 3
// 525.695 us; speedup vs baseline: 3.0870x; 1.6855x over previous
//
#include <hip/hip_runtime.h>
#include <math.h>

#define H 768
#define SEQ 2048
#define NSP 4096
#define HIDD 150
#define TOPK 128
#define NPAD 160

// d_out layout (floats): [0,512) mention_scores | [512,66048) ant | [66048,66560) f_starts | [66560,67072) f_ends
#define OFS_ANT 512
#define OFS_FS 66048
#define OFS_FE 66560

// workspace layout (float offsets) — total ~2.03M floats (~8.1 MB)
static const size_t OFF_A   = 0ull;          // 768*768
static const size_t OFF_C   = 589824ull;     // 768*768
static const size_t OFF_T   = 1179648ull;    // 11*768
static const size_t OFF_AV  = 1188096ull;    // 768
static const size_t OFF_CV  = 1188864ull;    // 768
static const size_t OFF_TW  = 1189632ull;    // 16
static const size_t OFF_SC  = 1189648ull;    // 16384
static const size_t OFF_IDX = 1206032ull;    // 512 ints
static const size_t OFF_FS  = 1206544ull;    // 512 ints (absolute seq row)
static const size_t OFF_FE  = 1207056ull;    // 512 ints
static const size_t OFF_WID = 1207568ull;    // 512 ints
static const size_t OFF_RK  = 1208080ull;    // 512*768 f32 (repr_k)
static const size_t OFF_U   = 1601296ull;    // 512*160 f32 (u + b1, padded)
static const size_t OFF_V   = 1683216ull;    // 512*160 f32 (v, padded)
static const size_t OFF_GW  = 1765136ull;    // 160 f32 (ln_g*W2, padded)
static const size_t OFF_SCAL= 1765296ull;    // 8 f32: [0]=S_gw, [1]=C0
static const size_t OFF_WF  = 1765304ull;    // 10*24*64*8 bf16 = 61440 f32 slots
static const size_t OFF_RJF = 1826744ull;    // 512*768 bf16 = 196608 f32 slots

typedef __attribute__((ext_vector_type(8))) short bf16x8;
typedef __attribute__((ext_vector_type(4))) float f32x4;

__device__ __forceinline__ unsigned short f2bf_rne(float f) {
    unsigned u = __float_as_uint(f);
    unsigned r = u + 0x7fffu + ((u >> 16) & 1u);
    return (unsigned short)(r >> 16);
}

// T[w][j] = b_out[j] + b_start@Wo1 + b_end@Wo2 + width_emb[w]@Wo3
__global__ void k_prep(const float* __restrict__ b_start, const float* __restrict__ b_end,
                       const float* __restrict__ b_out, const float* __restrict__ width_emb,
                       const float* __restrict__ W_out, float* __restrict__ T) {
    int j = blockIdx.x * 256 + threadIdx.x;
    if (j >= H) return;
    float p0 = 0.f, p1 = 0.f, p2 = 0.f, p3 = 0.f;
#pragma unroll 8
    for (int k = 0; k < H; k += 2) {
        p0 += b_start[k]     * W_out[(size_t)k * H + j];
        p1 += b_start[k + 1] * W_out[(size_t)(k + 1) * H + j];
        p2 += b_end[k]       * W_out[(size_t)(H + k) * H + j];
        p3 += b_end[k + 1]   * W_out[(size_t)(H + k + 1) * H + j];
    }
    float bias = b_out[j] + p0 + p1 + p2 + p3;
    for (int w = 0; w <= 10; ++w) {
        float acc = bias;
#pragma unroll
        for (int k = 0; k < 30; ++k)
            acc += width_emb[w * 30 + k] * W_out[(size_t)(2 * H + k) * H + j];
        T[w * H + j] = acc;
    }
}

// Ac = W_start @ W_out[0:768], Cc = W_end @ W_out[768:1536]. 64x64 tiles.
__global__ __launch_bounds__(256) void k_combine(const float* __restrict__ W_start,
    const float* __restrict__ W_end, const float* __restrict__ W_out,
    float* __restrict__ Ac, float* __restrict__ Cc) {
    __shared__ float sA[16][68];
    __shared__ float sB[16][68];
    const int z = blockIdx.z;
    const float* Wsrc = z ? W_end : W_start;
    const float* Wo = W_out + (z ? (size_t)H * H : 0);
    float* dst = z ? Cc : Ac;
    const int tid = threadIdx.x;
    const int m0 = blockIdx.y * 64, n0 = blockIdx.x * 64;
    const int tr = tid >> 4, tc = tid & 15;
    const int rr = tid >> 2, kg = (tid & 3) * 4;
    const int kb = tid >> 4, jc = (tid & 15) * 4;
    float acc[4][4];
#pragma unroll
    for (int i = 0; i < 4; ++i)
#pragma unroll
        for (int j = 0; j < 4; ++j) acc[i][j] = 0.f;
    for (int k0 = 0; k0 < H; k0 += 16) {
        float4 va = *(const float4*)(Wsrc + (size_t)(m0 + rr) * H + k0 + kg);
        float4 vb = *(const float4*)(Wo + (size_t)(k0 + kb) * H + n0 + jc);
        sA[kg + 0][rr] = va.x; sA[kg + 1][rr] = va.y;
        sA[kg + 2][rr] = va.z; sA[kg + 3][rr] = va.w;
        *(float4*)&sB[kb][jc] = vb;
        __syncthreads();
#pragma unroll
        for (int kk = 0; kk < 16; ++kk) {
            float a[4], b[4];
            *(float4*)a = *(const float4*)&sA[kk][tr * 4];
            *(float4*)b = *(const float4*)&sB[kk][tc * 4];
#pragma unroll
            for (int i = 0; i < 4; ++i)
#pragma unroll
                for (int j = 0; j < 4; ++j) acc[i][j] += a[i] * b[j];
        }
        __syncthreads();
    }
#pragma unroll
    for (int i = 0; i < 4; ++i) {
        float4 o = make_float4(acc[i][0], acc[i][1], acc[i][2], acc[i][3]);
        *(float4*)(dst + (size_t)(m0 + tr * 4 + i) * H + n0 + tc * 4) = o;
    }
}

// av = Ac@w_ment, cv = Cc@w_ment (one wave per row); block 384: tw[w] = T[w]·w_ment + b_ment
__global__ void k_vecs(const float* __restrict__ Ac, const float* __restrict__ Cc,
                       const float* __restrict__ T, const float* __restrict__ w_ment,
                       const float* __restrict__ b_ment, float* __restrict__ av,
                       float* __restrict__ cv, float* __restrict__ tw) {
    const int wid = threadIdx.x >> 6, lane = threadIdx.x & 63;
    if (blockIdx.x < 384) {
        const int gr = blockIdx.x * 4 + wid;  // 0..1535
        const float* row = (gr < H) ? (Ac + (size_t)gr * H) : (Cc + (size_t)(gr - H) * H);
        float s = 0.f;
#pragma unroll
        for (int q = 0; q < 12; ++q) s += row[lane + 64 * q] * w_ment[lane + 64 * q];
#pragma unroll
        for (int off = 32; off; off >>= 1) s += __shfl_down(s, off, 64);
        if (lane == 0) {
            if (gr < H) av[gr] = s; else cv[gr - H] = s;
        }
    } else {
        for (int w = wid; w <= 10; w += 4) {
            float s = 0.f;
#pragma unroll
            for (int q = 0; q < 12; ++q) s += T[w * H + lane + 64 * q] * w_ment[lane + 64 * q];
#pragma unroll
            for (int off = 32; off; off >>= 1) s += __shfl_down(s, off, 64);
            if (lane == 0) tw[w] = s + b_ment[0];
        }
    }
}

// score_r = st_r·av + en_r·cv + tw[width_r]; one wave per row, gathered seq reads
__global__ void k_scores2(const float* __restrict__ seq, const int* __restrict__ starts,
                          const int* __restrict__ ends, const float* __restrict__ av,
                          const float* __restrict__ cv, const float* __restrict__ tw,
                          float* __restrict__ SC) {
    const int wid = threadIdx.x >> 6, lane = threadIdx.x & 63;
    const int r = blockIdx.x * 4 + wid;
    const int b = r >> 12;
    const int s = starts[r], e = ends[r];
    int w = e - s; w = w < 0 ? 0 : (w > 10 ? 10 : w);
    const float4* st = (const float4*)(seq + (size_t)(b * SEQ + s) * H);
    const float4* en = (const float4*)(seq + (size_t)(b * SEQ + e) * H);
    const float4* a4 = (const float4*)av;
    const float4* c4 = (const float4*)cv;
    float acc = 0.f;
#pragma unroll
    for (int q = 0; q < 3; ++q) {
        float4 x = st[lane + 64 * q], y = a4[lane + 64 * q];
        acc += x.x * y.x + x.y * y.y + x.z * y.z + x.w * y.w;
        float4 x2 = en[lane + 64 * q], y2 = c4[lane + 64 * q];
        acc += x2.x * y2.x + x2.y * y2.y + x2.z * y2.z + x2.w * y2.w;
    }
#pragma unroll
    for (int off = 32; off; off >>= 1) acc += __shfl_down(acc, off, 64);
    if (lane == 0) SC[r] = acc + tw[w];
}

// iterative top-128 per batch; key = (score desc, idx asc) packed in u64
__global__ void k_topk(const float* __restrict__ SC, const int* __restrict__ starts,
                       const int* __restrict__ ends, float* __restrict__ out,
                       int* __restrict__ idxbuf) {
    const int b = blockIdx.x, tid = threadIdx.x;
    const int lane = tid & 63, wid = tid >> 6;
    float sc[16];
    int id[16];
#pragma unroll
    for (int q = 0; q < 16; ++q) {
        int i = q * 256 + tid;
        sc[q] = SC[b * NSP + i];
        id[q] = i;
    }
    __shared__ unsigned long long red[4];
    for (int it = 0; it < TOPK; ++it) {
        unsigned long long best = 0ull;
#pragma unroll
        for (int q = 0; q < 16; ++q) {
            unsigned u = __float_as_uint(sc[q]);
            u = (u & 0x80000000u) ? ~u : (u | 0x80000000u);
            unsigned long long key =
                ((unsigned long long)u << 32) | (unsigned)(0xFFFFFFFFu - (unsigned)id[q]);
            best = key > best ? key : best;
        }
#pragma unroll
        for (int off = 32; off; off >>= 1) {
            unsigned long long o = __shfl_down(best, off, 64);
            best = o > best ? o : best;
        }
        if (lane == 0) red[wid] = best;
        __syncthreads();
        if (tid == 0) {
            unsigned long long m = red[0];
            for (int w = 1; w < 4; ++w) m = red[w] > m ? red[w] : m;
            red[0] = m;
        }
        __syncthreads();
        const unsigned long long win = red[0];
        const int widx = (int)(0xFFFFFFFFu - (unsigned)(win & 0xFFFFFFFFu));
        if (tid == 0) {
            unsigned hu = (unsigned)(win >> 32);
            float sval = __uint_as_float((hu & 0x80000000u) ? (hu & 0x7FFFFFFFu) : ~hu);
            out[b * TOPK + it] = sval;
            idxbuf[b * TOPK + it] = widx;
            out[OFS_FS + b * TOPK + it] = (float)starts[b * NSP + widx];
            out[OFS_FE + b * TOPK + it] = (float)ends[b * NSP + widx];
        }
        if ((widx & 255) == tid) sc[widx >> 8] = -INFINITY;
        __syncthreads();
    }
}

// per winner: absolute seq rows + clipped width
__global__ void k_gather2(const int* __restrict__ idxb, const int* __restrict__ starts,
                          const int* __restrict__ ends, int* __restrict__ fsI,
                          int* __restrict__ feI, int* __restrict__ widI) {
    const int p = blockIdx.x * 256 + threadIdx.x;
    if (p >= 512) return;
    const int b = p >> 7, g = idxb[p];
    const int s = starts[b * NSP + g], e = ends[b * NSP + g];
    fsI[p] = b * SEQ + s;
    feI[p] = b * SEQ + e;
    int w = e - s;
    widI[p] = w < 0 ? 0 : (w > 10 ? 10 : w);
}

// RK[p] = seq[fs_p]@Ac + seq[fe_p]@Cc + T[wid_p]  (512x768, K=1536), 64x64 tiles
__global__ __launch_bounds__(256) void k_sr512(const float* __restrict__ seq,
    const int* __restrict__ fsI, const int* __restrict__ feI, const int* __restrict__ widI,
    const float* __restrict__ Ac, const float* __restrict__ Cc,
    const float* __restrict__ T, float* __restrict__ RK) {
    __shared__ float sA[16][68];
    __shared__ float sB[16][68];
    __shared__ int sRow[2][64];
    __shared__ int sWid[64];
    const int tid = threadIdx.x;
    const int m0 = blockIdx.y * 64, n0 = blockIdx.x * 64;
    if (tid < 64) {
        sRow[0][tid] = fsI[m0 + tid];
        sRow[1][tid] = feI[m0 + tid];
        sWid[tid] = widI[m0 + tid];
    }
    __syncthreads();
    const int tr = tid >> 4, tc = tid & 15;
    const int rr = tid >> 2, kg = (tid & 3) * 4;
    const int kb = tid >> 4, jc = (tid & 15) * 4;
    float acc[4][4];
#pragma unroll
    for (int i = 0; i < 4; ++i)
#pragma unroll
        for (int j = 0; j < 4; ++j) acc[i][j] = 0.f;
    for (int ph = 0; ph < 2; ++ph) {
        const float* W = ph ? Cc : Ac;
        const int* rowp = sRow[ph];
        for (int k0 = 0; k0 < H; k0 += 16) {
            float4 va = *(const float4*)(seq + (size_t)rowp[rr] * H + k0 + kg);
            float4 vb = *(const float4*)(W + (size_t)(k0 + kb) * H + n0 + jc);
            sA[kg + 0][rr] = va.x; sA[kg + 1][rr] = va.y;
            sA[kg + 2][rr] = va.z; sA[kg + 3][rr] = va.w;
            *(float4*)&sB[kb][jc] = vb;
            __syncthreads();
#pragma unroll
            for (int kk = 0; kk < 16; ++kk) {
                float a[4], b[4];
                *(float4*)a = *(const float4*)&sA[kk][tr * 4];
                *(float4*)b = *(const float4*)&sB[kk][tc * 4];
#pragma unroll
                for (int i = 0; i < 4; ++i)
#pragma unroll
                    for (int j = 0; j < 4; ++j) acc[i][j] += a[i] * b[j];
            }
            __syncthreads();
        }
    }
#pragma unroll
    for (int i = 0; i < 4; ++i) {
        const int rm = m0 + tr * 4 + i;
        float4 t = *(const float4*)(T + (size_t)sWid[tr * 4 + i] * H + n0 + tc * 4);
        float4 o = make_float4(acc[i][0] + t.x, acc[i][1] + t.y,
                               acc[i][2] + t.z, acc[i][3] + t.w);
        *(float4*)(RK + (size_t)rm * H + n0 + tc * 4) = o;
    }
}

// bf16 A-fragment-major copy of RK for k_pair MFMA
// A-frag: row m = p&15, lane = m | ((k>>3 & 3)<<4), e = k&7, tile t = p>>4
__global__ void k_frag(const float* __restrict__ RK, unsigned short* __restrict__ RJF) {
    const int p = blockIdx.x;
    const int tid = threadIdx.x;
    if (tid >= 96) return;
    const float* src = RK + (size_t)p * H;
    const int k0 = tid * 8;
    const int kt = k0 >> 5, sub = k0 & 31;
    const int lane = (p & 15) | ((sub >> 3) << 4);
    const int t = p >> 4;
    unsigned short* d2 = RJF + ((size_t)(t * 24 + kt) * 64 + lane) * 8;
#pragma unroll
    for (int e = 0; e < 8; ++e) d2[e] = f2bf_rne(src[k0 + e]);
}

// Wfrag: Wd (=W1[3H:4H]) in bf16, B-fragment-major order for 16x16x32 MFMA.
__global__ void k_prepw(const float* __restrict__ W1, unsigned short* __restrict__ WF) {
    const int idx = blockIdx.x * 256 + threadIdx.x;
    if (idx >= 10 * 24 * 64) return;
    const int nt = idx / 1536;
    const int rem = idx - nt * 1536;
    const int kt = rem >> 6, lane = rem & 63;
    const int n = nt * 16 + (lane & 15);
    const int kb = kt * 32 + (lane >> 4) * 8;
    unsigned short* dst = WF + (size_t)idx * 8;
#pragma unroll
    for (int e = 0; e < 8; ++e) {
        float v = (n < HIDD) ? W1[(size_t)(3 * H + kb + e) * HIDD + n] : 0.f;
        dst[e] = f2bf_rne(v);
    }
}

// gw[d]=ln_g*W2 (padded), S_gw = sum(ln_g*W2), C0 = sum(ln_b*W2)+b2
__global__ void k_prepg(const float* __restrict__ ln_g, const float* __restrict__ ln_b,
                        const float* __restrict__ W2, const float* __restrict__ b2,
                        float* __restrict__ GW, float* __restrict__ SCAL) {
    const int tid = threadIdx.x;
    if (tid < NPAD) GW[tid] = (tid < HIDD) ? ln_g[tid] * W2[tid] : 0.f;
    if (tid == 0) {
        float sg = 0.f, sb = 0.f;
        for (int d = 0; d < HIDD; ++d) { sg += ln_g[d] * W2[d]; sb += ln_b[d] * W2[d]; }
        SCAL[0] = sg;
        SCAL[1] = sb + b2[0];
    }
}

// U'[p][d] = r@(Wa+Wc) + b1, V'[p][d] = r@(Wb-Wc); stride 160, zero-padded
__global__ void k_uv(const float* __restrict__ RK, const float* __restrict__ W1,
                     const float* __restrict__ b1, float* __restrict__ U,
                     float* __restrict__ V) {
    __shared__ float r[H];
    const int p = blockIdx.x, tid = threadIdx.x;
    for (int k = tid; k < H; k += 192) r[k] = RK[(size_t)p * H + k];
    __syncthreads();
    if (tid < NPAD) {
        if (tid < HIDD) {
            float u = 0.f, v = 0.f;
            for (int h = 0; h < H; ++h) {
                float rv = r[h];
                float wa = W1[(size_t)h * HIDD + tid];
                float wb = W1[(size_t)(H + h) * HIDD + tid];
                float wc = W1[(size_t)(2 * H + h) * HIDD + tid];
                u += rv * (wa + wc);
                v += rv * (wb - wc);
            }
            U[(size_t)p * NPAD + tid] = u + b1[tid];
            V[(size_t)p * NPAD + tid] = v;
        } else {
            U[(size_t)p * NPAD + tid] = 0.f;
            V[(size_t)p * NPAD + tid] = 0.f;
        }
    }
}

// Pairwise MFMA: per (b, i, 32-j tile), 2 waves, each wave M=16 pairs x N=160 x K=768.
__global__ __launch_bounds__(128) void k_pair(
    const unsigned short* __restrict__ RJF, const unsigned short* __restrict__ WF,
    const float* __restrict__ RK, const float* __restrict__ U, const float* __restrict__ V,
    const float* __restrict__ GW, const float* __restrict__ SCAL,
    float* __restrict__ ant) {
    const int b = blockIdx.z, ii = blockIdx.y, j0 = blockIdx.x * 32;
    float* arow = ant + ((size_t)b * TOPK + ii) * TOPK;
    const int tid = threadIdx.x;
    if (j0 >= ii) {
        if (tid < 32) arow[j0 + tid] = 0.f;
        return;
    }
    const int wave = tid >> 6, lane = tid & 63;
    const int jbase = j0 + wave * 16;
    if (jbase >= ii) {
        if (lane < 16) arow[jbase + lane] = 0.f;
        return;
    }
    const int g = lane >> 4, c = lane & 15;
    const int t = b * 8 + (jbase >> 4);
    const unsigned short* Af = RJF + (size_t)t * 24 * 64 * 8;
    const float* Ri = RK + (size_t)(b * TOPK + ii) * H;

    f32x4 acc[10];
#pragma unroll
    for (int nt = 0; nt < 10; ++nt) acc[nt] = (f32x4){0.f, 0.f, 0.f, 0.f};

    for (int kt = 0; kt < 24; ++kt) {
        uint4 rj = *(const uint4*)(Af + ((size_t)(kt * 64 + lane)) * 8);
        const float* rip = Ri + kt * 32 + g * 8;
        float4 ri0 = *(const float4*)rip;
        float4 ri1 = *(const float4*)(rip + 4);
        float p0 = ri0.x * __uint_as_float(rj.x << 16);
        float p1 = ri0.y * __uint_as_float(rj.x & 0xffff0000u);
        float p2 = ri0.z * __uint_as_float(rj.y << 16);
        float p3 = ri0.w * __uint_as_float(rj.y & 0xffff0000u);
        float p4 = ri1.x * __uint_as_float(rj.z << 16);
        float p5 = ri1.y * __uint_as_float(rj.z & 0xffff0000u);
        float p6 = ri1.z * __uint_as_float(rj.w << 16);
        float p7 = ri1.w * __uint_as_float(rj.w & 0xffff0000u);
        bf16x8 a;
        a[0] = (short)f2bf_rne(p0); a[1] = (short)f2bf_rne(p1);
        a[2] = (short)f2bf_rne(p2); a[3] = (short)f2bf_rne(p3);
        a[4] = (short)f2bf_rne(p4); a[5] = (short)f2bf_rne(p5);
        a[6] = (short)f2bf_rne(p6); a[7] = (short)f2bf_rne(p7);
#pragma unroll
        for (int nt = 0; nt < 10; ++nt) {
            bf16x8 bv = *(const bf16x8*)(WF + ((size_t)((nt * 24 + kt) * 64 + lane)) * 8);
            acc[nt] = __builtin_amdgcn_mfma_f32_16x16x32_bf16(a, bv, acc[nt], 0, 0, 0);
        }
    }

    const float* Up = U + (size_t)(b * TOPK + ii) * NPAD;
    float u10[10], gw10[10];
#pragma unroll
    for (int nt = 0; nt < 10; ++nt) {
        const int d = nt * 16 + c;
        u10[nt] = Up[d];
        gw10[nt] = GW[d];
    }
    const float Sgw = SCAL[0], C0 = SCAL[1];
#pragma unroll
    for (int r = 0; r < 4; ++r) {
        const int j = jbase + g * 4 + r;
        const float* Vp = V + (size_t)(b * TOPK + j) * NPAD;
        float s1 = 0.f, s2 = 0.f, s3 = 0.f;
#pragma unroll
        for (int nt = 0; nt < 10; ++nt) {
            const int d = nt * 16 + c;
            float z = acc[nt][r] + u10[nt] + Vp[d];
            float h = (d < HIDD && z > 0.f) ? z : 0.f;
            s1 += h;
            s2 += h * h;
            s3 += h * gw10[nt];
        }
#pragma unroll
        for (int off = 1; off < 16; off <<= 1) {
            s1 += __shfl_xor(s1, off, 64);
            s2 += __shfl_xor(s2, off, 64);
            s3 += __shfl_xor(s3, off, 64);
        }
        const float mu = s1 * (1.f / HIDD);
        const float var = s2 * (1.f / HIDD) - mu * mu;
        const float rstd = rsqrtf(var + 1e-5f);
        const float val = rstd * (s3 - mu * Sgw) + C0;
        if (c == 0) arow[j] = (j < ii) ? val : 0.f;
    }
}

extern "C" void kernel_launch(void* const* d_in, const int* in_sizes, int n_in,
                              void* d_out, int out_size, void* d_ws, size_t ws_size,
                              hipStream_t stream) {
    const float* seq      = (const float*)d_in[0];
    const int*   starts   = (const int*)d_in[1];
    const int*   ends     = (const int*)d_in[2];
    const float* W_start  = (const float*)d_in[3];
    const float* b_start  = (const float*)d_in[4];
    const float* W_end    = (const float*)d_in[5];
    const float* b_end    = (const float*)d_in[6];
    const float* width_e  = (const float*)d_in[7];
    const float* W_out    = (const float*)d_in[8];
    const float* b_out    = (const float*)d_in[9];
    const float* w_ment   = (const float*)d_in[10];
    const float* b_ment   = (const float*)d_in[11];
    const float* W1       = (const float*)d_in[12];
    const float* b1       = (const float*)d_in[13];
    const float* ln_g     = (const float*)d_in[14];
    const float* ln_b     = (const float*)d_in[15];
    const float* W2       = (const float*)d_in[16];
    const float* b2       = (const float*)d_in[17];
    float* out = (float*)d_out;
    float* ws  = (float*)d_ws;

    float* Ac = ws + OFF_A;
    float* Cc = ws + OFF_C;
    float* Tt = ws + OFF_T;
    float* av = ws + OFF_AV;
    float* cv = ws + OFF_CV;
    float* tw = ws + OFF_TW;
    float* SC = ws + OFF_SC;
    int*   idxb = (int*)(ws + OFF_IDX);
    int*   fsI  = (int*)(ws + OFF_FS);
    int*   feI  = (int*)(ws + OFF_FE);
    int*   widI = (int*)(ws + OFF_WID);
    float* RKp = ws + OFF_RK;
    float* Up  = ws + OFF_U;
    float* Vp  = ws + OFF_V;
    float* GWp = ws + OFF_GW;
    float* SCALp = ws + OFF_SCAL;
    unsigned short* WFp  = (unsigned short*)(ws + OFF_WF);
    unsigned short* RJFp = (unsigned short*)(ws + OFF_RJF);

    k_prep<<<3, 256, 0, stream>>>(b_start, b_end, b_out, width_e, W_out, Tt);
    k_combine<<<dim3(12, 12, 2), 256, 0, stream>>>(W_start, W_end, W_out, Ac, Cc);
    k_prepw<<<60, 256, 0, stream>>>(W1, WFp);
    k_prepg<<<1, 256, 0, stream>>>(ln_g, ln_b, W2, b2, GWp, SCALp);
    k_vecs<<<385, 256, 0, stream>>>(Ac, Cc, Tt, w_ment, b_ment, av, cv, tw);
    k_scores2<<<4096, 256, 0, stream>>>(seq, starts, ends, av, cv, tw, SC);
    k_topk<<<4, 256, 0, stream>>>(SC, starts, ends, out, idxb);
    k_gather2<<<2, 256, 0, stream>>>(idxb, starts, ends, fsI, feI, widI);
    k_sr512<<<dim3(12, 8), 256, 0, stream>>>(seq, fsI, feI, widI, Ac, Cc, Tt, RKp);
    k_frag<<<512, 128, 0, stream>>>(RKp, RJFp);
    k_uv<<<512, 192, 0, stream>>>(RKp, W1, b1, Up, Vp);
    k_pair<<<dim3(4, 128, 4), 128, 0, stream>>>(RJFp, WFp, RKp, Up, Vp, GWp, SCALp,
                                                out + OFS_ANT);
}

// Round 4
// 410.149 us; speedup vs baseline: 3.9567x; 1.2817x over previous
//
#include <hip/hip_runtime.h>
#include <math.h>

#define H 768
#define SEQ 2048
#define NSP 4096
#define HIDD 150
#define TOPK 128
#define NPAD 160

// d_out layout (floats): [0,512) mention_scores | [512,66048) ant | [66048,66560) f_starts | [66560,67072) f_ends
#define OFS_ANT 512
#define OFS_FS 66048
#define OFS_FE 66560

// workspace layout (float offsets)
static const size_t OFF_A   = 0ull;          // 768*768
static const size_t OFF_C   = 589824ull;     // 768*768
static const size_t OFF_T   = 1179648ull;    // 11*768
static const size_t OFF_AV  = 1188096ull;    // 768
static const size_t OFF_CV  = 1188864ull;    // 768
static const size_t OFF_TW  = 1189632ull;    // 16
static const size_t OFF_SC  = 1189648ull;    // 16384
static const size_t OFF_IDX = 1206032ull;    // 512 ints
static const size_t OFF_FS  = 1206544ull;    // 512 ints (absolute seq row)
static const size_t OFF_FE  = 1207056ull;    // 512 ints
static const size_t OFF_WID = 1207568ull;    // 512 ints
static const size_t OFF_RK  = 1208080ull;    // 512*768 f32 (repr_k)
static const size_t OFF_U   = 1601296ull;    // 512*160 f32 (u + b1, padded)
static const size_t OFF_V   = 1683216ull;    // 512*160 f32 (v, padded)
static const size_t OFF_GW  = 1765136ull;    // 160 f32 (ln_g*W2, padded)
static const size_t OFF_SCAL= 1765296ull;    // 8 f32: [0]=S_gw, [1]=C0
static const size_t OFF_WF  = 1765304ull;    // 10*24*64*8 bf16 = 61440 f32 slots
static const size_t OFF_RJF = 1826744ull;    // 512*768 bf16 = 196608 f32 slots
static const size_t OFF_CAND= 2023352ull;    // 4096 u64 = 8192 f32 slots (8B-aligned)

typedef __attribute__((ext_vector_type(8))) short bf16x8;
typedef __attribute__((ext_vector_type(4))) float f32x4;

__device__ __forceinline__ unsigned short f2bf_rne(float f) {
    unsigned u = __float_as_uint(f);
    unsigned r = u + 0x7fffu + ((u >> 16) & 1u);
    return (unsigned short)(r >> 16);
}

// T[w][j] = b_out[j] + b_start@Wo1 + b_end@Wo2 + width_emb[w]@Wo3
__global__ void k_prep(const float* __restrict__ b_start, const float* __restrict__ b_end,
                       const float* __restrict__ b_out, const float* __restrict__ width_emb,
                       const float* __restrict__ W_out, float* __restrict__ T) {
    int j = blockIdx.x * 256 + threadIdx.x;
    if (j >= H) return;
    float p0 = 0.f, p1 = 0.f, p2 = 0.f, p3 = 0.f;
#pragma unroll 8
    for (int k = 0; k < H; k += 2) {
        p0 += b_start[k]     * W_out[(size_t)k * H + j];
        p1 += b_start[k + 1] * W_out[(size_t)(k + 1) * H + j];
        p2 += b_end[k]       * W_out[(size_t)(H + k) * H + j];
        p3 += b_end[k + 1]   * W_out[(size_t)(H + k + 1) * H + j];
    }
    float bias = b_out[j] + p0 + p1 + p2 + p3;
    for (int w = 0; w <= 10; ++w) {
        float acc = bias;
#pragma unroll
        for (int k = 0; k < 30; ++k)
            acc += width_emb[w * 30 + k] * W_out[(size_t)(2 * H + k) * H + j];
        T[w * H + j] = acc;
    }
}

// Ac = W_start @ W_out[0:768], Cc = W_end @ W_out[768:1536]. 64x64 tiles.
__global__ __launch_bounds__(256) void k_combine(const float* __restrict__ W_start,
    const float* __restrict__ W_end, const float* __restrict__ W_out,
    float* __restrict__ Ac, float* __restrict__ Cc) {
    __shared__ float sA[16][68];
    __shared__ float sB[16][68];
    const int z = blockIdx.z;
    const float* Wsrc = z ? W_end : W_start;
    const float* Wo = W_out + (z ? (size_t)H * H : 0);
    float* dst = z ? Cc : Ac;
    const int tid = threadIdx.x;
    const int m0 = blockIdx.y * 64, n0 = blockIdx.x * 64;
    const int tr = tid >> 4, tc = tid & 15;
    const int rr = tid >> 2, kg = (tid & 3) * 4;
    const int kb = tid >> 4, jc = (tid & 15) * 4;
    float acc[4][4];
#pragma unroll
    for (int i = 0; i < 4; ++i)
#pragma unroll
        for (int j = 0; j < 4; ++j) acc[i][j] = 0.f;
    for (int k0 = 0; k0 < H; k0 += 16) {
        float4 va = *(const float4*)(Wsrc + (size_t)(m0 + rr) * H + k0 + kg);
        float4 vb = *(const float4*)(Wo + (size_t)(k0 + kb) * H + n0 + jc);
        sA[kg + 0][rr] = va.x; sA[kg + 1][rr] = va.y;
        sA[kg + 2][rr] = va.z; sA[kg + 3][rr] = va.w;
        *(float4*)&sB[kb][jc] = vb;
        __syncthreads();
#pragma unroll
        for (int kk = 0; kk < 16; ++kk) {
            float a[4], b[4];
            *(float4*)a = *(const float4*)&sA[kk][tr * 4];
            *(float4*)b = *(const float4*)&sB[kk][tc * 4];
#pragma unroll
            for (int i = 0; i < 4; ++i)
#pragma unroll
                for (int j = 0; j < 4; ++j) acc[i][j] += a[i] * b[j];
        }
        __syncthreads();
    }
#pragma unroll
    for (int i = 0; i < 4; ++i) {
        float4 o = make_float4(acc[i][0], acc[i][1], acc[i][2], acc[i][3]);
        *(float4*)(dst + (size_t)(m0 + tr * 4 + i) * H + n0 + tc * 4) = o;
    }
}

// av = Ac@w_ment, cv = Cc@w_ment (one wave per row); block 384: tw[w] = T[w]·w_ment + b_ment
__global__ void k_vecs(const float* __restrict__ Ac, const float* __restrict__ Cc,
                       const float* __restrict__ T, const float* __restrict__ w_ment,
                       const float* __restrict__ b_ment, float* __restrict__ av,
                       float* __restrict__ cv, float* __restrict__ tw) {
    const int wid = threadIdx.x >> 6, lane = threadIdx.x & 63;
    if (blockIdx.x < 384) {
        const int gr = blockIdx.x * 4 + wid;  // 0..1535
        const float* row = (gr < H) ? (Ac + (size_t)gr * H) : (Cc + (size_t)(gr - H) * H);
        float s = 0.f;
#pragma unroll
        for (int q = 0; q < 12; ++q) s += row[lane + 64 * q] * w_ment[lane + 64 * q];
#pragma unroll
        for (int off = 32; off; off >>= 1) s += __shfl_down(s, off, 64);
        if (lane == 0) {
            if (gr < H) av[gr] = s; else cv[gr - H] = s;
        }
    } else {
        for (int w = wid; w <= 10; w += 4) {
            float s = 0.f;
#pragma unroll
            for (int q = 0; q < 12; ++q) s += T[w * H + lane + 64 * q] * w_ment[lane + 64 * q];
#pragma unroll
            for (int off = 32; off; off >>= 1) s += __shfl_down(s, off, 64);
            if (lane == 0) tw[w] = s + b_ment[0];
        }
    }
}

// score_r = st_r·av + en_r·cv + tw[width_r]; one wave per row, gathered seq reads
__global__ void k_scores2(const float* __restrict__ seq, const int* __restrict__ starts,
                          const int* __restrict__ ends, const float* __restrict__ av,
                          const float* __restrict__ cv, const float* __restrict__ tw,
                          float* __restrict__ SC) {
    const int wid = threadIdx.x >> 6, lane = threadIdx.x & 63;
    const int r = blockIdx.x * 4 + wid;
    const int b = r >> 12;
    const int s = starts[r], e = ends[r];
    int w = e - s; w = w < 0 ? 0 : (w > 10 ? 10 : w);
    const float4* st = (const float4*)(seq + (size_t)(b * SEQ + s) * H);
    const float4* en = (const float4*)(seq + (size_t)(b * SEQ + e) * H);
    const float4* a4 = (const float4*)av;
    const float4* c4 = (const float4*)cv;
    float acc = 0.f;
#pragma unroll
    for (int q = 0; q < 3; ++q) {
        float4 x = st[lane + 64 * q], y = a4[lane + 64 * q];
        acc += x.x * y.x + x.y * y.y + x.z * y.z + x.w * y.w;
        float4 x2 = en[lane + 64 * q], y2 = c4[lane + 64 * q];
        acc += x2.x * y2.x + x2.y * y2.y + x2.z * y2.z + x2.w * y2.w;
    }
#pragma unroll
    for (int off = 32; off; off >>= 1) acc += __shfl_down(acc, off, 64);
    if (lane == 0) SC[r] = acc + tw[w];
}

// stage 1: 32 blocks; each sorts a 512-score chunk descending, emits top-128 keys
__global__ __launch_bounds__(256) void k_sort1(const float* __restrict__ SC,
                                               unsigned long long* __restrict__ CAND) {
    __shared__ unsigned long long keys[512];
    const int blk = blockIdx.x;
    const int b = blk >> 3, c = blk & 7;
    const int tid = threadIdx.x;
    for (int i = tid; i < 512; i += 256) {
        const int gi = c * 512 + i;
        unsigned u = __float_as_uint(SC[b * NSP + gi]);
        u = (u & 0x80000000u) ? ~u : (u | 0x80000000u);
        keys[i] = ((unsigned long long)u << 32) | (unsigned)(0xFFFFFFFFu - (unsigned)gi);
    }
    __syncthreads();
    for (int k = 2; k <= 512; k <<= 1) {
        for (int j = k >> 1; j > 0; j >>= 1) {
            const int p = tid;
            const int i = ((p & ~(j - 1)) << 1) | (p & (j - 1));
            const int l = i | j;
            unsigned long long a = keys[i], d = keys[l];
            const bool desc = ((i & k) == 0);
            if ((a < d) == desc) { keys[i] = d; keys[l] = a; }
            __syncthreads();
        }
    }
    if (tid < 128) CAND[(size_t)(b * 8 + c) * 128 + tid] = keys[tid];
}

// stage 2: per batch, sort 1024 candidates descending; emit top-128 outputs
__global__ __launch_bounds__(512) void k_sort2(const unsigned long long* __restrict__ CAND,
    const int* __restrict__ starts, const int* __restrict__ ends,
    float* __restrict__ out, int* __restrict__ idxbuf) {
    __shared__ unsigned long long keys[1024];
    const int b = blockIdx.x;
    const int tid = threadIdx.x;
    for (int i = tid; i < 1024; i += 512) keys[i] = CAND[(size_t)b * 1024 + i];
    __syncthreads();
    for (int k = 2; k <= 1024; k <<= 1) {
        for (int j = k >> 1; j > 0; j >>= 1) {
            const int p = tid;
            const int i = ((p & ~(j - 1)) << 1) | (p & (j - 1));
            const int l = i | j;
            unsigned long long a = keys[i], d = keys[l];
            const bool desc = ((i & k) == 0);
            if ((a < d) == desc) { keys[i] = d; keys[l] = a; }
            __syncthreads();
        }
    }
    if (tid < TOPK) {
        const unsigned long long key = keys[tid];
        const int widx = (int)(0xFFFFFFFFu - (unsigned)(key & 0xFFFFFFFFu));
        const unsigned hu = (unsigned)(key >> 32);
        const float sval = __uint_as_float((hu & 0x80000000u) ? (hu & 0x7FFFFFFFu) : ~hu);
        out[b * TOPK + tid] = sval;
        idxbuf[b * TOPK + tid] = widx;
        out[OFS_FS + b * TOPK + tid] = (float)starts[b * NSP + widx];
        out[OFS_FE + b * TOPK + tid] = (float)ends[b * NSP + widx];
    }
}

// per winner: absolute seq rows + clipped width
__global__ void k_gather2(const int* __restrict__ idxb, const int* __restrict__ starts,
                          const int* __restrict__ ends, int* __restrict__ fsI,
                          int* __restrict__ feI, int* __restrict__ widI) {
    const int p = blockIdx.x * 256 + threadIdx.x;
    if (p >= 512) return;
    const int b = p >> 7, g = idxb[p];
    const int s = starts[b * NSP + g], e = ends[b * NSP + g];
    fsI[p] = b * SEQ + s;
    feI[p] = b * SEQ + e;
    int w = e - s;
    widI[p] = w < 0 ? 0 : (w > 10 ? 10 : w);
}

// RK[p] = seq[fs_p]@Ac + seq[fe_p]@Cc + T[wid_p]  (512x768, K=1536), 64x64 tiles
__global__ __launch_bounds__(256) void k_sr512(const float* __restrict__ seq,
    const int* __restrict__ fsI, const int* __restrict__ feI, const int* __restrict__ widI,
    const float* __restrict__ Ac, const float* __restrict__ Cc,
    const float* __restrict__ T, float* __restrict__ RK) {
    __shared__ float sA[16][68];
    __shared__ float sB[16][68];
    __shared__ int sRow[2][64];
    __shared__ int sWid[64];
    const int tid = threadIdx.x;
    const int m0 = blockIdx.y * 64, n0 = blockIdx.x * 64;
    if (tid < 64) {
        sRow[0][tid] = fsI[m0 + tid];
        sRow[1][tid] = feI[m0 + tid];
        sWid[tid] = widI[m0 + tid];
    }
    __syncthreads();
    const int tr = tid >> 4, tc = tid & 15;
    const int rr = tid >> 2, kg = (tid & 3) * 4;
    const int kb = tid >> 4, jc = (tid & 15) * 4;
    float acc[4][4];
#pragma unroll
    for (int i = 0; i < 4; ++i)
#pragma unroll
        for (int j = 0; j < 4; ++j) acc[i][j] = 0.f;
    for (int ph = 0; ph < 2; ++ph) {
        const float* W = ph ? Cc : Ac;
        const int* rowp = sRow[ph];
        for (int k0 = 0; k0 < H; k0 += 16) {
            float4 va = *(const float4*)(seq + (size_t)rowp[rr] * H + k0 + kg);
            float4 vb = *(const float4*)(W + (size_t)(k0 + kb) * H + n0 + jc);
            sA[kg + 0][rr] = va.x; sA[kg + 1][rr] = va.y;
            sA[kg + 2][rr] = va.z; sA[kg + 3][rr] = va.w;
            *(float4*)&sB[kb][jc] = vb;
            __syncthreads();
#pragma unroll
            for (int kk = 0; kk < 16; ++kk) {
                float a[4], b[4];
                *(float4*)a = *(const float4*)&sA[kk][tr * 4];
                *(float4*)b = *(const float4*)&sB[kk][tc * 4];
#pragma unroll
                for (int i = 0; i < 4; ++i)
#pragma unroll
                    for (int j = 0; j < 4; ++j) acc[i][j] += a[i] * b[j];
            }
            __syncthreads();
        }
    }
#pragma unroll
    for (int i = 0; i < 4; ++i) {
        const int rm = m0 + tr * 4 + i;
        float4 t = *(const float4*)(T + (size_t)sWid[tr * 4 + i] * H + n0 + tc * 4);
        float4 o = make_float4(acc[i][0] + t.x, acc[i][1] + t.y,
                               acc[i][2] + t.z, acc[i][3] + t.w);
        *(float4*)(RK + (size_t)rm * H + n0 + tc * 4) = o;
    }
}

// bf16 A-fragment-major copy of RK for k_pair MFMA
__global__ void k_frag(const float* __restrict__ RK, unsigned short* __restrict__ RJF) {
    const int p = blockIdx.x;
    const int tid = threadIdx.x;
    if (tid >= 96) return;
    const float* src = RK + (size_t)p * H;
    const int k0 = tid * 8;
    const int kt = k0 >> 5, sub = k0 & 31;
    const int lane = (p & 15) | ((sub >> 3) << 4);
    const int t = p >> 4;
    unsigned short* d2 = RJF + ((size_t)(t * 24 + kt) * 64 + lane) * 8;
#pragma unroll
    for (int e = 0; e < 8; ++e) d2[e] = f2bf_rne(src[k0 + e]);
}

// Wfrag: Wd (=W1[3H:4H]) in bf16, B-fragment-major order for 16x16x32 MFMA.
__global__ void k_prepw(const float* __restrict__ W1, unsigned short* __restrict__ WF) {
    const int idx = blockIdx.x * 256 + threadIdx.x;
    if (idx >= 10 * 24 * 64) return;
    const int nt = idx / 1536;
    const int rem = idx - nt * 1536;
    const int kt = rem >> 6, lane = rem & 63;
    const int n = nt * 16 + (lane & 15);
    const int kb = kt * 32 + (lane >> 4) * 8;
    unsigned short* dst = WF + (size_t)idx * 8;
#pragma unroll
    for (int e = 0; e < 8; ++e) {
        float v = (n < HIDD) ? W1[(size_t)(3 * H + kb + e) * HIDD + n] : 0.f;
        dst[e] = f2bf_rne(v);
    }
}

// gw[d]=ln_g*W2 (padded), S_gw = sum(ln_g*W2), C0 = sum(ln_b*W2)+b2
__global__ void k_prepg(const float* __restrict__ ln_g, const float* __restrict__ ln_b,
                        const float* __restrict__ W2, const float* __restrict__ b2,
                        float* __restrict__ GW, float* __restrict__ SCAL) {
    const int tid = threadIdx.x;
    if (tid < NPAD) GW[tid] = (tid < HIDD) ? ln_g[tid] * W2[tid] : 0.f;
    if (tid == 0) {
        float sg = 0.f, sb = 0.f;
        for (int d = 0; d < HIDD; ++d) { sg += ln_g[d] * W2[d]; sb += ln_b[d] * W2[d]; }
        SCAL[0] = sg;
        SCAL[1] = sb + b2[0];
    }
}

// U'[p][d] = r@(Wa+Wc) + b1, V'[p][d] = r@(Wb-Wc); stride 160, zero-padded
__global__ void k_uv(const float* __restrict__ RK, const float* __restrict__ W1,
                     const float* __restrict__ b1, float* __restrict__ U,
                     float* __restrict__ V) {
    __shared__ float r[H];
    const int p = blockIdx.x, tid = threadIdx.x;
    for (int k = tid; k < H; k += 192) r[k] = RK[(size_t)p * H + k];
    __syncthreads();
    if (tid < NPAD) {
        if (tid < HIDD) {
            float u = 0.f, v = 0.f;
            for (int h = 0; h < H; ++h) {
                float rv = r[h];
                float wa = W1[(size_t)h * HIDD + tid];
                float wb = W1[(size_t)(H + h) * HIDD + tid];
                float wc = W1[(size_t)(2 * H + h) * HIDD + tid];
                u += rv * (wa + wc);
                v += rv * (wb - wc);
            }
            U[(size_t)p * NPAD + tid] = u + b1[tid];
            V[(size_t)p * NPAD + tid] = v;
        } else {
            U[(size_t)p * NPAD + tid] = 0.f;
            V[(size_t)p * NPAD + tid] = 0.f;
        }
    }
}

// Pairwise MFMA: per (b, i, 32-j tile), 2 waves, each wave M=16 pairs x N=160 x K=768.
__global__ __launch_bounds__(128) void k_pair(
    const unsigned short* __restrict__ RJF, const unsigned short* __restrict__ WF,
    const float* __restrict__ RK, const float* __restrict__ U, const float* __restrict__ V,
    const float* __restrict__ GW, const float* __restrict__ SCAL,
    float* __restrict__ ant) {
    const int b = blockIdx.z, ii = blockIdx.y, j0 = blockIdx.x * 32;
    float* arow = ant + ((size_t)b * TOPK + ii) * TOPK;
    const int tid = threadIdx.x;
    if (j0 >= ii) {
        if (tid < 32) arow[j0 + tid] = 0.f;
        return;
    }
    const int wave = tid >> 6, lane = tid & 63;
    const int jbase = j0 + wave * 16;
    if (jbase >= ii) {
        if (lane < 16) arow[jbase + lane] = 0.f;
        return;
    }
    const int g = lane >> 4, c = lane & 15;
    const int t = b * 8 + (jbase >> 4);
    const unsigned short* Af = RJF + (size_t)t * 24 * 64 * 8;
    const float* Ri = RK + (size_t)(b * TOPK + ii) * H;

    f32x4 acc[10];
#pragma unroll
    for (int nt = 0; nt < 10; ++nt) acc[nt] = (f32x4){0.f, 0.f, 0.f, 0.f};

    for (int kt = 0; kt < 24; ++kt) {
        uint4 rj = *(const uint4*)(Af + ((size_t)(kt * 64 + lane)) * 8);
        const float* rip = Ri + kt * 32 + g * 8;
        float4 ri0 = *(const float4*)rip;
        float4 ri1 = *(const float4*)(rip + 4);
        float p0 = ri0.x * __uint_as_float(rj.x << 16);
        float p1 = ri0.y * __uint_as_float(rj.x & 0xffff0000u);
        float p2 = ri0.z * __uint_as_float(rj.y << 16);
        float p3 = ri0.w * __uint_as_float(rj.y & 0xffff0000u);
        float p4 = ri1.x * __uint_as_float(rj.z << 16);
        float p5 = ri1.y * __uint_as_float(rj.z & 0xffff0000u);
        float p6 = ri1.z * __uint_as_float(rj.w << 16);
        float p7 = ri1.w * __uint_as_float(rj.w & 0xffff0000u);
        bf16x8 a;
        a[0] = (short)f2bf_rne(p0); a[1] = (short)f2bf_rne(p1);
        a[2] = (short)f2bf_rne(p2); a[3] = (short)f2bf_rne(p3);
        a[4] = (short)f2bf_rne(p4); a[5] = (short)f2bf_rne(p5);
        a[6] = (short)f2bf_rne(p6); a[7] = (short)f2bf_rne(p7);
#pragma unroll
        for (int nt = 0; nt < 10; ++nt) {
            bf16x8 bv = *(const bf16x8*)(WF + ((size_t)((nt * 24 + kt) * 64 + lane)) * 8);
            acc[nt] = __builtin_amdgcn_mfma_f32_16x16x32_bf16(a, bv, acc[nt], 0, 0, 0);
        }
    }

    const float* Up = U + (size_t)(b * TOPK + ii) * NPAD;
    float u10[10], gw10[10];
#pragma unroll
    for (int nt = 0; nt < 10; ++nt) {
        const int d = nt * 16 + c;
        u10[nt] = Up[d];
        gw10[nt] = GW[d];
    }
    const float Sgw = SCAL[0], C0 = SCAL[1];
#pragma unroll
    for (int r = 0; r < 4; ++r) {
        const int j = jbase + g * 4 + r;
        const float* Vp = V + (size_t)(b * TOPK + j) * NPAD;
        float s1 = 0.f, s2 = 0.f, s3 = 0.f;
#pragma unroll
        for (int nt = 0; nt < 10; ++nt) {
            const int d = nt * 16 + c;
            float z = acc[nt][r] + u10[nt] + Vp[d];
            float h = (d < HIDD && z > 0.f) ? z : 0.f;
            s1 += h;
            s2 += h * h;
            s3 += h * gw10[nt];
        }
#pragma unroll
        for (int off = 1; off < 16; off <<= 1) {
            s1 += __shfl_xor(s1, off, 64);
            s2 += __shfl_xor(s2, off, 64);
            s3 += __shfl_xor(s3, off, 64);
        }
        const float mu = s1 * (1.f / HIDD);
        const float var = s2 * (1.f / HIDD) - mu * mu;
        const float rstd = rsqrtf(var + 1e-5f);
        const float val = rstd * (s3 - mu * Sgw) + C0;
        if (c == 0) arow[j] = (j < ii) ? val : 0.f;
    }
}

extern "C" void kernel_launch(void* const* d_in, const int* in_sizes, int n_in,
                              void* d_out, int out_size, void* d_ws, size_t ws_size,
                              hipStream_t stream) {
    const float* seq      = (const float*)d_in[0];
    const int*   starts   = (const int*)d_in[1];
    const int*   ends     = (const int*)d_in[2];
    const float* W_start  = (const float*)d_in[3];
    const float* b_start  = (const float*)d_in[4];
    const float* W_end    = (const float*)d_in[5];
    const float* b_end    = (const float*)d_in[6];
    const float* width_e  = (const float*)d_in[7];
    const float* W_out    = (const float*)d_in[8];
    const float* b_out    = (const float*)d_in[9];
    const float* w_ment   = (const float*)d_in[10];
    const float* b_ment   = (const float*)d_in[11];
    const float* W1       = (const float*)d_in[12];
    const float* b1       = (const float*)d_in[13];
    const float* ln_g     = (const float*)d_in[14];
    const float* ln_b     = (const float*)d_in[15];
    const float* W2       = (const float*)d_in[16];
    const float* b2       = (const float*)d_in[17];
    float* out = (float*)d_out;
    float* ws  = (float*)d_ws;

    float* Ac = ws + OFF_A;
    float* Cc = ws + OFF_C;
    float* Tt = ws + OFF_T;
    float* av = ws + OFF_AV;
    float* cv = ws + OFF_CV;
    float* tw = ws + OFF_TW;
    float* SC = ws + OFF_SC;
    int*   idxb = (int*)(ws + OFF_IDX);
    int*   fsI  = (int*)(ws + OFF_FS);
    int*   feI  = (int*)(ws + OFF_FE);
    int*   widI = (int*)(ws + OFF_WID);
    float* RKp = ws + OFF_RK;
    float* Up  = ws + OFF_U;
    float* Vp  = ws + OFF_V;
    float* GWp = ws + OFF_GW;
    float* SCALp = ws + OFF_SCAL;
    unsigned short* WFp  = (unsigned short*)(ws + OFF_WF);
    unsigned short* RJFp = (unsigned short*)(ws + OFF_RJF);
    unsigned long long* CANDp = (unsigned long long*)(ws + OFF_CAND);

    k_prep<<<3, 256, 0, stream>>>(b_start, b_end, b_out, width_e, W_out, Tt);
    k_combine<<<dim3(12, 12, 2), 256, 0, stream>>>(W_start, W_end, W_out, Ac, Cc);
    k_prepw<<<60, 256, 0, stream>>>(W1, WFp);
    k_prepg<<<1, 256, 0, stream>>>(ln_g, ln_b, W2, b2, GWp, SCALp);
    k_vecs<<<385, 256, 0, stream>>>(Ac, Cc, Tt, w_ment, b_ment, av, cv, tw);
    k_scores2<<<4096, 256, 0, stream>>>(seq, starts, ends, av, cv, tw, SC);
    k_sort1<<<32, 256, 0, stream>>>(SC, CANDp);
    k_sort2<<<4, 512, 0, stream>>>(CANDp, starts, ends, out, idxb);
    k_gather2<<<2, 256, 0, stream>>>(idxb, starts, ends, fsI, feI, widI);
    k_sr512<<<dim3(12, 8), 256, 0, stream>>>(seq, fsI, feI, widI, Ac, Cc, Tt, RKp);
    k_frag<<<512, 128, 0, stream>>>(RKp, RJFp);
    k_uv<<<512, 192, 0, stream>>>(RKp, W1, b1, Up, Vp);
    k_pair<<<dim3(4, 128, 4), 128, 0, stream>>>(RJFp, WFp, RKp, Up, Vp, GWp, SCALp,
                                                out + OFS_ANT);
}

// Round 5
// 330.371 us; speedup vs baseline: 4.9121x; 1.2415x over previous
//
#include <hip/hip_runtime.h>
#include <math.h>

#define H 768
#define SEQ 2048
#define NSP 4096
#define HIDD 150
#define TOPK 128
#define NPAD 160

// d_out layout (floats): [0,512) mention_scores | [512,66048) ant | [66048,66560) f_starts | [66560,67072) f_ends
#define OFS_ANT 512
#define OFS_FS 66048
#define OFS_FE 66560

// workspace layout (float offsets)
static const size_t OFF_A    = 0ull;          // 768*768
static const size_t OFF_C    = 589824ull;     // 768*768
static const size_t OFF_T    = 1179648ull;    // 11*768
static const size_t OFF_AV   = 1188096ull;    // 768
static const size_t OFF_CV   = 1188864ull;    // 768
static const size_t OFF_TW   = 1189632ull;    // 16
static const size_t OFF_SC   = 1189648ull;    // 16384
static const size_t OFF_IDX  = 1206032ull;    // 512 ints
static const size_t OFF_FS   = 1206544ull;    // 512 ints (absolute seq row)
static const size_t OFF_FE   = 1207056ull;    // 512 ints
static const size_t OFF_WID  = 1207568ull;    // 512 ints
static const size_t OFF_RK   = 1208080ull;    // 512*768 f32 (repr_k)
static const size_t OFF_U    = 1601296ull;    // 512*160 f32 (u + b1, padded)
static const size_t OFF_V    = 1683216ull;    // 512*160 f32 (v, padded)
static const size_t OFF_GW   = 1765136ull;    // 160 f32 (ln_g*W2, padded)
static const size_t OFF_SCAL = 1765296ull;    // 8 f32
static const size_t OFF_WF   = 1765304ull;    // 61440 f32 slots (bf16 W-fragments)
static const size_t OFF_RJF  = 1826744ull;    // 196608 f32 slots (bf16 A-fragments)
static const size_t OFF_CAND = 2023352ull;    // 4096 u64 = 8192 f32 (8B aligned: even)
static const size_t OFF_BIASP= 2031544ull;    // 8*768
static const size_t OFF_WC   = 2037688ull;    // 768*320
static const size_t OFF_RKP  = 2283448ull;    // 8*512*768 partials (12.6 MB)

typedef __attribute__((ext_vector_type(8))) short bf16x8;
typedef __attribute__((ext_vector_type(4))) float f32x4;

__device__ __forceinline__ unsigned short f2bf_rne(float f) {
    unsigned u = __float_as_uint(f);
    unsigned r = u + 0x7fffu + ((u >> 16) & 1u);
    return (unsigned short)(r >> 16);
}

// bias partials: biasP[kc][j] = (kc==0? b_out[j]:0) + sum_{k in chunk} b_start[k]Wo1[k][j] + b_end[k]Wo2[k][j]
__global__ void k_prep_bias(const float* __restrict__ b_start, const float* __restrict__ b_end,
                            const float* __restrict__ b_out, const float* __restrict__ W_out,
                            float* __restrict__ biasP) {
    const int j = blockIdx.x * 256 + threadIdx.x;
    const int kc = blockIdx.y;
    if (j >= H) return;
    float acc = (kc == 0) ? b_out[j] : 0.f;
    const int k0 = kc * 96;
#pragma unroll 4
    for (int k = k0; k < k0 + 96; ++k) {
        acc += b_start[k] * W_out[(size_t)k * H + j];
        acc += b_end[k]   * W_out[(size_t)(H + k) * H + j];
    }
    biasP[kc * H + j] = acc;
}

// T[w][j] = sum_kc biasP[kc][j] + width_emb[w]@Wo3[:,j]
__global__ void k_prep_T(const float* __restrict__ biasP, const float* __restrict__ width_emb,
                         const float* __restrict__ W_out, float* __restrict__ T) {
    const int w = blockIdx.x / 3, jb = blockIdx.x % 3;
    const int j = jb * 256 + threadIdx.x;
    float acc = 0.f;
#pragma unroll
    for (int kc = 0; kc < 8; ++kc) acc += biasP[kc * H + j];
#pragma unroll
    for (int k = 0; k < 30; ++k)
        acc += width_emb[w * 30 + k] * W_out[(size_t)(2 * H + k) * H + j];
    T[w * H + j] = acc;
}

// Ac = W_start @ W_out[0:768], Cc = W_end @ W_out[768:1536]. 64x64 tiles.
__global__ __launch_bounds__(256) void k_combine(const float* __restrict__ W_start,
    const float* __restrict__ W_end, const float* __restrict__ W_out,
    float* __restrict__ Ac, float* __restrict__ Cc) {
    __shared__ float sA[16][68];
    __shared__ float sB[16][68];
    const int z = blockIdx.z;
    const float* Wsrc = z ? W_end : W_start;
    const float* Wo = W_out + (z ? (size_t)H * H : 0);
    float* dst = z ? Cc : Ac;
    const int tid = threadIdx.x;
    const int m0 = blockIdx.y * 64, n0 = blockIdx.x * 64;
    const int tr = tid >> 4, tc = tid & 15;
    const int rr = tid >> 2, kg = (tid & 3) * 4;
    const int kb = tid >> 4, jc = (tid & 15) * 4;
    float acc[4][4];
#pragma unroll
    for (int i = 0; i < 4; ++i)
#pragma unroll
        for (int j = 0; j < 4; ++j) acc[i][j] = 0.f;
    for (int k0 = 0; k0 < H; k0 += 16) {
        float4 va = *(const float4*)(Wsrc + (size_t)(m0 + rr) * H + k0 + kg);
        float4 vb = *(const float4*)(Wo + (size_t)(k0 + kb) * H + n0 + jc);
        sA[kg + 0][rr] = va.x; sA[kg + 1][rr] = va.y;
        sA[kg + 2][rr] = va.z; sA[kg + 3][rr] = va.w;
        *(float4*)&sB[kb][jc] = vb;
        __syncthreads();
#pragma unroll
        for (int kk = 0; kk < 16; ++kk) {
            float a[4], b[4];
            *(float4*)a = *(const float4*)&sA[kk][tr * 4];
            *(float4*)b = *(const float4*)&sB[kk][tc * 4];
#pragma unroll
            for (int i = 0; i < 4; ++i)
#pragma unroll
                for (int j = 0; j < 4; ++j) acc[i][j] += a[i] * b[j];
        }
        __syncthreads();
    }
#pragma unroll
    for (int i = 0; i < 4; ++i) {
        float4 o = make_float4(acc[i][0], acc[i][1], acc[i][2], acc[i][3]);
        *(float4*)(dst + (size_t)(m0 + tr * 4 + i) * H + n0 + tc * 4) = o;
    }
}

// av = Ac@w_ment, cv = Cc@w_ment; block 384: tw[w] = T[w]·w_ment + b_ment
__global__ void k_vecs(const float* __restrict__ Ac, const float* __restrict__ Cc,
                       const float* __restrict__ T, const float* __restrict__ w_ment,
                       const float* __restrict__ b_ment, float* __restrict__ av,
                       float* __restrict__ cv, float* __restrict__ tw) {
    const int wid = threadIdx.x >> 6, lane = threadIdx.x & 63;
    if (blockIdx.x < 384) {
        const int gr = blockIdx.x * 4 + wid;
        const float* row = (gr < H) ? (Ac + (size_t)gr * H) : (Cc + (size_t)(gr - H) * H);
        float s = 0.f;
#pragma unroll
        for (int q = 0; q < 12; ++q) s += row[lane + 64 * q] * w_ment[lane + 64 * q];
#pragma unroll
        for (int off = 32; off; off >>= 1) s += __shfl_down(s, off, 64);
        if (lane == 0) {
            if (gr < H) av[gr] = s; else cv[gr - H] = s;
        }
    } else {
        for (int w = wid; w <= 10; w += 4) {
            float s = 0.f;
#pragma unroll
            for (int q = 0; q < 12; ++q) s += T[w * H + lane + 64 * q] * w_ment[lane + 64 * q];
#pragma unroll
            for (int off = 32; off; off >>= 1) s += __shfl_down(s, off, 64);
            if (lane == 0) tw[w] = s + b_ment[0];
        }
    }
}

// score_r = st_r·av + en_r·cv + tw[width_r]
__global__ void k_scores2(const float* __restrict__ seq, const int* __restrict__ starts,
                          const int* __restrict__ ends, const float* __restrict__ av,
                          const float* __restrict__ cv, const float* __restrict__ tw,
                          float* __restrict__ SC) {
    const int wid = threadIdx.x >> 6, lane = threadIdx.x & 63;
    const int r = blockIdx.x * 4 + wid;
    const int b = r >> 12;
    const int s = starts[r], e = ends[r];
    int w = e - s; w = w < 0 ? 0 : (w > 10 ? 10 : w);
    const float4* st = (const float4*)(seq + (size_t)(b * SEQ + s) * H);
    const float4* en = (const float4*)(seq + (size_t)(b * SEQ + e) * H);
    const float4* a4 = (const float4*)av;
    const float4* c4 = (const float4*)cv;
    float acc = 0.f;
#pragma unroll
    for (int q = 0; q < 3; ++q) {
        float4 x = st[lane + 64 * q], y = a4[lane + 64 * q];
        acc += x.x * y.x + x.y * y.y + x.z * y.z + x.w * y.w;
        float4 x2 = en[lane + 64 * q], y2 = c4[lane + 64 * q];
        acc += x2.x * y2.x + x2.y * y2.y + x2.z * y2.z + x2.w * y2.w;
    }
#pragma unroll
    for (int off = 32; off; off >>= 1) acc += __shfl_down(acc, off, 64);
    if (lane == 0) SC[r] = acc + tw[w];
}

// stage 1: 32 blocks; each sorts a 512-score chunk descending, emits top-128 keys
__global__ __launch_bounds__(256) void k_sort1(const float* __restrict__ SC,
                                               unsigned long long* __restrict__ CAND) {
    __shared__ unsigned long long keys[512];
    const int blk = blockIdx.x;
    const int b = blk >> 3, c = blk & 7;
    const int tid = threadIdx.x;
    for (int i = tid; i < 512; i += 256) {
        const int gi = c * 512 + i;
        unsigned u = __float_as_uint(SC[b * NSP + gi]);
        u = (u & 0x80000000u) ? ~u : (u | 0x80000000u);
        keys[i] = ((unsigned long long)u << 32) | (unsigned)(0xFFFFFFFFu - (unsigned)gi);
    }
    __syncthreads();
    for (int k = 2; k <= 512; k <<= 1) {
        for (int j = k >> 1; j > 0; j >>= 1) {
            const int p = tid;
            const int i = ((p & ~(j - 1)) << 1) | (p & (j - 1));
            const int l = i | j;
            unsigned long long a = keys[i], d = keys[l];
            const bool desc = ((i & k) == 0);
            if ((a < d) == desc) { keys[i] = d; keys[l] = a; }
            __syncthreads();
        }
    }
    if (tid < 128) CAND[(size_t)(b * 8 + c) * 128 + tid] = keys[tid];
}

// stage 2: per batch, sort 1024 candidates descending; emit top-128 outputs
__global__ __launch_bounds__(512) void k_sort2(const unsigned long long* __restrict__ CAND,
    const int* __restrict__ starts, const int* __restrict__ ends,
    float* __restrict__ out, int* __restrict__ idxbuf) {
    __shared__ unsigned long long keys[1024];
    const int b = blockIdx.x;
    const int tid = threadIdx.x;
    for (int i = tid; i < 1024; i += 512) keys[i] = CAND[(size_t)b * 1024 + i];
    __syncthreads();
    for (int k = 2; k <= 1024; k <<= 1) {
        for (int j = k >> 1; j > 0; j >>= 1) {
            const int p = tid;
            const int i = ((p & ~(j - 1)) << 1) | (p & (j - 1));
            const int l = i | j;
            unsigned long long a = keys[i], d = keys[l];
            const bool desc = ((i & k) == 0);
            if ((a < d) == desc) { keys[i] = d; keys[l] = a; }
            __syncthreads();
        }
    }
    if (tid < TOPK) {
        const unsigned long long key = keys[tid];
        const int widx = (int)(0xFFFFFFFFu - (unsigned)(key & 0xFFFFFFFFu));
        const unsigned hu = (unsigned)(key >> 32);
        const float sval = __uint_as_float((hu & 0x80000000u) ? (hu & 0x7FFFFFFFu) : ~hu);
        out[b * TOPK + tid] = sval;
        idxbuf[b * TOPK + tid] = widx;
        out[OFS_FS + b * TOPK + tid] = (float)starts[b * NSP + widx];
        out[OFS_FE + b * TOPK + tid] = (float)ends[b * NSP + widx];
    }
}

// per winner: absolute seq rows + clipped width
__global__ void k_gather2(const int* __restrict__ idxb, const int* __restrict__ starts,
                          const int* __restrict__ ends, int* __restrict__ fsI,
                          int* __restrict__ feI, int* __restrict__ widI) {
    const int p = blockIdx.x * 256 + threadIdx.x;
    if (p >= 512) return;
    const int b = p >> 7, g = idxb[p];
    const int s = starts[b * NSP + g], e = ends[b * NSP + g];
    fsI[p] = b * SEQ + s;
    feI[p] = b * SEQ + e;
    int w = e - s;
    widI[p] = w < 0 ? 0 : (w > 10 ? 10 : w);
}

// split-K partials: RKpart[kc] += gathered_rows @ W-chunk.  grid (12, 8, 8)
__global__ __launch_bounds__(256) void k_sr512(const float* __restrict__ seq,
    const int* __restrict__ fsI, const int* __restrict__ feI,
    const float* __restrict__ Ac, const float* __restrict__ Cc,
    float* __restrict__ RKpart) {
    __shared__ float sA[16][68];
    __shared__ float sB[16][68];
    __shared__ int sRow[64];
    const int tid = threadIdx.x;
    const int n0 = blockIdx.x * 64, m0 = blockIdx.y * 64, kc = blockIdx.z;
    const int ph = kc >> 2;
    const int kbase = (kc & 3) * 192;
    const int* rsrc = ph ? feI : fsI;
    if (tid < 64) sRow[tid] = rsrc[m0 + tid];
    __syncthreads();
    const float* W = ph ? Cc : Ac;
    const int tr = tid >> 4, tc = tid & 15;
    const int rr = tid >> 2, kg = (tid & 3) * 4;
    const int kb = tid >> 4, jc = (tid & 15) * 4;
    float acc[4][4];
#pragma unroll
    for (int i = 0; i < 4; ++i)
#pragma unroll
        for (int j = 0; j < 4; ++j) acc[i][j] = 0.f;
    for (int k0 = kbase; k0 < kbase + 192; k0 += 16) {
        float4 va = *(const float4*)(seq + (size_t)sRow[rr] * H + k0 + kg);
        float4 vb = *(const float4*)(W + (size_t)(k0 + kb) * H + n0 + jc);
        sA[kg + 0][rr] = va.x; sA[kg + 1][rr] = va.y;
        sA[kg + 2][rr] = va.z; sA[kg + 3][rr] = va.w;
        *(float4*)&sB[kb][jc] = vb;
        __syncthreads();
#pragma unroll
        for (int kk = 0; kk < 16; ++kk) {
            float a[4], b[4];
            *(float4*)a = *(const float4*)&sA[kk][tr * 4];
            *(float4*)b = *(const float4*)&sB[kk][tc * 4];
#pragma unroll
            for (int i = 0; i < 4; ++i)
#pragma unroll
                for (int j = 0; j < 4; ++j) acc[i][j] += a[i] * b[j];
        }
        __syncthreads();
    }
    float* dst = RKpart + (size_t)kc * 512 * H;
#pragma unroll
    for (int i = 0; i < 4; ++i) {
        float4 o = make_float4(acc[i][0], acc[i][1], acc[i][2], acc[i][3]);
        *(float4*)(dst + (size_t)(m0 + tr * 4 + i) * H + n0 + tc * 4) = o;
    }
}

// reduce 8 partials + T[width] -> RK; emit bf16 A-fragment-major copy (fused k_frag)
__global__ __launch_bounds__(256) void k_reduce(const float* __restrict__ RKpart,
    const float* __restrict__ T, const int* __restrict__ widI,
    float* __restrict__ RK, unsigned short* __restrict__ RJF) {
    __shared__ float srow[H];
    const int p = blockIdx.x, tid = threadIdx.x;
    const int w = widI[p];
    if (tid < 192) {
        const int c0 = tid * 4;
        float4 s = *(const float4*)(T + (size_t)w * H + c0);
#pragma unroll
        for (int kc = 0; kc < 8; ++kc) {
            float4 v = *(const float4*)(RKpart + ((size_t)kc * 512 + p) * H + c0);
            s.x += v.x; s.y += v.y; s.z += v.z; s.w += v.w;
        }
        *(float4*)(RK + (size_t)p * H + c0) = s;
        *(float4*)&srow[c0] = s;
    }
    __syncthreads();
    if (tid < 96) {
        const int k0 = tid * 8;
        const int kt = k0 >> 5, sub = k0 & 31;
        const int lane = (p & 15) | ((sub >> 3) << 4);
        const int t = p >> 4;
        unsigned short* d2 = RJF + ((size_t)(t * 24 + kt) * 64 + lane) * 8;
#pragma unroll
        for (int e = 0; e < 8; ++e) d2[e] = f2bf_rne(srow[k0 + e]);
    }
}

// Wfrag: Wd (=W1[3H:4H]) in bf16, B-fragment-major order for 16x16x32 MFMA.
__global__ void k_prepw(const float* __restrict__ W1, unsigned short* __restrict__ WF) {
    const int idx = blockIdx.x * 256 + threadIdx.x;
    if (idx >= 10 * 24 * 64) return;
    const int nt = idx / 1536;
    const int rem = idx - nt * 1536;
    const int kt = rem >> 6, lane = rem & 63;
    const int n = nt * 16 + (lane & 15);
    const int kb = kt * 32 + (lane >> 4) * 8;
    unsigned short* dst = WF + (size_t)idx * 8;
#pragma unroll
    for (int e = 0; e < 8; ++e) {
        float v = (n < HIDD) ? W1[(size_t)(3 * H + kb + e) * HIDD + n] : 0.f;
        dst[e] = f2bf_rne(v);
    }
}

// gw[d]=ln_g*W2 (padded), S_gw, C0
__global__ void k_prepg(const float* __restrict__ ln_g, const float* __restrict__ ln_b,
                        const float* __restrict__ W2, const float* __restrict__ b2,
                        float* __restrict__ GW, float* __restrict__ SCAL) {
    const int tid = threadIdx.x;
    if (tid < NPAD) GW[tid] = (tid < HIDD) ? ln_g[tid] * W2[tid] : 0.f;
    if (tid == 0) {
        float sg = 0.f, sb = 0.f;
        for (int d = 0; d < HIDD; ++d) { sg += ln_g[d] * W2[d]; sb += ln_b[d] * W2[d]; }
        SCAL[0] = sg;
        SCAL[1] = sb + b2[0];
    }
}

// WC[h][0:160) = Wa+Wc (0-padded), WC[h][160:320) = Wb-Wc
__global__ void k_prepuv(const float* __restrict__ W1, float* __restrict__ WC) {
    const int idx = blockIdx.x * 256 + threadIdx.x;
    if (idx >= H * 320) return;
    const int h = idx / 320, dd = idx - h * 320;
    float v = 0.f;
    if (dd < 160) {
        if (dd < HIDD)
            v = W1[(size_t)h * HIDD + dd] + W1[(size_t)(2 * H + h) * HIDD + dd];
    } else {
        const int d = dd - 160;
        if (d < HIDD)
            v = W1[(size_t)(H + h) * HIDD + d] - W1[(size_t)(2 * H + h) * HIDD + d];
    }
    WC[idx] = v;
}

// U[p][d] = r_p·(Wa+Wc)_d + b1[d], V[p][d] = r_p·(Wb-Wc)_d; 4 rows per block
__global__ __launch_bounds__(320) void k_uv2(const float* __restrict__ RK,
    const float* __restrict__ WC, const float* __restrict__ b1,
    float* __restrict__ U, float* __restrict__ V) {
    __shared__ float r4[4][H];
    const int p0 = blockIdx.x * 4, tid = threadIdx.x;
    for (int i = tid; i < 4 * 192; i += 320) {
        const int q = i / 192, c = (i - q * 192) * 4;
        *(float4*)&r4[q][c] = *(const float4*)(RK + (size_t)(p0 + q) * H + c);
    }
    __syncthreads();
    float a0 = 0.f, a1 = 0.f, a2 = 0.f, a3 = 0.f;
#pragma unroll 4
    for (int h = 0; h < H; ++h) {
        const float wc = WC[h * 320 + tid];
        a0 += r4[0][h] * wc;
        a1 += r4[1][h] * wc;
        a2 += r4[2][h] * wc;
        a3 += r4[3][h] * wc;
    }
    const bool isU = tid < 160;
    const int d = isU ? tid : tid - 160;
    const float addb = (isU && d < HIDD) ? b1[d] : 0.f;
    float* dst = isU ? U : V;
    dst[(size_t)(p0 + 0) * NPAD + d] = a0 + addb;
    dst[(size_t)(p0 + 1) * NPAD + d] = a1 + addb;
    dst[(size_t)(p0 + 2) * NPAD + d] = a2 + addb;
    dst[(size_t)(p0 + 3) * NPAD + d] = a3 + addb;
}

// Pairwise MFMA: per (b, i, 32-j tile), 2 waves, each wave M=16 pairs x N=160 x K=768.
__global__ __launch_bounds__(128) void k_pair(
    const unsigned short* __restrict__ RJF, const unsigned short* __restrict__ WF,
    const float* __restrict__ RK, const float* __restrict__ U, const float* __restrict__ V,
    const float* __restrict__ GW, const float* __restrict__ SCAL,
    float* __restrict__ ant) {
    const int b = blockIdx.z, ii = blockIdx.y, j0 = blockIdx.x * 32;
    float* arow = ant + ((size_t)b * TOPK + ii) * TOPK;
    const int tid = threadIdx.x;
    if (j0 >= ii) {
        if (tid < 32) arow[j0 + tid] = 0.f;
        return;
    }
    const int wave = tid >> 6, lane = tid & 63;
    const int jbase = j0 + wave * 16;
    if (jbase >= ii) {
        if (lane < 16) arow[jbase + lane] = 0.f;
        return;
    }
    const int g = lane >> 4, c = lane & 15;
    const int t = b * 8 + (jbase >> 4);
    const unsigned short* Af = RJF + (size_t)t * 24 * 64 * 8;
    const float* Ri = RK + (size_t)(b * TOPK + ii) * H;

    f32x4 acc[10];
#pragma unroll
    for (int nt = 0; nt < 10; ++nt) acc[nt] = (f32x4){0.f, 0.f, 0.f, 0.f};

    for (int kt = 0; kt < 24; ++kt) {
        uint4 rj = *(const uint4*)(Af + ((size_t)(kt * 64 + lane)) * 8);
        const float* rip = Ri + kt * 32 + g * 8;
        float4 ri0 = *(const float4*)rip;
        float4 ri1 = *(const float4*)(rip + 4);
        float p0 = ri0.x * __uint_as_float(rj.x << 16);
        float p1 = ri0.y * __uint_as_float(rj.x & 0xffff0000u);
        float p2 = ri0.z * __uint_as_float(rj.y << 16);
        float p3 = ri0.w * __uint_as_float(rj.y & 0xffff0000u);
        float p4 = ri1.x * __uint_as_float(rj.z << 16);
        float p5 = ri1.y * __uint_as_float(rj.z & 0xffff0000u);
        float p6 = ri1.z * __uint_as_float(rj.w << 16);
        float p7 = ri1.w * __uint_as_float(rj.w & 0xffff0000u);
        bf16x8 a;
        a[0] = (short)f2bf_rne(p0); a[1] = (short)f2bf_rne(p1);
        a[2] = (short)f2bf_rne(p2); a[3] = (short)f2bf_rne(p3);
        a[4] = (short)f2bf_rne(p4); a[5] = (short)f2bf_rne(p5);
        a[6] = (short)f2bf_rne(p6); a[7] = (short)f2bf_rne(p7);
#pragma unroll
        for (int nt = 0; nt < 10; ++nt) {
            bf16x8 bv = *(const bf16x8*)(WF + ((size_t)((nt * 24 + kt) * 64 + lane)) * 8);
            acc[nt] = __builtin_amdgcn_mfma_f32_16x16x32_bf16(a, bv, acc[nt], 0, 0, 0);
        }
    }

    const float* Up = U + (size_t)(b * TOPK + ii) * NPAD;
    float u10[10], gw10[10];
#pragma unroll
    for (int nt = 0; nt < 10; ++nt) {
        const int d = nt * 16 + c;
        u10[nt] = Up[d];
        gw10[nt] = GW[d];
    }
    const float Sgw = SCAL[0], C0 = SCAL[1];
#pragma unroll
    for (int r = 0; r < 4; ++r) {
        const int j = jbase + g * 4 + r;
        const float* Vp = V + (size_t)(b * TOPK + j) * NPAD;
        float s1 = 0.f, s2 = 0.f, s3 = 0.f;
#pragma unroll
        for (int nt = 0; nt < 10; ++nt) {
            const int d = nt * 16 + c;
            float z = acc[nt][r] + u10[nt] + Vp[d];
            float h = (d < HIDD && z > 0.f) ? z : 0.f;
            s1 += h;
            s2 += h * h;
            s3 += h * gw10[nt];
        }
#pragma unroll
        for (int off = 1; off < 16; off <<= 1) {
            s1 += __shfl_xor(s1, off, 64);
            s2 += __shfl_xor(s2, off, 64);
            s3 += __shfl_xor(s3, off, 64);
        }
        const float mu = s1 * (1.f / HIDD);
        const float var = s2 * (1.f / HIDD) - mu * mu;
        const float rstd = rsqrtf(var + 1e-5f);
        const float val = rstd * (s3 - mu * Sgw) + C0;
        if (c == 0) arow[j] = (j < ii) ? val : 0.f;
    }
}

extern "C" void kernel_launch(void* const* d_in, const int* in_sizes, int n_in,
                              void* d_out, int out_size, void* d_ws, size_t ws_size,
                              hipStream_t stream) {
    const float* seq      = (const float*)d_in[0];
    const int*   starts   = (const int*)d_in[1];
    const int*   ends     = (const int*)d_in[2];
    const float* W_start  = (const float*)d_in[3];
    const float* b_start  = (const float*)d_in[4];
    const float* W_end    = (const float*)d_in[5];
    const float* b_end    = (const float*)d_in[6];
    const float* width_e  = (const float*)d_in[7];
    const float* W_out    = (const float*)d_in[8];
    const float* b_out    = (const float*)d_in[9];
    const float* w_ment   = (const float*)d_in[10];
    const float* b_ment   = (const float*)d_in[11];
    const float* W1       = (const float*)d_in[12];
    const float* b1       = (const float*)d_in[13];
    const float* ln_g     = (const float*)d_in[14];
    const float* ln_b     = (const float*)d_in[15];
    const float* W2       = (const float*)d_in[16];
    const float* b2       = (const float*)d_in[17];
    float* out = (float*)d_out;
    float* ws  = (float*)d_ws;

    float* Ac = ws + OFF_A;
    float* Cc = ws + OFF_C;
    float* Tt = ws + OFF_T;
    float* av = ws + OFF_AV;
    float* cv = ws + OFF_CV;
    float* tw = ws + OFF_TW;
    float* SC = ws + OFF_SC;
    int*   idxb = (int*)(ws + OFF_IDX);
    int*   fsI  = (int*)(ws + OFF_FS);
    int*   feI  = (int*)(ws + OFF_FE);
    int*   widI = (int*)(ws + OFF_WID);
    float* RKp = ws + OFF_RK;
    float* Up  = ws + OFF_U;
    float* Vp  = ws + OFF_V;
    float* GWp = ws + OFF_GW;
    float* SCALp = ws + OFF_SCAL;
    unsigned short* WFp  = (unsigned short*)(ws + OFF_WF);
    unsigned short* RJFp = (unsigned short*)(ws + OFF_RJF);
    unsigned long long* CANDp = (unsigned long long*)(ws + OFF_CAND);
    float* biasP = ws + OFF_BIASP;
    float* WCp   = ws + OFF_WC;
    float* RKpart= ws + OFF_RKP;

    k_prep_bias<<<dim3(3, 8), 256, 0, stream>>>(b_start, b_end, b_out, W_out, biasP);
    k_prep_T<<<33, 256, 0, stream>>>(biasP, width_e, W_out, Tt);
    k_combine<<<dim3(12, 12, 2), 256, 0, stream>>>(W_start, W_end, W_out, Ac, Cc);
    k_prepw<<<60, 256, 0, stream>>>(W1, WFp);
    k_prepg<<<1, 256, 0, stream>>>(ln_g, ln_b, W2, b2, GWp, SCALp);
    k_prepuv<<<960, 256, 0, stream>>>(W1, WCp);
    k_vecs<<<385, 256, 0, stream>>>(Ac, Cc, Tt, w_ment, b_ment, av, cv, tw);
    k_scores2<<<4096, 256, 0, stream>>>(seq, starts, ends, av, cv, tw, SC);
    k_sort1<<<32, 256, 0, stream>>>(SC, CANDp);
    k_sort2<<<4, 512, 0, stream>>>(CANDp, starts, ends, out, idxb);
    k_gather2<<<2, 256, 0, stream>>>(idxb, starts, ends, fsI, feI, widI);
    k_sr512<<<dim3(12, 8, 8), 256, 0, stream>>>(seq, fsI, feI, Ac, Cc, RKpart);
    k_reduce<<<512, 256, 0, stream>>>(RKpart, Tt, widI, RKp, RJFp);
    k_uv2<<<128, 320, 0, stream>>>(RKp, WCp, b1, Up, Vp);
    k_pair<<<dim3(4, 128, 4), 128, 0, stream>>>(RJFp, WFp, RKp, Up, Vp, GWp, SCALp,
                                                out + OFS_ANT);
}

// Round 6
// 285.053 us; speedup vs baseline: 5.6930x; 1.1590x over previous
//
#include <hip/hip_runtime.h>
#include <math.h>

#define H 768
#define SEQ 2048
#define NSP 4096
#define HIDD 150
#define TOPK 128
#define NPAD 160

// d_out layout (floats): [0,512) mention_scores | [512,66048) ant | [66048,66560) f_starts | [66560,67072) f_ends
#define OFS_ANT 512
#define OFS_FS 66048
#define OFS_FE 66560

// workspace layout (float offsets) — ~19.7 MB total
static const size_t OFF_T     = 0ull;         // 11*768
static const size_t OFF_BIASP = 8448ull;      // 8*768
static const size_t OFF_WOV   = 14592ull;     // 1536  (Wo1@wm | Wo2@wm)
static const size_t OFF_AV    = 16128ull;     // 768
static const size_t OFF_CV    = 16896ull;     // 768
static const size_t OFF_TW    = 17664ull;     // 16
static const size_t OFF_PD    = 17680ull;     // 2*8192 position dots
static const size_t OFF_SC    = 34064ull;     // 16384
static const size_t OFF_CAND  = 50448ull;     // 4096 u64 = 8192 f32 (even: 8B aligned)
static const size_t OFF_IDX   = 58640ull;     // 512 ints
static const size_t OFF_FS    = 59152ull;     // 512 ints
static const size_t OFF_FE    = 59664ull;     // 512 ints
static const size_t OFF_WID   = 60176ull;     // 512 ints
static const size_t OFF_RK    = 60688ull;     // 512*768
static const size_t OFF_U     = 453904ull;    // 512*160
static const size_t OFF_V     = 535824ull;    // 512*160
static const size_t OFF_GW    = 617744ull;    // 160
static const size_t OFF_SCAL  = 617904ull;    // 8
static const size_t OFF_WF    = 617912ull;    // 61440 (Wd bf16 frags)
static const size_t OFF_WCF   = 679352ull;    // 122880 (UV-weight bf16 frags, 20 n-tiles)
static const size_t OFF_RJF   = 802232ull;    // 196608 (RK bf16 A-frags)
static const size_t OFF_SE    = 998840ull;    // 2*512*768 (SE | EE)
static const size_t OFF_SEP   = 1785272ull;   // 8*512*768 partials (reused as RKP)

typedef __attribute__((ext_vector_type(8))) short bf16x8;
typedef __attribute__((ext_vector_type(4))) float f32x4;

__device__ __forceinline__ unsigned short f2bf_rne(float f) {
    unsigned u = __float_as_uint(f);
    unsigned r = u + 0x7fffu + ((u >> 16) & 1u);
    return (unsigned short)(r >> 16);
}

// bias partials
__global__ void k_prep_bias(const float* __restrict__ b_start, const float* __restrict__ b_end,
                            const float* __restrict__ b_out, const float* __restrict__ W_out,
                            float* __restrict__ biasP) {
    const int j = blockIdx.x * 256 + threadIdx.x;
    const int kc = blockIdx.y;
    if (j >= H) return;
    float acc = (kc == 0) ? b_out[j] : 0.f;
    const int k0 = kc * 96;
#pragma unroll 4
    for (int k = k0; k < k0 + 96; ++k) {
        acc += b_start[k] * W_out[(size_t)k * H + j];
        acc += b_end[k]   * W_out[(size_t)(H + k) * H + j];
    }
    biasP[kc * H + j] = acc;
}

// T[w][j]
__global__ void k_prep_T(const float* __restrict__ biasP, const float* __restrict__ width_emb,
                         const float* __restrict__ W_out, float* __restrict__ T) {
    const int w = blockIdx.x / 3, jb = blockIdx.x % 3;
    const int j = jb * 256 + threadIdx.x;
    float acc = 0.f;
#pragma unroll
    for (int kc = 0; kc < 8; ++kc) acc += biasP[kc * H + j];
#pragma unroll
    for (int k = 0; k < 30; ++k)
        acc += width_emb[w * 30 + k] * W_out[(size_t)(2 * H + k) * H + j];
    T[w * H + j] = acc;
}

// WOV[gr] = W_out[gr,:]·w_ment  for gr in [0,1536)  (rows of Wo1 then Wo2)
__global__ void k_wvecs(const float* __restrict__ W_out, const float* __restrict__ w_ment,
                        float* __restrict__ WOV) {
    const int wid = threadIdx.x >> 6, lane = threadIdx.x & 63;
    const int gr = blockIdx.x * 4 + wid;
    const float* row = W_out + (size_t)gr * H;
    float s = 0.f;
#pragma unroll
    for (int q = 0; q < 12; ++q) s += row[lane + 64 * q] * w_ment[lane + 64 * q];
#pragma unroll
    for (int off = 32; off; off >>= 1) s += __shfl_down(s, off, 64);
    if (lane == 0) WOV[gr] = s;
}

// av[m] = W_start[m,:]·wo1v ; cv[m] = W_end[m,:]·wo2v ; block 384: tw
__global__ void k_avcv(const float* __restrict__ W_start, const float* __restrict__ W_end,
                       const float* __restrict__ WOV, const float* __restrict__ T,
                       const float* __restrict__ w_ment, const float* __restrict__ b_ment,
                       float* __restrict__ av, float* __restrict__ cv, float* __restrict__ tw) {
    const int wid = threadIdx.x >> 6, lane = threadIdx.x & 63;
    if (blockIdx.x < 384) {
        const int gr = blockIdx.x * 4 + wid;
        const float* row = (gr < H) ? (W_start + (size_t)gr * H) : (W_end + (size_t)(gr - H) * H);
        const float* vec = (gr < H) ? WOV : (WOV + H);
        float s = 0.f;
#pragma unroll
        for (int q = 0; q < 12; ++q) s += row[lane + 64 * q] * vec[lane + 64 * q];
#pragma unroll
        for (int off = 32; off; off >>= 1) s += __shfl_down(s, off, 64);
        if (lane == 0) {
            if (gr < H) av[gr] = s; else cv[gr - H] = s;
        }
    } else {
        for (int w = wid; w <= 10; w += 4) {
            float s = 0.f;
#pragma unroll
            for (int q = 0; q < 12; ++q) s += T[w * H + lane + 64 * q] * w_ment[lane + 64 * q];
#pragma unroll
            for (int off = 32; off; off >>= 1) s += __shfl_down(s, off, 64);
            if (lane == 0) tw[w] = s + b_ment[0];
        }
    }
}

// PD[0][r]=seq_row·av, PD[1][r]=seq_row·cv ; one wave per position, row read once
__global__ void k_posdots(const float* __restrict__ seq, const float* __restrict__ av,
                          const float* __restrict__ cv, float* __restrict__ PD) {
    const int wid = threadIdx.x >> 6, lane = threadIdx.x & 63;
    const int r = blockIdx.x * 4 + wid;  // 0..8191 = b*2048+pos
    const float4* row = (const float4*)(seq + (size_t)r * H);
    const float4* a4 = (const float4*)av;
    const float4* c4 = (const float4*)cv;
    float sa = 0.f, sc = 0.f;
#pragma unroll
    for (int q = 0; q < 3; ++q) {
        float4 x = row[lane + 64 * q];
        float4 ya = a4[lane + 64 * q], yc = c4[lane + 64 * q];
        sa += x.x * ya.x + x.y * ya.y + x.z * ya.z + x.w * ya.w;
        sc += x.x * yc.x + x.y * yc.y + x.z * yc.z + x.w * yc.w;
    }
#pragma unroll
    for (int off = 32; off; off >>= 1) {
        sa += __shfl_down(sa, off, 64);
        sc += __shfl_down(sc, off, 64);
    }
    if (lane == 0) { PD[r] = sa; PD[8192 + r] = sc; }
}

// SC[r] = PD0[b,s] + PD1[b,e] + tw[w]
__global__ void k_scoregather(const float* __restrict__ PD, const int* __restrict__ starts,
                              const int* __restrict__ ends, const float* __restrict__ tw,
                              float* __restrict__ SC) {
    const int r = blockIdx.x * 256 + threadIdx.x;
    const int b = r >> 12;
    const int s = starts[r], e = ends[r];
    int w = e - s; w = w < 0 ? 0 : (w > 10 ? 10 : w);
    SC[r] = PD[b * SEQ + s] + PD[8192 + b * SEQ + e] + tw[w];
}

// stage 1 sort: 32 blocks; each sorts a 512-score chunk, emits top-128 keys
__global__ __launch_bounds__(256) void k_sort1(const float* __restrict__ SC,
                                               unsigned long long* __restrict__ CAND) {
    __shared__ unsigned long long keys[512];
    const int blk = blockIdx.x;
    const int b = blk >> 3, c = blk & 7;
    const int tid = threadIdx.x;
    for (int i = tid; i < 512; i += 256) {
        const int gi = c * 512 + i;
        unsigned u = __float_as_uint(SC[b * NSP + gi]);
        u = (u & 0x80000000u) ? ~u : (u | 0x80000000u);
        keys[i] = ((unsigned long long)u << 32) | (unsigned)(0xFFFFFFFFu - (unsigned)gi);
    }
    __syncthreads();
    for (int k = 2; k <= 512; k <<= 1) {
        for (int j = k >> 1; j > 0; j >>= 1) {
            const int p = tid;
            const int i = ((p & ~(j - 1)) << 1) | (p & (j - 1));
            const int l = i | j;
            unsigned long long a = keys[i], d = keys[l];
            const bool desc = ((i & k) == 0);
            if ((a < d) == desc) { keys[i] = d; keys[l] = a; }
            __syncthreads();
        }
    }
    if (tid < 128) CAND[(size_t)(b * 8 + c) * 128 + tid] = keys[tid];
}

// stage 2: per batch, sort 1024 candidates; emit top-128 outputs
__global__ __launch_bounds__(512) void k_sort2(const unsigned long long* __restrict__ CAND,
    const int* __restrict__ starts, const int* __restrict__ ends,
    float* __restrict__ out, int* __restrict__ idxbuf) {
    __shared__ unsigned long long keys[1024];
    const int b = blockIdx.x;
    const int tid = threadIdx.x;
    for (int i = tid; i < 1024; i += 512) keys[i] = CAND[(size_t)b * 1024 + i];
    __syncthreads();
    for (int k = 2; k <= 1024; k <<= 1) {
        for (int j = k >> 1; j > 0; j >>= 1) {
            const int p = tid;
            const int i = ((p & ~(j - 1)) << 1) | (p & (j - 1));
            const int l = i | j;
            unsigned long long a = keys[i], d = keys[l];
            const bool desc = ((i & k) == 0);
            if ((a < d) == desc) { keys[i] = d; keys[l] = a; }
            __syncthreads();
        }
    }
    if (tid < TOPK) {
        const unsigned long long key = keys[tid];
        const int widx = (int)(0xFFFFFFFFu - (unsigned)(key & 0xFFFFFFFFu));
        const unsigned hu = (unsigned)(key >> 32);
        const float sval = __uint_as_float((hu & 0x80000000u) ? (hu & 0x7FFFFFFFu) : ~hu);
        out[b * TOPK + tid] = sval;
        idxbuf[b * TOPK + tid] = widx;
        out[OFS_FS + b * TOPK + tid] = (float)starts[b * NSP + widx];
        out[OFS_FE + b * TOPK + tid] = (float)ends[b * NSP + widx];
    }
}

// per winner: absolute seq rows + clipped width
__global__ void k_gather2(const int* __restrict__ idxb, const int* __restrict__ starts,
                          const int* __restrict__ ends, int* __restrict__ fsI,
                          int* __restrict__ feI, int* __restrict__ widI) {
    const int p = blockIdx.x * 256 + threadIdx.x;
    if (p >= 512) return;
    const int b = p >> 7, g = idxb[p];
    const int s = starts[b * NSP + g], e = ends[b * NSP + g];
    fsI[p] = b * SEQ + s;
    feI[p] = b * SEQ + e;
    int w = e - s;
    widI[p] = w < 0 ? 0 : (w > 10 ? 10 : w);
}

// SEP[z] = gathered seq rows @ W chunk.  z: which=z>>2 (start/end), kc=z&3 (K chunk of 192)
__global__ __launch_bounds__(256) void k_se(const float* __restrict__ seq,
    const int* __restrict__ fsI, const int* __restrict__ feI,
    const float* __restrict__ W_start, const float* __restrict__ W_end,
    float* __restrict__ SEP) {
    __shared__ float sA[16][68];
    __shared__ float sB[16][68];
    __shared__ int sRow[64];
    const int tid = threadIdx.x;
    const int n0 = blockIdx.x * 64, m0 = blockIdx.y * 64, z = blockIdx.z;
    const int which = z >> 2;
    const int kbase = (z & 3) * 192;
    const int* rsrc = which ? feI : fsI;
    if (tid < 64) sRow[tid] = rsrc[m0 + tid];
    __syncthreads();
    const float* W = which ? W_end : W_start;
    const int tr = tid >> 4, tc = tid & 15;
    const int rr = tid >> 2, kg = (tid & 3) * 4;
    const int kb = tid >> 4, jc = (tid & 15) * 4;
    float acc[4][4];
#pragma unroll
    for (int i = 0; i < 4; ++i)
#pragma unroll
        for (int j = 0; j < 4; ++j) acc[i][j] = 0.f;
    for (int k0 = kbase; k0 < kbase + 192; k0 += 16) {
        float4 va = *(const float4*)(seq + (size_t)sRow[rr] * H + k0 + kg);
        float4 vb = *(const float4*)(W + (size_t)(k0 + kb) * H + n0 + jc);
        sA[kg + 0][rr] = va.x; sA[kg + 1][rr] = va.y;
        sA[kg + 2][rr] = va.z; sA[kg + 3][rr] = va.w;
        *(float4*)&sB[kb][jc] = vb;
        __syncthreads();
#pragma unroll
        for (int kk = 0; kk < 16; ++kk) {
            float a[4], b[4];
            *(float4*)a = *(const float4*)&sA[kk][tr * 4];
            *(float4*)b = *(const float4*)&sB[kk][tc * 4];
#pragma unroll
            for (int i = 0; i < 4; ++i)
#pragma unroll
                for (int j = 0; j < 4; ++j) acc[i][j] += a[i] * b[j];
        }
        __syncthreads();
    }
    float* dst = SEP + (size_t)z * 512 * H;
#pragma unroll
    for (int i = 0; i < 4; ++i) {
        float4 o = make_float4(acc[i][0], acc[i][1], acc[i][2], acc[i][3]);
        *(float4*)(dst + (size_t)(m0 + tr * 4 + i) * H + n0 + tc * 4) = o;
    }
}

// SE[p] = sum of 4 K-chunk partials (p = which*512 + row)
__global__ void k_reduceSE(const float* __restrict__ SEP, float* __restrict__ SE) {
    const int p = blockIdx.x, tid = threadIdx.x;
    if (tid >= 192) return;
    const int which = p >> 9, row = p & 511;
    const int c0 = tid * 4;
    float4 s = make_float4(0.f, 0.f, 0.f, 0.f);
#pragma unroll
    for (int kc = 0; kc < 4; ++kc) {
        float4 v = *(const float4*)(SEP + ((size_t)((which << 2) | kc) * 512 + row) * H + c0);
        s.x += v.x; s.y += v.y; s.z += v.z; s.w += v.w;
    }
    *(float4*)(SE + (size_t)p * H + c0) = s;
}

// RKP[z] = SE-half @ W_out chunk.  z: ph=z>>2 (SE@Wo1 / EE@Wo2), kc=z&3
__global__ __launch_bounds__(256) void k_rk(const float* __restrict__ SE,
    const float* __restrict__ W_out, float* __restrict__ RKP) {
    __shared__ float sA[16][68];
    __shared__ float sB[16][68];
    const int tid = threadIdx.x;
    const int n0 = blockIdx.x * 64, m0 = blockIdx.y * 64, z = blockIdx.z;
    const int ph = z >> 2;
    const int kbase = (z & 3) * 192;
    const float* A = SE + (size_t)ph * 512 * H;
    const float* B = W_out + (size_t)ph * H * H;
    const int tr = tid >> 4, tc = tid & 15;
    const int rr = tid >> 2, kg = (tid & 3) * 4;
    const int kb = tid >> 4, jc = (tid & 15) * 4;
    float acc[4][4];
#pragma unroll
    for (int i = 0; i < 4; ++i)
#pragma unroll
        for (int j = 0; j < 4; ++j) acc[i][j] = 0.f;
    for (int k0 = kbase; k0 < kbase + 192; k0 += 16) {
        float4 va = *(const float4*)(A + (size_t)(m0 + rr) * H + k0 + kg);
        float4 vb = *(const float4*)(B + (size_t)(k0 + kb) * H + n0 + jc);
        sA[kg + 0][rr] = va.x; sA[kg + 1][rr] = va.y;
        sA[kg + 2][rr] = va.z; sA[kg + 3][rr] = va.w;
        *(float4*)&sB[kb][jc] = vb;
        __syncthreads();
#pragma unroll
        for (int kk = 0; kk < 16; ++kk) {
            float a[4], b[4];
            *(float4*)a = *(const float4*)&sA[kk][tr * 4];
            *(float4*)b = *(const float4*)&sB[kk][tc * 4];
#pragma unroll
            for (int i = 0; i < 4; ++i)
#pragma unroll
                for (int j = 0; j < 4; ++j) acc[i][j] += a[i] * b[j];
        }
        __syncthreads();
    }
    float* dst = RKP + (size_t)z * 512 * H;
#pragma unroll
    for (int i = 0; i < 4; ++i) {
        float4 o = make_float4(acc[i][0], acc[i][1], acc[i][2], acc[i][3]);
        *(float4*)(dst + (size_t)(m0 + tr * 4 + i) * H + n0 + tc * 4) = o;
    }
}

// reduce 8 partials + T[width] -> RK; emit bf16 A-fragment-major copy
__global__ __launch_bounds__(256) void k_reduce(const float* __restrict__ RKpart,
    const float* __restrict__ T, const int* __restrict__ widI,
    float* __restrict__ RK, unsigned short* __restrict__ RJF) {
    __shared__ float srow[H];
    const int p = blockIdx.x, tid = threadIdx.x;
    const int w = widI[p];
    if (tid < 192) {
        const int c0 = tid * 4;
        float4 s = *(const float4*)(T + (size_t)w * H + c0);
#pragma unroll
        for (int kc = 0; kc < 8; ++kc) {
            float4 v = *(const float4*)(RKpart + ((size_t)kc * 512 + p) * H + c0);
            s.x += v.x; s.y += v.y; s.z += v.z; s.w += v.w;
        }
        *(float4*)(RK + (size_t)p * H + c0) = s;
        *(float4*)&srow[c0] = s;
    }
    __syncthreads();
    if (tid < 96) {
        const int k0 = tid * 8;
        const int kt = k0 >> 5, sub = k0 & 31;
        const int lane = (p & 15) | ((sub >> 3) << 4);
        const int t = p >> 4;
        unsigned short* d2 = RJF + ((size_t)(t * 24 + kt) * 64 + lane) * 8;
#pragma unroll
        for (int e = 0; e < 8; ++e) d2[e] = f2bf_rne(srow[k0 + e]);
    }
}

// Wd bf16 B-fragments (10 n-tiles)
__global__ void k_prepw(const float* __restrict__ W1, unsigned short* __restrict__ WF) {
    const int idx = blockIdx.x * 256 + threadIdx.x;
    if (idx >= 10 * 24 * 64) return;
    const int nt = idx / 1536;
    const int rem = idx - nt * 1536;
    const int kt = rem >> 6, lane = rem & 63;
    const int n = nt * 16 + (lane & 15);
    const int kb = kt * 32 + (lane >> 4) * 8;
    unsigned short* dst = WF + (size_t)idx * 8;
#pragma unroll
    for (int e = 0; e < 8; ++e) {
        float v = (n < HIDD) ? W1[(size_t)(3 * H + kb + e) * HIDD + n] : 0.f;
        dst[e] = f2bf_rne(v);
    }
}

// combined UV weights [Wa+Wc | Wb-Wc] bf16 B-fragments (20 n-tiles over 320 cols)
__global__ void k_prepwc(const float* __restrict__ W1, unsigned short* __restrict__ WCF) {
    const int idx = blockIdx.x * 256 + threadIdx.x;
    if (idx >= 20 * 24 * 64) return;
    const int nt = idx / 1536;
    const int rem = idx - nt * 1536;
    const int kt = rem >> 6, lane = rem & 63;
    const int n = nt * 16 + (lane & 15);
    const int kb = kt * 32 + (lane >> 4) * 8;
    unsigned short* dst = WCF + (size_t)idx * 8;
#pragma unroll
    for (int e = 0; e < 8; ++e) {
        const int h = kb + e;
        float v = 0.f;
        if (n < 160) {
            if (n < HIDD)
                v = W1[(size_t)h * HIDD + n] + W1[(size_t)(2 * H + h) * HIDD + n];
        } else {
            const int d = n - 160;
            if (d < HIDD)
                v = W1[(size_t)(H + h) * HIDD + d] - W1[(size_t)(2 * H + h) * HIDD + d];
        }
        dst[e] = f2bf_rne(v);
    }
}

// gw[d]=ln_g*W2 (padded), S_gw, C0
__global__ void k_prepg(const float* __restrict__ ln_g, const float* __restrict__ ln_b,
                        const float* __restrict__ W2, const float* __restrict__ b2,
                        float* __restrict__ GW, float* __restrict__ SCAL) {
    const int tid = threadIdx.x;
    if (tid < NPAD) GW[tid] = (tid < HIDD) ? ln_g[tid] * W2[tid] : 0.f;
    if (tid == 0) {
        float sg = 0.f, sb = 0.f;
        for (int d = 0; d < HIDD; ++d) { sg += ln_g[d] * W2[d]; sb += ln_b[d] * W2[d]; }
        SCAL[0] = sg;
        SCAL[1] = sb + b2[0];
    }
}

// U/V via MFMA on RJF A-frags: 32 blocks (one 16-row tile each), 4 waves x 5 n-tiles
__global__ __launch_bounds__(256) void k_uv3(const unsigned short* __restrict__ RJF,
    const unsigned short* __restrict__ WCF, const float* __restrict__ b1,
    float* __restrict__ U, float* __restrict__ V) {
    const int t = blockIdx.x;
    const int wave = threadIdx.x >> 6, lane = threadIdx.x & 63;
    const unsigned short* Af = RJF + (size_t)t * 24 * 64 * 8;
    f32x4 acc[5];
#pragma unroll
    for (int q = 0; q < 5; ++q) acc[q] = (f32x4){0.f, 0.f, 0.f, 0.f};
    for (int kt = 0; kt < 24; ++kt) {
        bf16x8 a = *(const bf16x8*)(Af + ((size_t)(kt * 64 + lane)) * 8);
#pragma unroll
        for (int q = 0; q < 5; ++q) {
            const int nt = wave * 5 + q;
            bf16x8 bv = *(const bf16x8*)(WCF + ((size_t)((nt * 24 + kt) * 64 + lane)) * 8);
            acc[q] = __builtin_amdgcn_mfma_f32_16x16x32_bf16(a, bv, acc[q], 0, 0, 0);
        }
    }
    const int c = lane & 15, g = lane >> 4;
#pragma unroll
    for (int q = 0; q < 5; ++q) {
        const int n = (wave * 5 + q) * 16 + c;
#pragma unroll
        for (int r = 0; r < 4; ++r) {
            const int p = t * 16 + g * 4 + r;
            float v = acc[q][r];
            if (n < 160) {
                U[(size_t)p * NPAD + n] = v + ((n < HIDD) ? b1[n] : 0.f);
            } else {
                V[(size_t)p * NPAD + (n - 160)] = v;
            }
        }
    }
}

// Pairwise MFMA + fused relu/LN/dot epilogue
__global__ __launch_bounds__(128) void k_pair(
    const unsigned short* __restrict__ RJF, const unsigned short* __restrict__ WF,
    const float* __restrict__ RK, const float* __restrict__ U, const float* __restrict__ V,
    const float* __restrict__ GW, const float* __restrict__ SCAL,
    float* __restrict__ ant) {
    const int b = blockIdx.z, ii = blockIdx.y, j0 = blockIdx.x * 32;
    float* arow = ant + ((size_t)b * TOPK + ii) * TOPK;
    const int tid = threadIdx.x;
    if (j0 >= ii) {
        if (tid < 32) arow[j0 + tid] = 0.f;
        return;
    }
    const int wave = tid >> 6, lane = tid & 63;
    const int jbase = j0 + wave * 16;
    if (jbase >= ii) {
        if (lane < 16) arow[jbase + lane] = 0.f;
        return;
    }
    const int g = lane >> 4, c = lane & 15;
    const int t = b * 8 + (jbase >> 4);
    const unsigned short* Af = RJF + (size_t)t * 24 * 64 * 8;
    const float* Ri = RK + (size_t)(b * TOPK + ii) * H;

    f32x4 acc[10];
#pragma unroll
    for (int nt = 0; nt < 10; ++nt) acc[nt] = (f32x4){0.f, 0.f, 0.f, 0.f};

    for (int kt = 0; kt < 24; ++kt) {
        uint4 rj = *(const uint4*)(Af + ((size_t)(kt * 64 + lane)) * 8);
        const float* rip = Ri + kt * 32 + g * 8;
        float4 ri0 = *(const float4*)rip;
        float4 ri1 = *(const float4*)(rip + 4);
        float p0 = ri0.x * __uint_as_float(rj.x << 16);
        float p1 = ri0.y * __uint_as_float(rj.x & 0xffff0000u);
        float p2 = ri0.z * __uint_as_float(rj.y << 16);
        float p3 = ri0.w * __uint_as_float(rj.y & 0xffff0000u);
        float p4 = ri1.x * __uint_as_float(rj.z << 16);
        float p5 = ri1.y * __uint_as_float(rj.z & 0xffff0000u);
        float p6 = ri1.z * __uint_as_float(rj.w << 16);
        float p7 = ri1.w * __uint_as_float(rj.w & 0xffff0000u);
        bf16x8 a;
        a[0] = (short)f2bf_rne(p0); a[1] = (short)f2bf_rne(p1);
        a[2] = (short)f2bf_rne(p2); a[3] = (short)f2bf_rne(p3);
        a[4] = (short)f2bf_rne(p4); a[5] = (short)f2bf_rne(p5);
        a[6] = (short)f2bf_rne(p6); a[7] = (short)f2bf_rne(p7);
#pragma unroll
        for (int nt = 0; nt < 10; ++nt) {
            bf16x8 bv = *(const bf16x8*)(WF + ((size_t)((nt * 24 + kt) * 64 + lane)) * 8);
            acc[nt] = __builtin_amdgcn_mfma_f32_16x16x32_bf16(a, bv, acc[nt], 0, 0, 0);
        }
    }

    const float* Up = U + (size_t)(b * TOPK + ii) * NPAD;
    float u10[10], gw10[10];
#pragma unroll
    for (int nt = 0; nt < 10; ++nt) {
        const int d = nt * 16 + c;
        u10[nt] = Up[d];
        gw10[nt] = GW[d];
    }
    const float Sgw = SCAL[0], C0 = SCAL[1];
#pragma unroll
    for (int r = 0; r < 4; ++r) {
        const int j = jbase + g * 4 + r;
        const float* Vp = V + (size_t)(b * TOPK + j) * NPAD;
        float s1 = 0.f, s2 = 0.f, s3 = 0.f;
#pragma unroll
        for (int nt = 0; nt < 10; ++nt) {
            const int d = nt * 16 + c;
            float z = acc[nt][r] + u10[nt] + Vp[d];
            float h = (d < HIDD && z > 0.f) ? z : 0.f;
            s1 += h;
            s2 += h * h;
            s3 += h * gw10[nt];
        }
#pragma unroll
        for (int off = 1; off < 16; off <<= 1) {
            s1 += __shfl_xor(s1, off, 64);
            s2 += __shfl_xor(s2, off, 64);
            s3 += __shfl_xor(s3, off, 64);
        }
        const float mu = s1 * (1.f / HIDD);
        const float var = s2 * (1.f / HIDD) - mu * mu;
        const float rstd = rsqrtf(var + 1e-5f);
        const float val = rstd * (s3 - mu * Sgw) + C0;
        if (c == 0) arow[j] = (j < ii) ? val : 0.f;
    }
}

extern "C" void kernel_launch(void* const* d_in, const int* in_sizes, int n_in,
                              void* d_out, int out_size, void* d_ws, size_t ws_size,
                              hipStream_t stream) {
    const float* seq      = (const float*)d_in[0];
    const int*   starts   = (const int*)d_in[1];
    const int*   ends     = (const int*)d_in[2];
    const float* W_start  = (const float*)d_in[3];
    const float* b_start  = (const float*)d_in[4];
    const float* W_end    = (const float*)d_in[5];
    const float* b_end    = (const float*)d_in[6];
    const float* width_e  = (const float*)d_in[7];
    const float* W_out    = (const float*)d_in[8];
    const float* b_out    = (const float*)d_in[9];
    const float* w_ment   = (const float*)d_in[10];
    const float* b_ment   = (const float*)d_in[11];
    const float* W1       = (const float*)d_in[12];
    const float* b1       = (const float*)d_in[13];
    const float* ln_g     = (const float*)d_in[14];
    const float* ln_b     = (const float*)d_in[15];
    const float* W2       = (const float*)d_in[16];
    const float* b2       = (const float*)d_in[17];
    float* out = (float*)d_out;
    float* ws  = (float*)d_ws;

    float* Tt    = ws + OFF_T;
    float* biasP = ws + OFF_BIASP;
    float* WOV   = ws + OFF_WOV;
    float* av    = ws + OFF_AV;
    float* cv    = ws + OFF_CV;
    float* tw    = ws + OFF_TW;
    float* PD    = ws + OFF_PD;
    float* SC    = ws + OFF_SC;
    unsigned long long* CANDp = (unsigned long long*)(ws + OFF_CAND);
    int*   idxb  = (int*)(ws + OFF_IDX);
    int*   fsI   = (int*)(ws + OFF_FS);
    int*   feI   = (int*)(ws + OFF_FE);
    int*   widI  = (int*)(ws + OFF_WID);
    float* RKp   = ws + OFF_RK;
    float* Up    = ws + OFF_U;
    float* Vp    = ws + OFF_V;
    float* GWp   = ws + OFF_GW;
    float* SCALp = ws + OFF_SCAL;
    unsigned short* WFp  = (unsigned short*)(ws + OFF_WF);
    unsigned short* WCFp = (unsigned short*)(ws + OFF_WCF);
    unsigned short* RJFp = (unsigned short*)(ws + OFF_RJF);
    float* SEp   = ws + OFF_SE;
    float* SEPp  = ws + OFF_SEP;   // also RKP (alias; SEP dead after k_reduceSE)

    k_prep_bias<<<dim3(3, 8), 256, 0, stream>>>(b_start, b_end, b_out, W_out, biasP);
    k_prep_T<<<33, 256, 0, stream>>>(biasP, width_e, W_out, Tt);
    k_wvecs<<<384, 256, 0, stream>>>(W_out, w_ment, WOV);
    k_avcv<<<385, 256, 0, stream>>>(W_start, W_end, WOV, Tt, w_ment, b_ment, av, cv, tw);
    k_prepw<<<60, 256, 0, stream>>>(W1, WFp);
    k_prepwc<<<120, 256, 0, stream>>>(W1, WCFp);
    k_prepg<<<1, 256, 0, stream>>>(ln_g, ln_b, W2, b2, GWp, SCALp);
    k_posdots<<<2048, 256, 0, stream>>>(seq, av, cv, PD);
    k_scoregather<<<64, 256, 0, stream>>>(PD, starts, ends, tw, SC);
    k_sort1<<<32, 256, 0, stream>>>(SC, CANDp);
    k_sort2<<<4, 512, 0, stream>>>(CANDp, starts, ends, out, idxb);
    k_gather2<<<2, 256, 0, stream>>>(idxb, starts, ends, fsI, feI, widI);
    k_se<<<dim3(12, 8, 8), 256, 0, stream>>>(seq, fsI, feI, W_start, W_end, SEPp);
    k_reduceSE<<<1024, 192, 0, stream>>>(SEPp, SEp);
    k_rk<<<dim3(12, 8, 8), 256, 0, stream>>>(SEp, W_out, SEPp);
    k_reduce<<<512, 256, 0, stream>>>(SEPp, Tt, widI, RKp, RJFp);
    k_uv3<<<32, 256, 0, stream>>>(RJFp, WCFp, b1, Up, Vp);
    k_pair<<<dim3(4, 128, 4), 128, 0, stream>>>(RJFp, WFp, RKp, Up, Vp, GWp, SCALp,
                                                out + OFS_ANT);
}

// Round 7
// 261.766 us; speedup vs baseline: 6.1995x; 1.0890x over previous
//
#include <hip/hip_runtime.h>
#include <math.h>

#define H 768
#define SEQ 2048
#define NSP 4096
#define HIDD 150
#define TOPK 128
#define NPAD 160

// d_out layout (floats): [0,512) mention_scores | [512,66048) ant | [66048,66560) f_starts | [66560,67072) f_ends
#define OFS_ANT 512
#define OFS_FS 66048
#define OFS_FE 66560

// workspace layout (float offsets) — ~18.9 MB total
static const size_t OFF_T     = 0ull;         // 11*768
static const size_t OFF_BIASP = 8448ull;      // 8*768
static const size_t OFF_WOV   = 14592ull;     // 1536
static const size_t OFF_AV    = 16128ull;     // 768
static const size_t OFF_CV    = 16896ull;     // 768
static const size_t OFF_TW    = 17664ull;     // 16
static const size_t OFF_PD    = 17680ull;     // 2*8192
static const size_t OFF_CAND  = 34064ull;     // 4096 u64 = 8192 f32 (even -> 8B aligned)
static const size_t OFF_FS    = 42256ull;     // 512 ints
static const size_t OFF_FE    = 42768ull;     // 512 ints
static const size_t OFF_WID   = 43280ull;     // 512 ints
static const size_t OFF_U     = 43792ull;     // 512*160
static const size_t OFF_V     = 125712ull;    // 512*160
static const size_t OFF_GW    = 207632ull;    // 160
static const size_t OFF_SCAL  = 207792ull;    // 8
static const size_t OFF_WF    = 207800ull;    // 10*24*64*8 f16 = 61440 f32 slots
static const size_t OFF_WCF   = 269240ull;    // 20*24*64*8 f16 = 122880 f32 slots
static const size_t OFF_RJF   = 392120ull;    // 512*768 f16 = 196608 f32 slots (A-frags)
static const size_t OFF_RKH   = 588728ull;    // 512*768 f16 row-major
static const size_t OFF_SE    = 785336ull;    // 2*512*768 f32
static const size_t OFF_SEP   = 1571768ull;   // 8*512*768 f32 partials (reused as RKP)

typedef __attribute__((ext_vector_type(8))) _Float16 half8;
typedef __attribute__((ext_vector_type(4))) float f32x4;

// ============ kA: independent preps (589 blocks) ============
// blk 0..23: bias partials | 24..407: WOV matvecs | 408..467: WF f16 frags
// blk 468..587: WCF f16 frags | 588: GW/SCAL
__global__ __launch_bounds__(256) void kA(
    const float* __restrict__ b_start, const float* __restrict__ b_end,
    const float* __restrict__ b_out, const float* __restrict__ W_out,
    const float* __restrict__ w_ment, const float* __restrict__ W1,
    const float* __restrict__ ln_g, const float* __restrict__ ln_b,
    const float* __restrict__ W2, const float* __restrict__ b2,
    float* __restrict__ biasP, float* __restrict__ WOV,
    _Float16* __restrict__ WF, _Float16* __restrict__ WCF,
    float* __restrict__ GW, float* __restrict__ SCAL) {
    const int blk = blockIdx.x, tid = threadIdx.x;
    if (blk < 24) {
        const int kc = blk / 3, jb = blk - kc * 3;
        const int j = jb * 256 + tid;
        float acc = (kc == 0) ? b_out[j] : 0.f;
        const int k0 = kc * 96;
#pragma unroll 4
        for (int k = k0; k < k0 + 96; ++k) {
            acc += b_start[k] * W_out[(size_t)k * H + j];
            acc += b_end[k]   * W_out[(size_t)(H + k) * H + j];
        }
        biasP[kc * H + j] = acc;
    } else if (blk < 408) {
        const int wid = tid >> 6, lane = tid & 63;
        const int gr = (blk - 24) * 4 + wid;
        const float* row = W_out + (size_t)gr * H;
        float s = 0.f;
#pragma unroll
        for (int q = 0; q < 12; ++q) s += row[lane + 64 * q] * w_ment[lane + 64 * q];
#pragma unroll
        for (int off = 32; off; off >>= 1) s += __shfl_down(s, off, 64);
        if (lane == 0) WOV[gr] = s;
    } else if (blk < 468) {
        const int idx = (blk - 408) * 256 + tid;   // < 15360
        const int nt = idx / 1536;
        const int rem = idx - nt * 1536;
        const int kt = rem >> 6, lane = rem & 63;
        const int n = nt * 16 + (lane & 15);
        const int kb = kt * 32 + (lane >> 4) * 8;
        _Float16* dst = WF + (size_t)idx * 8;
#pragma unroll
        for (int e = 0; e < 8; ++e) {
            float v = (n < HIDD) ? W1[(size_t)(3 * H + kb + e) * HIDD + n] : 0.f;
            dst[e] = (_Float16)v;
        }
    } else if (blk < 588) {
        const int idx = (blk - 468) * 256 + tid;   // < 30720
        const int nt = idx / 1536;
        const int rem = idx - nt * 1536;
        const int kt = rem >> 6, lane = rem & 63;
        const int n = nt * 16 + (lane & 15);
        const int kb = kt * 32 + (lane >> 4) * 8;
        _Float16* dst = WCF + (size_t)idx * 8;
#pragma unroll
        for (int e = 0; e < 8; ++e) {
            const int h = kb + e;
            float v = 0.f;
            if (n < 160) {
                if (n < HIDD)
                    v = W1[(size_t)h * HIDD + n] + W1[(size_t)(2 * H + h) * HIDD + n];
            } else {
                const int d = n - 160;
                if (d < HIDD)
                    v = W1[(size_t)(H + h) * HIDD + d] - W1[(size_t)(2 * H + h) * HIDD + d];
            }
            dst[e] = (_Float16)v;
        }
    } else {
        if (tid < NPAD) GW[tid] = (tid < HIDD) ? ln_g[tid] * W2[tid] : 0.f;
        if (tid == 0) {
            float sg = 0.f, sb = 0.f;
            for (int d = 0; d < HIDD; ++d) { sg += ln_g[d] * W2[d]; sb += ln_b[d] * W2[d]; }
            SCAL[0] = sg;
            SCAL[1] = sb + b2[0];
        }
    }
}

// ============ kB: T table + av/cv (417 blocks) ============
// blk 0..32: T[w][j] | blk 33..416: av/cv matvecs
__global__ __launch_bounds__(256) void kB(
    const float* __restrict__ biasP, const float* __restrict__ width_emb,
    const float* __restrict__ W_out, const float* __restrict__ W_start,
    const float* __restrict__ W_end, const float* __restrict__ WOV,
    float* __restrict__ T, float* __restrict__ av, float* __restrict__ cv) {
    const int blk = blockIdx.x, tid = threadIdx.x;
    if (blk < 33) {
        const int w = blk / 3, jb = blk - w * 3;
        const int j = jb * 256 + tid;
        float acc = 0.f;
#pragma unroll
        for (int kc = 0; kc < 8; ++kc) acc += biasP[kc * H + j];
#pragma unroll
        for (int k = 0; k < 30; ++k)
            acc += width_emb[w * 30 + k] * W_out[(size_t)(2 * H + k) * H + j];
        T[w * H + j] = acc;
    } else {
        const int wid = tid >> 6, lane = tid & 63;
        const int gr = (blk - 33) * 4 + wid;
        const float* row = (gr < H) ? (W_start + (size_t)gr * H) : (W_end + (size_t)(gr - H) * H);
        const float* vec = (gr < H) ? WOV : (WOV + H);
        float s = 0.f;
#pragma unroll
        for (int q = 0; q < 12; ++q) s += row[lane + 64 * q] * vec[lane + 64 * q];
#pragma unroll
        for (int off = 32; off; off >>= 1) s += __shfl_down(s, off, 64);
        if (lane == 0) {
            if (gr < H) av[gr] = s; else cv[gr - H] = s;
        }
    }
}

// position dots + tw (block 2048)
__global__ void k_posdots(const float* __restrict__ seq, const float* __restrict__ av,
                          const float* __restrict__ cv, const float* __restrict__ T,
                          const float* __restrict__ w_ment, const float* __restrict__ b_ment,
                          float* __restrict__ PD, float* __restrict__ tw) {
    const int wid = threadIdx.x >> 6, lane = threadIdx.x & 63;
    if (blockIdx.x < 2048) {
        const int r = blockIdx.x * 4 + wid;
        const float4* row = (const float4*)(seq + (size_t)r * H);
        const float4* a4 = (const float4*)av;
        const float4* c4 = (const float4*)cv;
        float sa = 0.f, sc = 0.f;
#pragma unroll
        for (int q = 0; q < 3; ++q) {
            float4 x = row[lane + 64 * q];
            float4 ya = a4[lane + 64 * q], yc = c4[lane + 64 * q];
            sa += x.x * ya.x + x.y * ya.y + x.z * ya.z + x.w * ya.w;
            sc += x.x * yc.x + x.y * yc.y + x.z * yc.z + x.w * yc.w;
        }
#pragma unroll
        for (int off = 32; off; off >>= 1) {
            sa += __shfl_down(sa, off, 64);
            sc += __shfl_down(sc, off, 64);
        }
        if (lane == 0) { PD[r] = sa; PD[8192 + r] = sc; }
    } else {
        for (int w = wid; w <= 10; w += 4) {
            float s = 0.f;
#pragma unroll
            for (int q = 0; q < 12; ++q) s += T[w * H + lane + 64 * q] * w_ment[lane + 64 * q];
#pragma unroll
            for (int off = 32; off; off >>= 1) s += __shfl_down(s, off, 64);
            if (lane == 0) tw[w] = s + b_ment[0];
        }
    }
}

// stage 1 sort (scores computed inline from PD): 32 blocks, 512-chunk each, top-128 out
__global__ __launch_bounds__(256) void k_sort1(const float* __restrict__ PD,
    const int* __restrict__ starts, const int* __restrict__ ends,
    const float* __restrict__ tw, unsigned long long* __restrict__ CAND) {
    __shared__ unsigned long long keys[512];
    const int blk = blockIdx.x;
    const int b = blk >> 3, c = blk & 7;
    const int tid = threadIdx.x;
    for (int i = tid; i < 512; i += 256) {
        const int gi = c * 512 + i;
        const int r = b * NSP + gi;
        const int s = starts[r], e = ends[r];
        int w = e - s; w = w < 0 ? 0 : (w > 10 ? 10 : w);
        const float sc = PD[b * SEQ + s] + PD[8192 + b * SEQ + e] + tw[w];
        unsigned u = __float_as_uint(sc);
        u = (u & 0x80000000u) ? ~u : (u | 0x80000000u);
        keys[i] = ((unsigned long long)u << 32) | (unsigned)(0xFFFFFFFFu - (unsigned)gi);
    }
    __syncthreads();
    for (int k = 2; k <= 512; k <<= 1) {
        for (int j = k >> 1; j > 0; j >>= 1) {
            const int p = tid;
            const int i = ((p & ~(j - 1)) << 1) | (p & (j - 1));
            const int l = i | j;
            unsigned long long a = keys[i], d = keys[l];
            const bool desc = ((i & k) == 0);
            if ((a < d) == desc) { keys[i] = d; keys[l] = a; }
            __syncthreads();
        }
    }
    if (tid < 128) CAND[(size_t)(b * 8 + c) * 128 + tid] = keys[tid];
}

// stage 2: sort 1024 candidates; emit outputs + fsI/feI/widI
__global__ __launch_bounds__(512) void k_sort2(const unsigned long long* __restrict__ CAND,
    const int* __restrict__ starts, const int* __restrict__ ends,
    float* __restrict__ out, int* __restrict__ fsI, int* __restrict__ feI,
    int* __restrict__ widI) {
    __shared__ unsigned long long keys[1024];
    const int b = blockIdx.x;
    const int tid = threadIdx.x;
    for (int i = tid; i < 1024; i += 512) keys[i] = CAND[(size_t)b * 1024 + i];
    __syncthreads();
    for (int k = 2; k <= 1024; k <<= 1) {
        for (int j = k >> 1; j > 0; j >>= 1) {
            const int p = tid;
            const int i = ((p & ~(j - 1)) << 1) | (p & (j - 1));
            const int l = i | j;
            unsigned long long a = keys[i], d = keys[l];
            const bool desc = ((i & k) == 0);
            if ((a < d) == desc) { keys[i] = d; keys[l] = a; }
            __syncthreads();
        }
    }
    if (tid < TOPK) {
        const unsigned long long key = keys[tid];
        const int widx = (int)(0xFFFFFFFFu - (unsigned)(key & 0xFFFFFFFFu));
        const unsigned hu = (unsigned)(key >> 32);
        const float sval = __uint_as_float((hu & 0x80000000u) ? (hu & 0x7FFFFFFFu) : ~hu);
        const int s = starts[b * NSP + widx], e = ends[b * NSP + widx];
        const int p = b * TOPK + tid;
        out[p] = sval;
        out[OFS_FS + p] = (float)s;
        out[OFS_FE + p] = (float)e;
        fsI[p] = b * SEQ + s;
        feI[p] = b * SEQ + e;
        int w = e - s;
        widI[p] = w < 0 ? 0 : (w > 10 ? 10 : w);
    }
}

// SEP[z] = gathered seq rows @ W chunk.  z: which=z>>2, kc=z&3
__global__ __launch_bounds__(256) void k_se(const float* __restrict__ seq,
    const int* __restrict__ fsI, const int* __restrict__ feI,
    const float* __restrict__ W_start, const float* __restrict__ W_end,
    float* __restrict__ SEP) {
    __shared__ float sA[16][68];
    __shared__ float sB[16][68];
    __shared__ int sRow[64];
    const int tid = threadIdx.x;
    const int n0 = blockIdx.x * 64, m0 = blockIdx.y * 64, z = blockIdx.z;
    const int which = z >> 2;
    const int kbase = (z & 3) * 192;
    const int* rsrc = which ? feI : fsI;
    if (tid < 64) sRow[tid] = rsrc[m0 + tid];
    __syncthreads();
    const float* W = which ? W_end : W_start;
    const int tr = tid >> 4, tc = tid & 15;
    const int rr = tid >> 2, kg = (tid & 3) * 4;
    const int kb = tid >> 4, jc = (tid & 15) * 4;
    float acc[4][4];
#pragma unroll
    for (int i = 0; i < 4; ++i)
#pragma unroll
        for (int j = 0; j < 4; ++j) acc[i][j] = 0.f;
    for (int k0 = kbase; k0 < kbase + 192; k0 += 16) {
        float4 va = *(const float4*)(seq + (size_t)sRow[rr] * H + k0 + kg);
        float4 vb = *(const float4*)(W + (size_t)(k0 + kb) * H + n0 + jc);
        sA[kg + 0][rr] = va.x; sA[kg + 1][rr] = va.y;
        sA[kg + 2][rr] = va.z; sA[kg + 3][rr] = va.w;
        *(float4*)&sB[kb][jc] = vb;
        __syncthreads();
#pragma unroll
        for (int kk = 0; kk < 16; ++kk) {
            float a[4], b[4];
            *(float4*)a = *(const float4*)&sA[kk][tr * 4];
            *(float4*)b = *(const float4*)&sB[kk][tc * 4];
#pragma unroll
            for (int i = 0; i < 4; ++i)
#pragma unroll
                for (int j = 0; j < 4; ++j) acc[i][j] += a[i] * b[j];
        }
        __syncthreads();
    }
    float* dst = SEP + (size_t)z * 512 * H;
#pragma unroll
    for (int i = 0; i < 4; ++i) {
        float4 o = make_float4(acc[i][0], acc[i][1], acc[i][2], acc[i][3]);
        *(float4*)(dst + (size_t)(m0 + tr * 4 + i) * H + n0 + tc * 4) = o;
    }
}

// SE[p] = sum of 4 K-chunk partials
__global__ void k_reduceSE(const float* __restrict__ SEP, float* __restrict__ SE) {
    const int p = blockIdx.x, tid = threadIdx.x;
    if (tid >= 192) return;
    const int which = p >> 9, row = p & 511;
    const int c0 = tid * 4;
    float4 s = make_float4(0.f, 0.f, 0.f, 0.f);
#pragma unroll
    for (int kc = 0; kc < 4; ++kc) {
        float4 v = *(const float4*)(SEP + ((size_t)((which << 2) | kc) * 512 + row) * H + c0);
        s.x += v.x; s.y += v.y; s.z += v.z; s.w += v.w;
    }
    *(float4*)(SE + (size_t)p * H + c0) = s;
}

// RKP[z] = SE-half @ W_out chunk
__global__ __launch_bounds__(256) void k_rk(const float* __restrict__ SE,
    const float* __restrict__ W_out, float* __restrict__ RKP) {
    __shared__ float sA[16][68];
    __shared__ float sB[16][68];
    const int tid = threadIdx.x;
    const int n0 = blockIdx.x * 64, m0 = blockIdx.y * 64, z = blockIdx.z;
    const int ph = z >> 2;
    const int kbase = (z & 3) * 192;
    const float* A = SE + (size_t)ph * 512 * H;
    const float* B = W_out + (size_t)ph * H * H;
    const int tr = tid >> 4, tc = tid & 15;
    const int rr = tid >> 2, kg = (tid & 3) * 4;
    const int kb = tid >> 4, jc = (tid & 15) * 4;
    float acc[4][4];
#pragma unroll
    for (int i = 0; i < 4; ++i)
#pragma unroll
        for (int j = 0; j < 4; ++j) acc[i][j] = 0.f;
    for (int k0 = kbase; k0 < kbase + 192; k0 += 16) {
        float4 va = *(const float4*)(A + (size_t)(m0 + rr) * H + k0 + kg);
        float4 vb = *(const float4*)(B + (size_t)(k0 + kb) * H + n0 + jc);
        sA[kg + 0][rr] = va.x; sA[kg + 1][rr] = va.y;
        sA[kg + 2][rr] = va.z; sA[kg + 3][rr] = va.w;
        *(float4*)&sB[kb][jc] = vb;
        __syncthreads();
#pragma unroll
        for (int kk = 0; kk < 16; ++kk) {
            float a[4], b[4];
            *(float4*)a = *(const float4*)&sA[kk][tr * 4];
            *(float4*)b = *(const float4*)&sB[kk][tc * 4];
#pragma unroll
            for (int i = 0; i < 4; ++i)
#pragma unroll
                for (int j = 0; j < 4; ++j) acc[i][j] += a[i] * b[j];
        }
        __syncthreads();
    }
    float* dst = RKP + (size_t)z * 512 * H;
#pragma unroll
    for (int i = 0; i < 4; ++i) {
        float4 o = make_float4(acc[i][0], acc[i][1], acc[i][2], acc[i][3]);
        *(float4*)(dst + (size_t)(m0 + tr * 4 + i) * H + n0 + tc * 4) = o;
    }
}

// reduce 8 partials + T[width] -> RKH (f16 rows) + RJF (f16 A-frags)
__global__ __launch_bounds__(256) void k_reduce(const float* __restrict__ RKpart,
    const float* __restrict__ T, const int* __restrict__ widI,
    _Float16* __restrict__ RKH, _Float16* __restrict__ RJF) {
    __shared__ float srow[H];
    const int p = blockIdx.x, tid = threadIdx.x;
    const int w = widI[p];
    if (tid < 192) {
        const int c0 = tid * 4;
        float4 s = *(const float4*)(T + (size_t)w * H + c0);
#pragma unroll
        for (int kc = 0; kc < 8; ++kc) {
            float4 v = *(const float4*)(RKpart + ((size_t)kc * 512 + p) * H + c0);
            s.x += v.x; s.y += v.y; s.z += v.z; s.w += v.w;
        }
        *(float4*)&srow[c0] = s;
        _Float16* hd = RKH + (size_t)p * H + c0;
        hd[0] = (_Float16)s.x; hd[1] = (_Float16)s.y;
        hd[2] = (_Float16)s.z; hd[3] = (_Float16)s.w;
    }
    __syncthreads();
    if (tid < 96) {
        const int k0 = tid * 8;
        const int kt = k0 >> 5, sub = k0 & 31;
        const int lane = (p & 15) | ((sub >> 3) << 4);
        const int t = p >> 4;
        _Float16* d2 = RJF + ((size_t)(t * 24 + kt) * 64 + lane) * 8;
#pragma unroll
        for (int e = 0; e < 8; ++e) d2[e] = (_Float16)srow[k0 + e];
    }
}

// U/V via f16 MFMA on RJF A-frags: 32 blocks, 4 waves x 5 n-tiles
__global__ __launch_bounds__(256) void k_uv3(const _Float16* __restrict__ RJF,
    const _Float16* __restrict__ WCF, const float* __restrict__ b1,
    float* __restrict__ U, float* __restrict__ V) {
    const int t = blockIdx.x;
    const int wave = threadIdx.x >> 6, lane = threadIdx.x & 63;
    const _Float16* Af = RJF + (size_t)t * 24 * 64 * 8;
    f32x4 acc[5];
#pragma unroll
    for (int q = 0; q < 5; ++q) acc[q] = (f32x4){0.f, 0.f, 0.f, 0.f};
    for (int kt = 0; kt < 24; ++kt) {
        half8 a = *(const half8*)(Af + ((size_t)(kt * 64 + lane)) * 8);
#pragma unroll
        for (int q = 0; q < 5; ++q) {
            const int nt = wave * 5 + q;
            half8 bv = *(const half8*)(WCF + ((size_t)((nt * 24 + kt) * 64 + lane)) * 8);
            acc[q] = __builtin_amdgcn_mfma_f32_16x16x32_f16(a, bv, acc[q], 0, 0, 0);
        }
    }
    const int c = lane & 15, g = lane >> 4;
#pragma unroll
    for (int q = 0; q < 5; ++q) {
        const int n = (wave * 5 + q) * 16 + c;
#pragma unroll
        for (int r = 0; r < 4; ++r) {
            const int p = t * 16 + g * 4 + r;
            float v = acc[q][r];
            if (n < 160) {
                U[(size_t)p * NPAD + n] = v + ((n < HIDD) ? b1[n] : 0.f);
            } else {
                V[(size_t)p * NPAD + (n - 160)] = v;
            }
        }
    }
}

// Pairwise f16 MFMA + fused relu/LN/dot epilogue.
// A-frag = RiH(f16, packed pairs) * RJF(f16, frag-major) via v_pk_mul_f16.
__global__ __launch_bounds__(128) void k_pair(
    const _Float16* __restrict__ RJF, const _Float16* __restrict__ WF,
    const _Float16* __restrict__ RKH, const float* __restrict__ U,
    const float* __restrict__ V, const float* __restrict__ GW,
    const float* __restrict__ SCAL, float* __restrict__ ant) {
    const int b = blockIdx.z, ii = blockIdx.y, j0 = blockIdx.x * 32;
    float* arow = ant + ((size_t)b * TOPK + ii) * TOPK;
    const int tid = threadIdx.x;
    if (j0 >= ii) {
        if (tid < 32) arow[j0 + tid] = 0.f;
        return;
    }
    const int wave = tid >> 6, lane = tid & 63;
    const int jbase = j0 + wave * 16;
    if (jbase >= ii) {
        if (lane < 16) arow[jbase + lane] = 0.f;
        return;
    }
    const int g = lane >> 4, c = lane & 15;
    const int t = b * 8 + (jbase >> 4);
    const _Float16* Af = RJF + (size_t)t * 24 * 64 * 8;
    const _Float16* RiH = RKH + (size_t)(b * TOPK + ii) * H;

    f32x4 acc[10];
#pragma unroll
    for (int nt = 0; nt < 10; ++nt) acc[nt] = (f32x4){0.f, 0.f, 0.f, 0.f};

    for (int kt = 0; kt < 24; ++kt) {
        half8 rj = *(const half8*)(Af + ((size_t)(kt * 64 + lane)) * 8);
        half8 ri = *(const half8*)(RiH + kt * 32 + g * 8);
        half8 a = ri * rj;   // 4x v_pk_mul_f16
#pragma unroll
        for (int nt = 0; nt < 10; ++nt) {
            half8 bv = *(const half8*)(WF + ((size_t)((nt * 24 + kt) * 64 + lane)) * 8);
            acc[nt] = __builtin_amdgcn_mfma_f32_16x16x32_f16(a, bv, acc[nt], 0, 0, 0);
        }
    }

    const float* Up = U + (size_t)(b * TOPK + ii) * NPAD;
    float u10[10], gw10[10];
#pragma unroll
    for (int nt = 0; nt < 10; ++nt) {
        const int d = nt * 16 + c;
        u10[nt] = Up[d];
        gw10[nt] = GW[d];
    }
    const float Sgw = SCAL[0], C0 = SCAL[1];
#pragma unroll
    for (int r = 0; r < 4; ++r) {
        const int j = jbase + g * 4 + r;
        const float* Vp = V + (size_t)(b * TOPK + j) * NPAD;
        float s1 = 0.f, s2 = 0.f, s3 = 0.f;
#pragma unroll
        for (int nt = 0; nt < 10; ++nt) {
            const int d = nt * 16 + c;
            float z = acc[nt][r] + u10[nt] + Vp[d];
            float h = (d < HIDD && z > 0.f) ? z : 0.f;
            s1 += h;
            s2 += h * h;
            s3 += h * gw10[nt];
        }
#pragma unroll
        for (int off = 1; off < 16; off <<= 1) {
            s1 += __shfl_xor(s1, off, 64);
            s2 += __shfl_xor(s2, off, 64);
            s3 += __shfl_xor(s3, off, 64);
        }
        const float mu = s1 * (1.f / HIDD);
        const float var = s2 * (1.f / HIDD) - mu * mu;
        const float rstd = rsqrtf(var + 1e-5f);
        const float val = rstd * (s3 - mu * Sgw) + C0;
        if (c == 0) arow[j] = (j < ii) ? val : 0.f;
    }
}

extern "C" void kernel_launch(void* const* d_in, const int* in_sizes, int n_in,
                              void* d_out, int out_size, void* d_ws, size_t ws_size,
                              hipStream_t stream) {
    const float* seq      = (const float*)d_in[0];
    const int*   starts   = (const int*)d_in[1];
    const int*   ends     = (const int*)d_in[2];
    const float* W_start  = (const float*)d_in[3];
    const float* b_start  = (const float*)d_in[4];
    const float* W_end    = (const float*)d_in[5];
    const float* b_end    = (const float*)d_in[6];
    const float* width_e  = (const float*)d_in[7];
    const float* W_out    = (const float*)d_in[8];
    const float* b_out    = (const float*)d_in[9];
    const float* w_ment   = (const float*)d_in[10];
    const float* b_ment   = (const float*)d_in[11];
    const float* W1       = (const float*)d_in[12];
    const float* b1       = (const float*)d_in[13];
    const float* ln_g     = (const float*)d_in[14];
    const float* ln_b     = (const float*)d_in[15];
    const float* W2       = (const float*)d_in[16];
    const float* b2       = (const float*)d_in[17];
    float* out = (float*)d_out;
    float* ws  = (float*)d_ws;

    float* Tt    = ws + OFF_T;
    float* biasP = ws + OFF_BIASP;
    float* WOV   = ws + OFF_WOV;
    float* av    = ws + OFF_AV;
    float* cv    = ws + OFF_CV;
    float* tw    = ws + OFF_TW;
    float* PD    = ws + OFF_PD;
    unsigned long long* CANDp = (unsigned long long*)(ws + OFF_CAND);
    int*   fsI   = (int*)(ws + OFF_FS);
    int*   feI   = (int*)(ws + OFF_FE);
    int*   widI  = (int*)(ws + OFF_WID);
    float* Up    = ws + OFF_U;
    float* Vp    = ws + OFF_V;
    float* GWp   = ws + OFF_GW;
    float* SCALp = ws + OFF_SCAL;
    _Float16* WFp  = (_Float16*)(ws + OFF_WF);
    _Float16* WCFp = (_Float16*)(ws + OFF_WCF);
    _Float16* RJFp = (_Float16*)(ws + OFF_RJF);
    _Float16* RKHp = (_Float16*)(ws + OFF_RKH);
    float* SEp   = ws + OFF_SE;
    float* SEPp  = ws + OFF_SEP;

    kA<<<589, 256, 0, stream>>>(b_start, b_end, b_out, W_out, w_ment, W1,
                                ln_g, ln_b, W2, b2, biasP, WOV, WFp, WCFp, GWp, SCALp);
    kB<<<417, 256, 0, stream>>>(biasP, width_e, W_out, W_start, W_end, WOV, Tt, av, cv);
    k_posdots<<<2049, 256, 0, stream>>>(seq, av, cv, Tt, w_ment, b_ment, PD, tw);
    k_sort1<<<32, 256, 0, stream>>>(PD, starts, ends, tw, CANDp);
    k_sort2<<<4, 512, 0, stream>>>(CANDp, starts, ends, out, fsI, feI, widI);
    k_se<<<dim3(12, 8, 8), 256, 0, stream>>>(seq, fsI, feI, W_start, W_end, SEPp);
    k_reduceSE<<<1024, 192, 0, stream>>>(SEPp, SEp);
    k_rk<<<dim3(12, 8, 8), 256, 0, stream>>>(SEp, W_out, SEPp);
    k_reduce<<<512, 256, 0, stream>>>(SEPp, Tt, widI, RKHp, RJFp);
    k_uv3<<<32, 256, 0, stream>>>(RJFp, WCFp, b1, Up, Vp);
    k_pair<<<dim3(4, 128, 4), 128, 0, stream>>>(RJFp, WFp, RKHp, Up, Vp, GWp, SCALp,
                                                out + OFS_ANT);
}

// Round 8
// 237.473 us; speedup vs baseline: 6.8337x; 1.1023x over previous
//
#include <hip/hip_runtime.h>
#include <math.h>

#define H 768
#define SEQ 2048
#define NSP 4096
#define HIDD 150
#define TOPK 128
#define NPAD 160

// d_out layout (floats): [0,512) mention_scores | [512,66048) ant | [66048,66560) f_starts | [66560,67072) f_ends
#define OFS_ANT 512
#define OFS_FS 66048
#define OFS_FE 66560

// workspace layout (float offsets)
static const size_t OFF_T     = 0ull;         // 11*768
static const size_t OFF_BIASP = 8448ull;      // 8*768
static const size_t OFF_WOV   = 14592ull;     // 1536
static const size_t OFF_AV    = 16128ull;     // 768
static const size_t OFF_CV    = 16896ull;     // 768
static const size_t OFF_TW    = 17664ull;     // 16
static const size_t OFF_PD    = 17680ull;     // 2*8192
static const size_t OFF_CAND  = 34064ull;     // 4096 u64 = 8192 f32 (even -> 8B aligned)
static const size_t OFF_FS    = 42256ull;     // 512 ints
static const size_t OFF_FE    = 42768ull;     // 512 ints
static const size_t OFF_WID   = 43280ull;     // 512 ints
static const size_t OFF_UVP   = 43792ull;     // 2*512*320 f32 (K-split U|V partials)
static const size_t OFF_GW    = 371472ull;    // 160
static const size_t OFF_SCAL  = 371632ull;    // 8
static const size_t OFF_WF    = 371640ull;    // 10*24*64*8 f16 = 61440 f32 slots
static const size_t OFF_WCF   = 433080ull;    // 20*24*64*8 f16 = 122880 f32 slots
static const size_t OFF_RJF   = 555960ull;    // 512*768 f16 = 196608 f32 slots (A-frags)
static const size_t OFF_RKH   = 752568ull;    // 512*768 f16 row-major
static const size_t OFF_SE    = 949176ull;    // 2*512*768 f32
static const size_t OFF_SEP   = 1735608ull;   // 8*512*768 f32 partials

typedef __attribute__((ext_vector_type(8))) _Float16 half8;
typedef __attribute__((ext_vector_type(4))) float f32x4;

// ============ kA: independent preps (589 blocks) ============
__global__ __launch_bounds__(256) void kA(
    const float* __restrict__ b_start, const float* __restrict__ b_end,
    const float* __restrict__ b_out, const float* __restrict__ W_out,
    const float* __restrict__ w_ment, const float* __restrict__ W1,
    const float* __restrict__ ln_g, const float* __restrict__ ln_b,
    const float* __restrict__ W2, const float* __restrict__ b2,
    float* __restrict__ biasP, float* __restrict__ WOV,
    _Float16* __restrict__ WF, _Float16* __restrict__ WCF,
    float* __restrict__ GW, float* __restrict__ SCAL) {
    const int blk = blockIdx.x, tid = threadIdx.x;
    if (blk < 24) {
        const int kc = blk / 3, jb = blk - kc * 3;
        const int j = jb * 256 + tid;
        float acc = (kc == 0) ? b_out[j] : 0.f;
        const int k0 = kc * 96;
#pragma unroll 4
        for (int k = k0; k < k0 + 96; ++k) {
            acc += b_start[k] * W_out[(size_t)k * H + j];
            acc += b_end[k]   * W_out[(size_t)(H + k) * H + j];
        }
        biasP[kc * H + j] = acc;
    } else if (blk < 408) {
        const int wid = tid >> 6, lane = tid & 63;
        const int gr = (blk - 24) * 4 + wid;
        const float* row = W_out + (size_t)gr * H;
        float s = 0.f;
#pragma unroll
        for (int q = 0; q < 12; ++q) s += row[lane + 64 * q] * w_ment[lane + 64 * q];
#pragma unroll
        for (int off = 32; off; off >>= 1) s += __shfl_down(s, off, 64);
        if (lane == 0) WOV[gr] = s;
    } else if (blk < 468) {
        const int idx = (blk - 408) * 256 + tid;
        const int nt = idx / 1536;
        const int rem = idx - nt * 1536;
        const int kt = rem >> 6, lane = rem & 63;
        const int n = nt * 16 + (lane & 15);
        const int kb = kt * 32 + (lane >> 4) * 8;
        _Float16* dst = WF + (size_t)idx * 8;
#pragma unroll
        for (int e = 0; e < 8; ++e) {
            float v = (n < HIDD) ? W1[(size_t)(3 * H + kb + e) * HIDD + n] : 0.f;
            dst[e] = (_Float16)v;
        }
    } else if (blk < 588) {
        const int idx = (blk - 468) * 256 + tid;
        const int nt = idx / 1536;
        const int rem = idx - nt * 1536;
        const int kt = rem >> 6, lane = rem & 63;
        const int n = nt * 16 + (lane & 15);
        const int kb = kt * 32 + (lane >> 4) * 8;
        _Float16* dst = WCF + (size_t)idx * 8;
#pragma unroll
        for (int e = 0; e < 8; ++e) {
            const int h = kb + e;
            float v = 0.f;
            if (n < 160) {
                if (n < HIDD)
                    v = W1[(size_t)h * HIDD + n] + W1[(size_t)(2 * H + h) * HIDD + n];
            } else {
                const int d = n - 160;
                if (d < HIDD)
                    v = W1[(size_t)(H + h) * HIDD + d] - W1[(size_t)(2 * H + h) * HIDD + d];
            }
            dst[e] = (_Float16)v;
        }
    } else {
        if (tid < NPAD) GW[tid] = (tid < HIDD) ? ln_g[tid] * W2[tid] : 0.f;
        if (tid == 0) {
            float sg = 0.f, sb = 0.f;
            for (int d = 0; d < HIDD; ++d) { sg += ln_g[d] * W2[d]; sb += ln_b[d] * W2[d]; }
            SCAL[0] = sg;
            SCAL[1] = sb + b2[0];
        }
    }
}

// ============ kB: T table + av/cv (417 blocks) ============
__global__ __launch_bounds__(256) void kB(
    const float* __restrict__ biasP, const float* __restrict__ width_emb,
    const float* __restrict__ W_out, const float* __restrict__ W_start,
    const float* __restrict__ W_end, const float* __restrict__ WOV,
    float* __restrict__ T, float* __restrict__ av, float* __restrict__ cv) {
    const int blk = blockIdx.x, tid = threadIdx.x;
    if (blk < 33) {
        const int w = blk / 3, jb = blk - w * 3;
        const int j = jb * 256 + tid;
        float acc = 0.f;
#pragma unroll
        for (int kc = 0; kc < 8; ++kc) acc += biasP[kc * H + j];
#pragma unroll
        for (int k = 0; k < 30; ++k)
            acc += width_emb[w * 30 + k] * W_out[(size_t)(2 * H + k) * H + j];
        T[w * H + j] = acc;
    } else {
        const int wid = tid >> 6, lane = tid & 63;
        const int gr = (blk - 33) * 4 + wid;
        const float* row = (gr < H) ? (W_start + (size_t)gr * H) : (W_end + (size_t)(gr - H) * H);
        const float* vec = (gr < H) ? WOV : (WOV + H);
        float s = 0.f;
#pragma unroll
        for (int q = 0; q < 12; ++q) s += row[lane + 64 * q] * vec[lane + 64 * q];
#pragma unroll
        for (int off = 32; off; off >>= 1) s += __shfl_down(s, off, 64);
        if (lane == 0) {
            if (gr < H) av[gr] = s; else cv[gr - H] = s;
        }
    }
}

// position dots + tw
__global__ void k_posdots(const float* __restrict__ seq, const float* __restrict__ av,
                          const float* __restrict__ cv, const float* __restrict__ T,
                          const float* __restrict__ w_ment, const float* __restrict__ b_ment,
                          float* __restrict__ PD, float* __restrict__ tw) {
    const int wid = threadIdx.x >> 6, lane = threadIdx.x & 63;
    if (blockIdx.x < 2048) {
        const int r = blockIdx.x * 4 + wid;
        const float4* row = (const float4*)(seq + (size_t)r * H);
        const float4* a4 = (const float4*)av;
        const float4* c4 = (const float4*)cv;
        float sa = 0.f, sc = 0.f;
#pragma unroll
        for (int q = 0; q < 3; ++q) {
            float4 x = row[lane + 64 * q];
            float4 ya = a4[lane + 64 * q], yc = c4[lane + 64 * q];
            sa += x.x * ya.x + x.y * ya.y + x.z * ya.z + x.w * ya.w;
            sc += x.x * yc.x + x.y * yc.y + x.z * yc.z + x.w * yc.w;
        }
#pragma unroll
        for (int off = 32; off; off >>= 1) {
            sa += __shfl_down(sa, off, 64);
            sc += __shfl_down(sc, off, 64);
        }
        if (lane == 0) { PD[r] = sa; PD[8192 + r] = sc; }
    } else {
        for (int w = wid; w <= 10; w += 4) {
            float s = 0.f;
#pragma unroll
            for (int q = 0; q < 12; ++q) s += T[w * H + lane + 64 * q] * w_ment[lane + 64 * q];
#pragma unroll
            for (int off = 32; off; off >>= 1) s += __shfl_down(s, off, 64);
            if (lane == 0) tw[w] = s + b_ment[0];
        }
    }
}

// stage 1 sort (scores inline from PD)
__global__ __launch_bounds__(256) void k_sort1(const float* __restrict__ PD,
    const int* __restrict__ starts, const int* __restrict__ ends,
    const float* __restrict__ tw, unsigned long long* __restrict__ CAND) {
    __shared__ unsigned long long keys[512];
    const int blk = blockIdx.x;
    const int b = blk >> 3, c = blk & 7;
    const int tid = threadIdx.x;
    for (int i = tid; i < 512; i += 256) {
        const int gi = c * 512 + i;
        const int r = b * NSP + gi;
        const int s = starts[r], e = ends[r];
        int w = e - s; w = w < 0 ? 0 : (w > 10 ? 10 : w);
        const float sc = PD[b * SEQ + s] + PD[8192 + b * SEQ + e] + tw[w];
        unsigned u = __float_as_uint(sc);
        u = (u & 0x80000000u) ? ~u : (u | 0x80000000u);
        keys[i] = ((unsigned long long)u << 32) | (unsigned)(0xFFFFFFFFu - (unsigned)gi);
    }
    __syncthreads();
    for (int k = 2; k <= 512; k <<= 1) {
        for (int j = k >> 1; j > 0; j >>= 1) {
            const int p = tid;
            const int i = ((p & ~(j - 1)) << 1) | (p & (j - 1));
            const int l = i | j;
            unsigned long long a = keys[i], d = keys[l];
            const bool desc = ((i & k) == 0);
            if ((a < d) == desc) { keys[i] = d; keys[l] = a; }
            __syncthreads();
        }
    }
    if (tid < 128) CAND[(size_t)(b * 8 + c) * 128 + tid] = keys[tid];
}

// stage 2 sort: emit outputs + fsI/feI/widI
__global__ __launch_bounds__(512) void k_sort2(const unsigned long long* __restrict__ CAND,
    const int* __restrict__ starts, const int* __restrict__ ends,
    float* __restrict__ out, int* __restrict__ fsI, int* __restrict__ feI,
    int* __restrict__ widI) {
    __shared__ unsigned long long keys[1024];
    const int b = blockIdx.x;
    const int tid = threadIdx.x;
    for (int i = tid; i < 1024; i += 512) keys[i] = CAND[(size_t)b * 1024 + i];
    __syncthreads();
    for (int k = 2; k <= 1024; k <<= 1) {
        for (int j = k >> 1; j > 0; j >>= 1) {
            const int p = tid;
            const int i = ((p & ~(j - 1)) << 1) | (p & (j - 1));
            const int l = i | j;
            unsigned long long a = keys[i], d = keys[l];
            const bool desc = ((i & k) == 0);
            if ((a < d) == desc) { keys[i] = d; keys[l] = a; }
            __syncthreads();
        }
    }
    if (tid < TOPK) {
        const unsigned long long key = keys[tid];
        const int widx = (int)(0xFFFFFFFFu - (unsigned)(key & 0xFFFFFFFFu));
        const unsigned hu = (unsigned)(key >> 32);
        const float sval = __uint_as_float((hu & 0x80000000u) ? (hu & 0x7FFFFFFFu) : ~hu);
        const int s = starts[b * NSP + widx], e = ends[b * NSP + widx];
        const int p = b * TOPK + tid;
        out[p] = sval;
        out[OFS_FS + p] = (float)s;
        out[OFS_FE + p] = (float)e;
        fsI[p] = b * SEQ + s;
        feI[p] = b * SEQ + e;
        int w = e - s;
        widI[p] = w < 0 ? 0 : (w > 10 ? 10 : w);
    }
}

// SEP[z] = gathered seq rows @ W chunk
__global__ __launch_bounds__(256) void k_se(const float* __restrict__ seq,
    const int* __restrict__ fsI, const int* __restrict__ feI,
    const float* __restrict__ W_start, const float* __restrict__ W_end,
    float* __restrict__ SEP) {
    __shared__ float sA[16][68];
    __shared__ float sB[16][68];
    __shared__ int sRow[64];
    const int tid = threadIdx.x;
    const int n0 = blockIdx.x * 64, m0 = blockIdx.y * 64, z = blockIdx.z;
    const int which = z >> 2;
    const int kbase = (z & 3) * 192;
    const int* rsrc = which ? feI : fsI;
    if (tid < 64) sRow[tid] = rsrc[m0 + tid];
    __syncthreads();
    const float* W = which ? W_end : W_start;
    const int tr = tid >> 4, tc = tid & 15;
    const int rr = tid >> 2, kg = (tid & 3) * 4;
    const int kb = tid >> 4, jc = (tid & 15) * 4;
    float acc[4][4];
#pragma unroll
    for (int i = 0; i < 4; ++i)
#pragma unroll
        for (int j = 0; j < 4; ++j) acc[i][j] = 0.f;
    for (int k0 = kbase; k0 < kbase + 192; k0 += 16) {
        float4 va = *(const float4*)(seq + (size_t)sRow[rr] * H + k0 + kg);
        float4 vb = *(const float4*)(W + (size_t)(k0 + kb) * H + n0 + jc);
        sA[kg + 0][rr] = va.x; sA[kg + 1][rr] = va.y;
        sA[kg + 2][rr] = va.z; sA[kg + 3][rr] = va.w;
        *(float4*)&sB[kb][jc] = vb;
        __syncthreads();
#pragma unroll
        for (int kk = 0; kk < 16; ++kk) {
            float a[4], b[4];
            *(float4*)a = *(const float4*)&sA[kk][tr * 4];
            *(float4*)b = *(const float4*)&sB[kk][tc * 4];
#pragma unroll
            for (int i = 0; i < 4; ++i)
#pragma unroll
                for (int j = 0; j < 4; ++j) acc[i][j] += a[i] * b[j];
        }
        __syncthreads();
    }
    float* dst = SEP + (size_t)z * 512 * H;
#pragma unroll
    for (int i = 0; i < 4; ++i) {
        float4 o = make_float4(acc[i][0], acc[i][1], acc[i][2], acc[i][3]);
        *(float4*)(dst + (size_t)(m0 + tr * 4 + i) * H + n0 + tc * 4) = o;
    }
}

// SE[p] = sum of 4 K-chunk partials
__global__ void k_reduceSE(const float* __restrict__ SEP, float* __restrict__ SE) {
    const int p = blockIdx.x, tid = threadIdx.x;
    if (tid >= 192) return;
    const int which = p >> 9, row = p & 511;
    const int c0 = tid * 4;
    float4 s = make_float4(0.f, 0.f, 0.f, 0.f);
#pragma unroll
    for (int kc = 0; kc < 4; ++kc) {
        float4 v = *(const float4*)(SEP + ((size_t)((which << 2) | kc) * 512 + row) * H + c0);
        s.x += v.x; s.y += v.y; s.z += v.z; s.w += v.w;
    }
    *(float4*)(SE + (size_t)p * H + c0) = s;
}

// RKP[z] = SE-half @ W_out chunk
__global__ __launch_bounds__(256) void k_rk(const float* __restrict__ SE,
    const float* __restrict__ W_out, float* __restrict__ RKP) {
    __shared__ float sA[16][68];
    __shared__ float sB[16][68];
    const int tid = threadIdx.x;
    const int n0 = blockIdx.x * 64, m0 = blockIdx.y * 64, z = blockIdx.z;
    const int ph = z >> 2;
    const int kbase = (z & 3) * 192;
    const float* A = SE + (size_t)ph * 512 * H;
    const float* B = W_out + (size_t)ph * H * H;
    const int tr = tid >> 4, tc = tid & 15;
    const int rr = tid >> 2, kg = (tid & 3) * 4;
    const int kb = tid >> 4, jc = (tid & 15) * 4;
    float acc[4][4];
#pragma unroll
    for (int i = 0; i < 4; ++i)
#pragma unroll
        for (int j = 0; j < 4; ++j) acc[i][j] = 0.f;
    for (int k0 = kbase; k0 < kbase + 192; k0 += 16) {
        float4 va = *(const float4*)(A + (size_t)(m0 + rr) * H + k0 + kg);
        float4 vb = *(const float4*)(B + (size_t)(k0 + kb) * H + n0 + jc);
        sA[kg + 0][rr] = va.x; sA[kg + 1][rr] = va.y;
        sA[kg + 2][rr] = va.z; sA[kg + 3][rr] = va.w;
        *(float4*)&sB[kb][jc] = vb;
        __syncthreads();
#pragma unroll
        for (int kk = 0; kk < 16; ++kk) {
            float a[4], b[4];
            *(float4*)a = *(const float4*)&sA[kk][tr * 4];
            *(float4*)b = *(const float4*)&sB[kk][tc * 4];
#pragma unroll
            for (int i = 0; i < 4; ++i)
#pragma unroll
                for (int j = 0; j < 4; ++j) acc[i][j] += a[i] * b[j];
        }
        __syncthreads();
    }
    float* dst = RKP + (size_t)z * 512 * H;
#pragma unroll
    for (int i = 0; i < 4; ++i) {
        float4 o = make_float4(acc[i][0], acc[i][1], acc[i][2], acc[i][3]);
        *(float4*)(dst + (size_t)(m0 + tr * 4 + i) * H + n0 + tc * 4) = o;
    }
}

// reduce 8 partials + T[width] -> RKH (f16 rows) + RJF (f16 A-frags)
__global__ __launch_bounds__(256) void k_reduce(const float* __restrict__ RKpart,
    const float* __restrict__ T, const int* __restrict__ widI,
    _Float16* __restrict__ RKH, _Float16* __restrict__ RJF) {
    __shared__ float srow[H];
    const int p = blockIdx.x, tid = threadIdx.x;
    const int w = widI[p];
    if (tid < 192) {
        const int c0 = tid * 4;
        float4 s = *(const float4*)(T + (size_t)w * H + c0);
#pragma unroll
        for (int kc = 0; kc < 8; ++kc) {
            float4 v = *(const float4*)(RKpart + ((size_t)kc * 512 + p) * H + c0);
            s.x += v.x; s.y += v.y; s.z += v.z; s.w += v.w;
        }
        *(float4*)&srow[c0] = s;
        _Float16* hd = RKH + (size_t)p * H + c0;
        hd[0] = (_Float16)s.x; hd[1] = (_Float16)s.y;
        hd[2] = (_Float16)s.z; hd[3] = (_Float16)s.w;
    }
    __syncthreads();
    if (tid < 96) {
        const int k0 = tid * 8;
        const int kt = k0 >> 5, sub = k0 & 31;
        const int lane = (p & 15) | ((sub >> 3) << 4);
        const int t = p >> 4;
        _Float16* d2 = RJF + ((size_t)(t * 24 + kt) * 64 + lane) * 8;
#pragma unroll
        for (int e = 0; e < 8; ++e) d2[e] = (_Float16)srow[k0 + e];
    }
}

// U/V partials via f16 MFMA, K-split x2: grid (32 tiles, 2 khalf)
// UVP[kh][p][n]: n in [0,160) = u-part, [160,320) = v-part
__global__ __launch_bounds__(256) void k_uv3(const _Float16* __restrict__ RJF,
    const _Float16* __restrict__ WCF, float* __restrict__ UVP) {
    const int t = blockIdx.x, kh = blockIdx.y;
    const int wave = threadIdx.x >> 6, lane = threadIdx.x & 63;
    const _Float16* Af = RJF + (size_t)t * 24 * 64 * 8;
    f32x4 acc[5];
#pragma unroll
    for (int q = 0; q < 5; ++q) acc[q] = (f32x4){0.f, 0.f, 0.f, 0.f};
    for (int kk = 0; kk < 12; ++kk) {
        const int kt = kh * 12 + kk;
        half8 a = *(const half8*)(Af + ((size_t)(kt * 64 + lane)) * 8);
#pragma unroll
        for (int q = 0; q < 5; ++q) {
            const int nt = wave * 5 + q;
            half8 bv = *(const half8*)(WCF + ((size_t)((nt * 24 + kt) * 64 + lane)) * 8);
            acc[q] = __builtin_amdgcn_mfma_f32_16x16x32_f16(a, bv, acc[q], 0, 0, 0);
        }
    }
    const int c = lane & 15, g = lane >> 4;
#pragma unroll
    for (int q = 0; q < 5; ++q) {
        const int n = (wave * 5 + q) * 16 + c;
#pragma unroll
        for (int r = 0; r < 4; ++r) {
            const int p = t * 16 + g * 4 + r;
            UVP[((size_t)kh * 512 + p) * 320 + n] = acc[q][r];
        }
    }
}

// Pairwise MFMA v3: one block per (ii, b); 4 waves, j-tiles {w, w+4};
// WF staged per-kt into double-buffered LDS; rj/ri register-prefetched.
__global__ __launch_bounds__(256) void k_pair(
    const _Float16* __restrict__ RJF, const _Float16* __restrict__ WF,
    const _Float16* __restrict__ RKH, const float* __restrict__ UVP,
    const float* __restrict__ b1, const float* __restrict__ GW,
    const float* __restrict__ SCAL, float* __restrict__ ant) {
    const int ii = blockIdx.x, b = blockIdx.y;
    float* arow = ant + ((size_t)b * TOPK + ii) * TOPK;
    const int tid = threadIdx.x;
    if (tid < TOPK && tid >= ii) arow[tid] = 0.f;
    const int ntiles = (ii + 15) >> 4;
    if (ntiles == 0) return;

    const int wave = tid >> 6, lane = tid & 63;
    const int g = lane >> 4, c = lane & 15;
    const int t0 = wave, t1 = wave + 4;
    const bool has0 = t0 < ntiles, has1 = t1 < ntiles;

    __shared__ _Float16 sB[2][5120];   // 2 x 10 nt x 64 lanes x 8 halves

    const _Float16* RiH = RKH + (size_t)(b * TOPK + ii) * H;
    const _Float16* Aj0 = RJF + (size_t)(b * 8 + t0) * 24 * 64 * 8;
    const _Float16* Aj1 = RJF + (size_t)(b * 8 + (t1 < 8 ? t1 : 7)) * 24 * 64 * 8;

    f32x4 acc0[10], acc1[10];
#pragma unroll
    for (int nt = 0; nt < 10; ++nt) {
        acc0[nt] = (f32x4){0.f, 0.f, 0.f, 0.f};
        acc1[nt] = (f32x4){0.f, 0.f, 0.f, 0.f};
    }

    // staging source: element i of kt-chunk (i = nt*64 + lane_within)
    auto stage_src = [&](int kt, int i) -> uint4 {
        const int nt = i >> 6, wi = i & 63;
        return *(const uint4*)(WF + ((size_t)((nt * 24 + kt) * 64 + wi)) * 8);
    };

    // prologue: stage kt=0, prefetch rj/ri kt=0
    uint4 s0 = stage_src(0, tid);
    uint4 s1 = stage_src(0, tid + 256);
    uint4 s2;
    if (tid < 128) s2 = stage_src(0, tid + 512);
    {
        uint4* sbw = (uint4*)sB[0];
        sbw[tid] = s0;
        sbw[tid + 256] = s1;
        if (tid < 128) sbw[tid + 512] = s2;
    }
    half8 rj0, rj1, ri;
    if (has0) rj0 = *(const half8*)(Aj0 + (size_t)lane * 8);
    if (has1) rj1 = *(const half8*)(Aj1 + (size_t)lane * 8);
    ri = *(const half8*)(RiH + g * 8);
    __syncthreads();

    for (int kt = 0; kt < 24; ++kt) {
        const int cur = kt & 1, nxt = cur ^ 1;
        uint4 n0, n1, n2;
        half8 nrj0, nrj1, nri;
        if (kt < 23) {
            n0 = stage_src(kt + 1, tid);
            n1 = stage_src(kt + 1, tid + 256);
            if (tid < 128) n2 = stage_src(kt + 1, tid + 512);
            if (has0) nrj0 = *(const half8*)(Aj0 + ((size_t)((kt + 1) * 64 + lane)) * 8);
            if (has1) nrj1 = *(const half8*)(Aj1 + ((size_t)((kt + 1) * 64 + lane)) * 8);
            nri = *(const half8*)(RiH + (kt + 1) * 32 + g * 8);
        }
        half8 a0, a1;
        if (has0) a0 = ri * rj0;
        if (has1) a1 = ri * rj1;
#pragma unroll
        for (int nt = 0; nt < 10; ++nt) {
            half8 bv = *(const half8*)&sB[cur][nt * 512 + lane * 8];
            if (has0) acc0[nt] = __builtin_amdgcn_mfma_f32_16x16x32_f16(a0, bv, acc0[nt], 0, 0, 0);
            if (has1) acc1[nt] = __builtin_amdgcn_mfma_f32_16x16x32_f16(a1, bv, acc1[nt], 0, 0, 0);
        }
        if (kt < 23) {
            uint4* sbw = (uint4*)sB[nxt];
            sbw[tid] = n0;
            sbw[tid + 256] = n1;
            if (tid < 128) sbw[tid + 512] = n2;
            rj0 = nrj0; rj1 = nrj1; ri = nri;
        }
        __syncthreads();
    }

    // epilogue
    const float Sgw = SCAL[0], C0 = SCAL[1];
    const int pi = b * TOPK + ii;
    float u10[10], gw10[10];
#pragma unroll
    for (int nt = 0; nt < 10; ++nt) {
        const int d = nt * 16 + c;
        const float ub = (d < HIDD) ? b1[d] : 0.f;
        u10[nt] = UVP[(size_t)pi * 320 + d] + UVP[(size_t)(512 + pi) * 320 + d] + ub;
        gw10[nt] = GW[d];
    }
    auto epi = [&](const f32x4 (&acc)[10], int t) {
#pragma unroll
        for (int r = 0; r < 4; ++r) {
            const int j = 16 * t + g * 4 + r;
            const int pj = b * TOPK + j;
            const float* Vp0 = UVP + (size_t)pj * 320 + 160;
            const float* Vp1 = UVP + (size_t)(512 + pj) * 320 + 160;
            float s1 = 0.f, s2 = 0.f, s3 = 0.f;
#pragma unroll
            for (int nt = 0; nt < 10; ++nt) {
                const int d = nt * 16 + c;
                float z = acc[nt][r] + u10[nt] + Vp0[d] + Vp1[d];
                float h = (d < HIDD && z > 0.f) ? z : 0.f;
                s1 += h;
                s2 += h * h;
                s3 += h * gw10[nt];
            }
#pragma unroll
            for (int off = 1; off < 16; off <<= 1) {
                s1 += __shfl_xor(s1, off, 64);
                s2 += __shfl_xor(s2, off, 64);
                s3 += __shfl_xor(s3, off, 64);
            }
            const float mu = s1 * (1.f / HIDD);
            const float var = s2 * (1.f / HIDD) - mu * mu;
            const float rstd = rsqrtf(var + 1e-5f);
            const float val = rstd * (s3 - mu * Sgw) + C0;
            if (c == 0 && j < ii) arow[j] = val;
        }
    };
    if (has0) epi(acc0, t0);
    if (has1) epi(acc1, t1);
}

extern "C" void kernel_launch(void* const* d_in, const int* in_sizes, int n_in,
                              void* d_out, int out_size, void* d_ws, size_t ws_size,
                              hipStream_t stream) {
    const float* seq      = (const float*)d_in[0];
    const int*   starts   = (const int*)d_in[1];
    const int*   ends     = (const int*)d_in[2];
    const float* W_start  = (const float*)d_in[3];
    const float* b_start  = (const float*)d_in[4];
    const float* W_end    = (const float*)d_in[5];
    const float* b_end    = (const float*)d_in[6];
    const float* width_e  = (const float*)d_in[7];
    const float* W_out    = (const float*)d_in[8];
    const float* b_out    = (const float*)d_in[9];
    const float* w_ment   = (const float*)d_in[10];
    const float* b_ment   = (const float*)d_in[11];
    const float* W1       = (const float*)d_in[12];
    const float* b1       = (const float*)d_in[13];
    const float* ln_g     = (const float*)d_in[14];
    const float* ln_b     = (const float*)d_in[15];
    const float* W2       = (const float*)d_in[16];
    const float* b2       = (const float*)d_in[17];
    float* out = (float*)d_out;
    float* ws  = (float*)d_ws;

    float* Tt    = ws + OFF_T;
    float* biasP = ws + OFF_BIASP;
    float* WOV   = ws + OFF_WOV;
    float* av    = ws + OFF_AV;
    float* cv    = ws + OFF_CV;
    float* tw    = ws + OFF_TW;
    float* PD    = ws + OFF_PD;
    unsigned long long* CANDp = (unsigned long long*)(ws + OFF_CAND);
    int*   fsI   = (int*)(ws + OFF_FS);
    int*   feI   = (int*)(ws + OFF_FE);
    int*   widI  = (int*)(ws + OFF_WID);
    float* UVPp  = ws + OFF_UVP;
    float* GWp   = ws + OFF_GW;
    float* SCALp = ws + OFF_SCAL;
    _Float16* WFp  = (_Float16*)(ws + OFF_WF);
    _Float16* WCFp = (_Float16*)(ws + OFF_WCF);
    _Float16* RJFp = (_Float16*)(ws + OFF_RJF);
    _Float16* RKHp = (_Float16*)(ws + OFF_RKH);
    float* SEp   = ws + OFF_SE;
    float* SEPp  = ws + OFF_SEP;

    kA<<<589, 256, 0, stream>>>(b_start, b_end, b_out, W_out, w_ment, W1,
                                ln_g, ln_b, W2, b2, biasP, WOV, WFp, WCFp, GWp, SCALp);
    kB<<<417, 256, 0, stream>>>(biasP, width_e, W_out, W_start, W_end, WOV, Tt, av, cv);
    k_posdots<<<2049, 256, 0, stream>>>(seq, av, cv, Tt, w_ment, b_ment, PD, tw);
    k_sort1<<<32, 256, 0, stream>>>(PD, starts, ends, tw, CANDp);
    k_sort2<<<4, 512, 0, stream>>>(CANDp, starts, ends, out, fsI, feI, widI);
    k_se<<<dim3(12, 8, 8), 256, 0, stream>>>(seq, fsI, feI, W_start, W_end, SEPp);
    k_reduceSE<<<1024, 192, 0, stream>>>(SEPp, SEp);
    k_rk<<<dim3(12, 8, 8), 256, 0, stream>>>(SEp, W_out, SEPp);
    k_reduce<<<512, 256, 0, stream>>>(SEPp, Tt, widI, RKHp, RJFp);
    k_uv3<<<dim3(32, 2), 256, 0, stream>>>(RJFp, WCFp, UVPp);
    k_pair<<<dim3(128, 4), 256, 0, stream>>>(RJFp, WFp, RKHp, UVPp, b1, GWp, SCALp,
                                             out + OFS_ANT);
}

// Round 9
// 210.264 us; speedup vs baseline: 7.7180x; 1.1294x over previous
//
#include <hip/hip_runtime.h>
#include <math.h>

#define H 768
#define SEQ 2048
#define NSP 4096
#define HIDD 150
#define TOPK 128
#define NPAD 160

// d_out layout (floats): [0,512) mention_scores | [512,66048) ant | [66048,66560) f_starts | [66560,67072) f_ends
#define OFS_ANT 512
#define OFS_FS 66048
#define OFS_FE 66560

// workspace layout (float offsets) — ~14 MB
static const size_t OFF_T     = 0ull;         // 11*768
static const size_t OFF_BIASP = 8448ull;      // 8*768
static const size_t OFF_WOV   = 14592ull;     // 1536
static const size_t OFF_AV    = 16128ull;     // 768
static const size_t OFF_CV    = 16896ull;     // 768
static const size_t OFF_TW    = 17664ull;     // 16
static const size_t OFF_PD    = 17680ull;     // 2*8192
static const size_t OFF_CAND  = 34064ull;     // 4096 u64 = 8192 f32 (even -> 8B aligned)
static const size_t OFF_FS    = 42256ull;     // 512 ints
static const size_t OFF_FE    = 42768ull;     // 512 ints
static const size_t OFF_WID   = 43280ull;     // 512 ints
static const size_t OFF_UVP   = 43792ull;     // 2*512*320 f32
static const size_t OFF_GW    = 371472ull;    // 160
static const size_t OFF_SCAL  = 371632ull;    // 8
static const size_t OFF_WF    = 371640ull;    // 61440   (Wd f16 B-frags, 10nt x 24kt)
static const size_t OFF_WCF   = 433080ull;    // 122880  (UV f16 B-frags, 20nt x 24kt)
static const size_t OFF_WSF   = 555960ull;    // 294912  (W_start f16 B-frags, 48nt x 24kt)
static const size_t OFF_WEF   = 850872ull;    // 294912  (W_end   f16 B-frags)
static const size_t OFF_WOF   = 1145784ull;   // 589824  (W_out   f16 B-frags, 48nt x 48kt)
static const size_t OFF_GSEH  = 1735608ull;   // 1024*768 f16 = 393216 f32 (gathered seq rows)
static const size_t OFF_SEH   = 2128824ull;   // 1024*768 f16 = 393216 f32
static const size_t OFF_RKH   = 2522040ull;   // 512*768 f16 = 196608 f32 (row-major repr_k)
static const size_t OFF_RKP2  = 2718648ull;   // 2*512*768 f32 partials

typedef __attribute__((ext_vector_type(8))) _Float16 half8;
typedef __attribute__((ext_vector_type(4))) _Float16 half4;
typedef __attribute__((ext_vector_type(4))) float f32x4;

// ============ kA: independent preps (1741 blocks) ============
__global__ __launch_bounds__(256) void kA(
    const float* __restrict__ b_start, const float* __restrict__ b_end,
    const float* __restrict__ b_out, const float* __restrict__ W_out,
    const float* __restrict__ w_ment, const float* __restrict__ W1,
    const float* __restrict__ ln_g, const float* __restrict__ ln_b,
    const float* __restrict__ W2, const float* __restrict__ b2,
    const float* __restrict__ W_start, const float* __restrict__ W_end,
    float* __restrict__ biasP, float* __restrict__ WOV,
    _Float16* __restrict__ WF, _Float16* __restrict__ WCF,
    _Float16* __restrict__ WSF, _Float16* __restrict__ WEF,
    _Float16* __restrict__ WOF, float* __restrict__ GW, float* __restrict__ SCAL) {
    const int blk = blockIdx.x, tid = threadIdx.x;
    if (blk < 24) {
        const int kc = blk / 3, jb = blk - kc * 3;
        const int j = jb * 256 + tid;
        float acc = (kc == 0) ? b_out[j] : 0.f;
        const int k0 = kc * 96;
#pragma unroll 4
        for (int k = k0; k < k0 + 96; ++k) {
            acc += b_start[k] * W_out[(size_t)k * H + j];
            acc += b_end[k]   * W_out[(size_t)(H + k) * H + j];
        }
        biasP[kc * H + j] = acc;
    } else if (blk < 408) {
        const int wid = tid >> 6, lane = tid & 63;
        const int gr = (blk - 24) * 4 + wid;
        const float* row = W_out + (size_t)gr * H;
        float s = 0.f;
#pragma unroll
        for (int q = 0; q < 12; ++q) s += row[lane + 64 * q] * w_ment[lane + 64 * q];
#pragma unroll
        for (int off = 32; off; off >>= 1) s += __shfl_down(s, off, 64);
        if (lane == 0) WOV[gr] = s;
    } else if (blk < 468) {
        const int idx = (blk - 408) * 256 + tid;
        const int nt = idx / 1536;
        const int rem = idx - nt * 1536;
        const int kt = rem >> 6, lane = rem & 63;
        const int n = nt * 16 + (lane & 15);
        const int kb = kt * 32 + (lane >> 4) * 8;
        _Float16* dst = WF + (size_t)idx * 8;
#pragma unroll
        for (int e = 0; e < 8; ++e) {
            float v = (n < HIDD) ? W1[(size_t)(3 * H + kb + e) * HIDD + n] : 0.f;
            dst[e] = (_Float16)v;
        }
    } else if (blk < 588) {
        const int idx = (blk - 468) * 256 + tid;
        const int nt = idx / 1536;
        const int rem = idx - nt * 1536;
        const int kt = rem >> 6, lane = rem & 63;
        const int n = nt * 16 + (lane & 15);
        const int kb = kt * 32 + (lane >> 4) * 8;
        _Float16* dst = WCF + (size_t)idx * 8;
#pragma unroll
        for (int e = 0; e < 8; ++e) {
            const int h = kb + e;
            float v = 0.f;
            if (n < 160) {
                if (n < HIDD)
                    v = W1[(size_t)h * HIDD + n] + W1[(size_t)(2 * H + h) * HIDD + n];
            } else {
                const int d = n - 160;
                if (d < HIDD)
                    v = W1[(size_t)(H + h) * HIDD + d] - W1[(size_t)(2 * H + h) * HIDD + d];
            }
            dst[e] = (_Float16)v;
        }
    } else if (blk == 588) {
        if (tid < NPAD) GW[tid] = (tid < HIDD) ? ln_g[tid] * W2[tid] : 0.f;
        if (tid == 0) {
            float sg = 0.f, sb = 0.f;
            for (int d = 0; d < HIDD; ++d) { sg += ln_g[d] * W2[d]; sb += ln_b[d] * W2[d]; }
            SCAL[0] = sg;
            SCAL[1] = sb + b2[0];
        }
    } else if (blk < 1165) {
        // WSF (589..876) / WEF (877..1164): 48nt x 24kt
        const bool isS = blk < 877;
        const int idx = (blk - (isS ? 589 : 877)) * 256 + tid;  // < 73728
        const float* Wsrc = isS ? W_start : W_end;
        _Float16* dstb = isS ? WSF : WEF;
        const int nt = idx / 1536;
        const int rem = idx - nt * 1536;
        const int kt = rem >> 6, lane = rem & 63;
        const int n = nt * 16 + (lane & 15);
        const int kb = kt * 32 + (lane >> 4) * 8;
        _Float16* dst = dstb + (size_t)idx * 8;
#pragma unroll
        for (int e = 0; e < 8; ++e) dst[e] = (_Float16)Wsrc[(size_t)(kb + e) * H + n];
    } else {
        // WOF (1165..1740): 48nt x 48kt over W_out rows 0..1535
        const int idx = (blk - 1165) * 256 + tid;  // < 147456
        const int nt = idx / 3072;
        const int rem = idx - nt * 3072;
        const int kt = rem >> 6, lane = rem & 63;
        const int n = nt * 16 + (lane & 15);
        const int kb = kt * 32 + (lane >> 4) * 8;
        _Float16* dst = WOF + (size_t)idx * 8;
#pragma unroll
        for (int e = 0; e < 8; ++e) dst[e] = (_Float16)W_out[(size_t)(kb + e) * H + n];
    }
}

// ============ kB: T table + av/cv (417 blocks) ============
__global__ __launch_bounds__(256) void kB(
    const float* __restrict__ biasP, const float* __restrict__ width_emb,
    const float* __restrict__ W_out, const float* __restrict__ W_start,
    const float* __restrict__ W_end, const float* __restrict__ WOV,
    float* __restrict__ T, float* __restrict__ av, float* __restrict__ cv) {
    const int blk = blockIdx.x, tid = threadIdx.x;
    if (blk < 33) {
        const int w = blk / 3, jb = blk - w * 3;
        const int j = jb * 256 + tid;
        float acc = 0.f;
#pragma unroll
        for (int kc = 0; kc < 8; ++kc) acc += biasP[kc * H + j];
#pragma unroll
        for (int k = 0; k < 30; ++k)
            acc += width_emb[w * 30 + k] * W_out[(size_t)(2 * H + k) * H + j];
        T[w * H + j] = acc;
    } else {
        const int wid = tid >> 6, lane = tid & 63;
        const int gr = (blk - 33) * 4 + wid;
        const float* row = (gr < H) ? (W_start + (size_t)gr * H) : (W_end + (size_t)(gr - H) * H);
        const float* vec = (gr < H) ? WOV : (WOV + H);
        float s = 0.f;
#pragma unroll
        for (int q = 0; q < 12; ++q) s += row[lane + 64 * q] * vec[lane + 64 * q];
#pragma unroll
        for (int off = 32; off; off >>= 1) s += __shfl_down(s, off, 64);
        if (lane == 0) {
            if (gr < H) av[gr] = s; else cv[gr - H] = s;
        }
    }
}

// position dots + tw
__global__ void k_posdots(const float* __restrict__ seq, const float* __restrict__ av,
                          const float* __restrict__ cv, const float* __restrict__ T,
                          const float* __restrict__ w_ment, const float* __restrict__ b_ment,
                          float* __restrict__ PD, float* __restrict__ tw) {
    const int wid = threadIdx.x >> 6, lane = threadIdx.x & 63;
    if (blockIdx.x < 2048) {
        const int r = blockIdx.x * 4 + wid;
        const float4* row = (const float4*)(seq + (size_t)r * H);
        const float4* a4 = (const float4*)av;
        const float4* c4 = (const float4*)cv;
        float sa = 0.f, sc = 0.f;
#pragma unroll
        for (int q = 0; q < 3; ++q) {
            float4 x = row[lane + 64 * q];
            float4 ya = a4[lane + 64 * q], yc = c4[lane + 64 * q];
            sa += x.x * ya.x + x.y * ya.y + x.z * ya.z + x.w * ya.w;
            sc += x.x * yc.x + x.y * yc.y + x.z * yc.z + x.w * yc.w;
        }
#pragma unroll
        for (int off = 32; off; off >>= 1) {
            sa += __shfl_down(sa, off, 64);
            sc += __shfl_down(sc, off, 64);
        }
        if (lane == 0) { PD[r] = sa; PD[8192 + r] = sc; }
    } else {
        for (int w = wid; w <= 10; w += 4) {
            float s = 0.f;
#pragma unroll
            for (int q = 0; q < 12; ++q) s += T[w * H + lane + 64 * q] * w_ment[lane + 64 * q];
#pragma unroll
            for (int off = 32; off; off >>= 1) s += __shfl_down(s, off, 64);
            if (lane == 0) tw[w] = s + b_ment[0];
        }
    }
}

// stage 1 sort (scores inline from PD): full 512 bitonic desc, emit top-128 (sorted)
__global__ __launch_bounds__(256) void k_sort1(const float* __restrict__ PD,
    const int* __restrict__ starts, const int* __restrict__ ends,
    const float* __restrict__ tw, unsigned long long* __restrict__ CAND) {
    __shared__ unsigned long long keys[512];
    const int blk = blockIdx.x;
    const int b = blk >> 3, c = blk & 7;
    const int tid = threadIdx.x;
    for (int i = tid; i < 512; i += 256) {
        const int gi = c * 512 + i;
        const int r = b * NSP + gi;
        const int s = starts[r], e = ends[r];
        int w = e - s; w = w < 0 ? 0 : (w > 10 ? 10 : w);
        const float sc = PD[b * SEQ + s] + PD[8192 + b * SEQ + e] + tw[w];
        unsigned u = __float_as_uint(sc);
        u = (u & 0x80000000u) ? ~u : (u | 0x80000000u);
        keys[i] = ((unsigned long long)u << 32) | (unsigned)(0xFFFFFFFFu - (unsigned)gi);
    }
    __syncthreads();
    for (int k = 2; k <= 512; k <<= 1) {
        for (int j = k >> 1; j > 0; j >>= 1) {
            const int p = tid;
            const int i = ((p & ~(j - 1)) << 1) | (p & (j - 1));
            const int l = i | j;
            unsigned long long a = keys[i], d = keys[l];
            const bool desc = ((i & k) == 0);
            if ((a < d) == desc) { keys[i] = d; keys[l] = a; }
            __syncthreads();
        }
    }
    if (tid < 128) CAND[(size_t)(b * 8 + c) * 128 + tid] = keys[tid];
}

// stage 2: bitonic top-k MERGE of 8 sorted-desc 128-lists (3 rounds x 8 passes)
__global__ __launch_bounds__(256) void k_sort2(const unsigned long long* __restrict__ CAND,
    const int* __restrict__ starts, const int* __restrict__ ends,
    float* __restrict__ out, int* __restrict__ fsI, int* __restrict__ feI,
    int* __restrict__ widI) {
    __shared__ unsigned long long K[1024];
    const int b = blockIdx.x, tid = threadIdx.x;
    for (int i = tid; i < 1024; i += 256) K[i] = CAND[(size_t)b * 1024 + i];
    __syncthreads();
    for (int nl = 4; nl >= 1; nl >>= 1) {
        const int items = nl * 128;
        // max-phase: merge pair (2q,2q+1) -> top-128 bitonic, compact to q*128
        unsigned long long v0 = 0, v1 = 0;
        if (tid < items) {
            const int q = tid >> 7, r = tid & 127;
            unsigned long long a = K[q * 256 + r];
            unsigned long long d = K[q * 256 + 128 + (127 - r)];
            v0 = a > d ? a : d;
        }
        if (tid + 256 < items) {
            const int i = tid + 256;
            const int q = i >> 7, r = i & 127;
            unsigned long long a = K[q * 256 + r];
            unsigned long long d = K[q * 256 + 128 + (127 - r)];
            v1 = a > d ? a : d;
        }
        __syncthreads();
        if (tid < items) K[(tid >> 7) * 128 + (tid & 127)] = v0;
        if (tid + 256 < items) { const int i = tid + 256; K[(i >> 7) * 128 + (i & 127)] = v1; }
        __syncthreads();
        // cleanup: 7 desc bitonic-merge passes per 128-list
        for (int j = 64; j; j >>= 1) {
            const int pairs = nl * 64;
            for (int i = tid; i < pairs; i += 256) {
                const int q = i >> 6, r = i & 63;
                const int lo = q * 128 + (((r & ~(j - 1)) << 1) | (r & (j - 1)));
                const int hi = lo + j;
                unsigned long long a = K[lo], d = K[hi];
                if (a < d) { K[lo] = d; K[hi] = a; }
            }
            __syncthreads();
        }
    }
    if (tid < TOPK) {
        const unsigned long long key = K[tid];
        const int widx = (int)(0xFFFFFFFFu - (unsigned)(key & 0xFFFFFFFFu));
        const unsigned hu = (unsigned)(key >> 32);
        const float sval = __uint_as_float((hu & 0x80000000u) ? (hu & 0x7FFFFFFFu) : ~hu);
        const int s = starts[b * NSP + widx], e = ends[b * NSP + widx];
        const int p = b * TOPK + tid;
        out[p] = sval;
        out[OFS_FS + p] = (float)s;
        out[OFS_FE + p] = (float)e;
        fsI[p] = b * SEQ + s;
        feI[p] = b * SEQ + e;
        int w = e - s;
        widI[p] = w < 0 ? 0 : (w > 10 ? 10 : w);
    }
}

// gather 1024 winner rows (start|end) -> f16 row-major
__global__ void k_gath(const float* __restrict__ seq, const int* __restrict__ fsI,
                       const int* __restrict__ feI, _Float16* __restrict__ GSEH) {
    const int r0 = blockIdx.x * 4;
    const int tid = threadIdx.x;
    for (int q = 0; q < 4; ++q) {
        const int row = r0 + q;
        const int src = (row < 512) ? fsI[row] : feI[row - 512];
        if (tid < 192) {
            float4 v = *(const float4*)(seq + (size_t)src * H + tid * 4);
            half4 h = {(_Float16)v.x, (_Float16)v.y, (_Float16)v.z, (_Float16)v.w};
            *(half4*)(GSEH + (size_t)row * H + tid * 4) = h;
        }
    }
}

// SEH(1024x768) = GSEH @ [W_start | W_end] via f16 MFMA. grid (64 mt, 6 ng), 4 waves x 2 nt
__global__ __launch_bounds__(256) void k_gemm1(const _Float16* __restrict__ GSEH,
    const _Float16* __restrict__ WSF, const _Float16* __restrict__ WEF,
    _Float16* __restrict__ SEH) {
    const int mt = blockIdx.x;
    const int wave = threadIdx.x >> 6, lane = threadIdx.x & 63;
    const int nt0 = blockIdx.y * 8 + wave * 2;
    const _Float16* Arow = GSEH + (size_t)(mt * 16 + (lane & 15)) * H + (lane >> 4) * 8;
    const _Float16* BF = (mt < 32) ? WSF : WEF;
    f32x4 acc0 = {0.f, 0.f, 0.f, 0.f}, acc1 = acc0;
    for (int kt = 0; kt < 24; ++kt) {
        half8 a = *(const half8*)(Arow + kt * 32);
        half8 b0 = *(const half8*)(BF + ((size_t)((nt0 * 24 + kt) * 64 + lane)) * 8);
        half8 b1 = *(const half8*)(BF + ((size_t)(((nt0 + 1) * 24 + kt) * 64 + lane)) * 8);
        acc0 = __builtin_amdgcn_mfma_f32_16x16x32_f16(a, b0, acc0, 0, 0, 0);
        acc1 = __builtin_amdgcn_mfma_f32_16x16x32_f16(a, b1, acc1, 0, 0, 0);
    }
    const int c = lane & 15, quad = lane >> 4;
#pragma unroll
    for (int r = 0; r < 4; ++r) {
        const int row = mt * 16 + quad * 4 + r;
        SEH[(size_t)row * H + nt0 * 16 + c] = (_Float16)acc0[r];
        SEH[(size_t)row * H + (nt0 + 1) * 16 + c] = (_Float16)acc1[r];
    }
}

// RKP2[kh] = SEH-half @ W_out-half via f16 MFMA. grid (32 mt, 6 ng, 2 kh), 4 waves x 2 nt
__global__ __launch_bounds__(256) void k_gemm2(const _Float16* __restrict__ SEH,
    const _Float16* __restrict__ WOF, float* __restrict__ RKP2) {
    const int mt = blockIdx.x, kh = blockIdx.z;
    const int wave = threadIdx.x >> 6, lane = threadIdx.x & 63;
    const int nt0 = blockIdx.y * 8 + wave * 2;
    const _Float16* Arow = SEH + (size_t)(kh * 512 + mt * 16 + (lane & 15)) * H + (lane >> 4) * 8;
    f32x4 acc0 = {0.f, 0.f, 0.f, 0.f}, acc1 = acc0;
    for (int kt2 = 0; kt2 < 24; ++kt2) {
        const int kt = kh * 24 + kt2;
        half8 a = *(const half8*)(Arow + kt2 * 32);
        half8 b0 = *(const half8*)(WOF + ((size_t)((nt0 * 48 + kt) * 64 + lane)) * 8);
        half8 b1 = *(const half8*)(WOF + ((size_t)(((nt0 + 1) * 48 + kt) * 64 + lane)) * 8);
        acc0 = __builtin_amdgcn_mfma_f32_16x16x32_f16(a, b0, acc0, 0, 0, 0);
        acc1 = __builtin_amdgcn_mfma_f32_16x16x32_f16(a, b1, acc1, 0, 0, 0);
    }
    const int c = lane & 15, quad = lane >> 4;
    float* dst = RKP2 + (size_t)kh * 512 * H;
#pragma unroll
    for (int r = 0; r < 4; ++r) {
        const int row = mt * 16 + quad * 4 + r;
        dst[(size_t)row * H + nt0 * 16 + c] = acc0[r];
        dst[(size_t)row * H + (nt0 + 1) * 16 + c] = acc1[r];
    }
}

// RKH[p] = (f16)(RKP2[0][p] + RKP2[1][p] + T[wid[p]])
__global__ void k_fin(const float* __restrict__ RKP2, const float* __restrict__ T,
                      const int* __restrict__ widI, _Float16* __restrict__ RKH) {
    const int p = blockIdx.x, tid = threadIdx.x;
    if (tid >= 192) return;
    const int w = widI[p];
    const int c0 = tid * 4;
    float4 s = *(const float4*)(T + (size_t)w * H + c0);
    float4 v0 = *(const float4*)(RKP2 + (size_t)p * H + c0);
    float4 v1 = *(const float4*)(RKP2 + (size_t)(512 + p) * H + c0);
    half4 h = {(_Float16)(s.x + v0.x + v1.x), (_Float16)(s.y + v0.y + v1.y),
               (_Float16)(s.z + v0.z + v1.z), (_Float16)(s.w + v0.w + v1.w)};
    *(half4*)(RKH + (size_t)p * H + c0) = h;
}

// U/V partials via f16 MFMA (A from RKH rows), K-split x2
__global__ __launch_bounds__(256) void k_uv3(const _Float16* __restrict__ RKH,
    const _Float16* __restrict__ WCF, float* __restrict__ UVP) {
    const int t = blockIdx.x, kh = blockIdx.y;
    const int wave = threadIdx.x >> 6, lane = threadIdx.x & 63;
    const _Float16* Arow = RKH + (size_t)(t * 16 + (lane & 15)) * H + (lane >> 4) * 8;
    f32x4 acc[5];
#pragma unroll
    for (int q = 0; q < 5; ++q) acc[q] = (f32x4){0.f, 0.f, 0.f, 0.f};
    for (int kk = 0; kk < 12; ++kk) {
        const int kt = kh * 12 + kk;
        half8 a = *(const half8*)(Arow + kt * 32);
#pragma unroll
        for (int q = 0; q < 5; ++q) {
            const int nt = wave * 5 + q;
            half8 bv = *(const half8*)(WCF + ((size_t)((nt * 24 + kt) * 64 + lane)) * 8);
            acc[q] = __builtin_amdgcn_mfma_f32_16x16x32_f16(a, bv, acc[q], 0, 0, 0);
        }
    }
    const int c = lane & 15, g = lane >> 4;
#pragma unroll
    for (int q = 0; q < 5; ++q) {
        const int n = (wave * 5 + q) * 16 + c;
#pragma unroll
        for (int r = 0; r < 4; ++r) {
            const int p = t * 16 + g * 4 + r;
            UVP[((size_t)kh * 512 + p) * 320 + n] = acc[q][r];
        }
    }
}

// Pairwise MFMA: one block per (ii, b); 4 waves, j-tiles {w, w+4};
// WF double-buffered in LDS; rj/ri register-prefetched from row-major RKH.
__global__ __launch_bounds__(256) void k_pair(
    const _Float16* __restrict__ WF, const _Float16* __restrict__ RKH,
    const float* __restrict__ UVP, const float* __restrict__ b1,
    const float* __restrict__ GW, const float* __restrict__ SCAL,
    float* __restrict__ ant) {
    const int ii = blockIdx.x, b = blockIdx.y;
    float* arow = ant + ((size_t)b * TOPK + ii) * TOPK;
    const int tid = threadIdx.x;
    if (tid < TOPK && tid >= ii) arow[tid] = 0.f;
    const int ntiles = (ii + 15) >> 4;
    if (ntiles == 0) return;

    const int wave = tid >> 6, lane = tid & 63;
    const int g = lane >> 4, c = lane & 15;
    const int t0 = wave, t1 = wave + 4;
    const bool has0 = t0 < ntiles, has1 = t1 < ntiles;

    __shared__ _Float16 sB[2][5120];

    const _Float16* RiH = RKH + (size_t)(b * TOPK + ii) * H;
    const _Float16* Rj0 = RKH + (size_t)(b * TOPK + t0 * 16 + c) * H + g * 8;
    const _Float16* Rj1 = RKH + (size_t)(b * TOPK + t1 * 16 + c) * H + g * 8;

    f32x4 acc0[10], acc1[10];
#pragma unroll
    for (int nt = 0; nt < 10; ++nt) {
        acc0[nt] = (f32x4){0.f, 0.f, 0.f, 0.f};
        acc1[nt] = (f32x4){0.f, 0.f, 0.f, 0.f};
    }

    auto stage_src = [&](int kt, int i) -> uint4 {
        const int nt = i >> 6, wi = i & 63;
        return *(const uint4*)(WF + ((size_t)((nt * 24 + kt) * 64 + wi)) * 8);
    };

    uint4 s0 = stage_src(0, tid);
    uint4 s1 = stage_src(0, tid + 256);
    uint4 s2;
    if (tid < 128) s2 = stage_src(0, tid + 512);
    {
        uint4* sbw = (uint4*)sB[0];
        sbw[tid] = s0;
        sbw[tid + 256] = s1;
        if (tid < 128) sbw[tid + 512] = s2;
    }
    half8 rj0, rj1, ri;
    if (has0) rj0 = *(const half8*)(Rj0);
    if (has1) rj1 = *(const half8*)(Rj1);
    ri = *(const half8*)(RiH + g * 8);
    __syncthreads();

    for (int kt = 0; kt < 24; ++kt) {
        const int cur = kt & 1, nxt = cur ^ 1;
        uint4 n0, n1, n2;
        half8 nrj0, nrj1, nri;
        if (kt < 23) {
            n0 = stage_src(kt + 1, tid);
            n1 = stage_src(kt + 1, tid + 256);
            if (tid < 128) n2 = stage_src(kt + 1, tid + 512);
            if (has0) nrj0 = *(const half8*)(Rj0 + (kt + 1) * 32);
            if (has1) nrj1 = *(const half8*)(Rj1 + (kt + 1) * 32);
            nri = *(const half8*)(RiH + (kt + 1) * 32 + g * 8);
        }
        half8 a0, a1;
        if (has0) a0 = ri * rj0;
        if (has1) a1 = ri * rj1;
#pragma unroll
        for (int nt = 0; nt < 10; ++nt) {
            half8 bv = *(const half8*)&sB[cur][nt * 512 + lane * 8];
            if (has0) acc0[nt] = __builtin_amdgcn_mfma_f32_16x16x32_f16(a0, bv, acc0[nt], 0, 0, 0);
            if (has1) acc1[nt] = __builtin_amdgcn_mfma_f32_16x16x32_f16(a1, bv, acc1[nt], 0, 0, 0);
        }
        if (kt < 23) {
            uint4* sbw = (uint4*)sB[nxt];
            sbw[tid] = n0;
            sbw[tid + 256] = n1;
            if (tid < 128) sbw[tid + 512] = n2;
            rj0 = nrj0; rj1 = nrj1; ri = nri;
        }
        __syncthreads();
    }

    const float Sgw = SCAL[0], C0 = SCAL[1];
    const int pi = b * TOPK + ii;
    float u10[10], gw10[10];
#pragma unroll
    for (int nt = 0; nt < 10; ++nt) {
        const int d = nt * 16 + c;
        const float ub = (d < HIDD) ? b1[d] : 0.f;
        u10[nt] = UVP[(size_t)pi * 320 + d] + UVP[(size_t)(512 + pi) * 320 + d] + ub;
        gw10[nt] = GW[d];
    }
    auto epi = [&](const f32x4 (&acc)[10], int t) {
#pragma unroll
        for (int r = 0; r < 4; ++r) {
            const int j = 16 * t + g * 4 + r;
            const int pj = b * TOPK + j;
            const float* Vp0 = UVP + (size_t)pj * 320 + 160;
            const float* Vp1 = UVP + (size_t)(512 + pj) * 320 + 160;
            float s1 = 0.f, s2 = 0.f, s3 = 0.f;
#pragma unroll
            for (int nt = 0; nt < 10; ++nt) {
                const int d = nt * 16 + c;
                float z = acc[nt][r] + u10[nt] + Vp0[d] + Vp1[d];
                float h = (d < HIDD && z > 0.f) ? z : 0.f;
                s1 += h;
                s2 += h * h;
                s3 += h * gw10[nt];
            }
#pragma unroll
            for (int off = 1; off < 16; off <<= 1) {
                s1 += __shfl_xor(s1, off, 64);
                s2 += __shfl_xor(s2, off, 64);
                s3 += __shfl_xor(s3, off, 64);
            }
            const float mu = s1 * (1.f / HIDD);
            const float var = s2 * (1.f / HIDD) - mu * mu;
            const float rstd = rsqrtf(var + 1e-5f);
            const float val = rstd * (s3 - mu * Sgw) + C0;
            if (c == 0 && j < ii) arow[j] = val;
        }
    };
    if (has0) epi(acc0, t0);
    if (has1) epi(acc1, t1);
}

extern "C" void kernel_launch(void* const* d_in, const int* in_sizes, int n_in,
                              void* d_out, int out_size, void* d_ws, size_t ws_size,
                              hipStream_t stream) {
    const float* seq      = (const float*)d_in[0];
    const int*   starts   = (const int*)d_in[1];
    const int*   ends     = (const int*)d_in[2];
    const float* W_start  = (const float*)d_in[3];
    const float* b_start  = (const float*)d_in[4];
    const float* W_end    = (const float*)d_in[5];
    const float* b_end    = (const float*)d_in[6];
    const float* width_e  = (const float*)d_in[7];
    const float* W_out    = (const float*)d_in[8];
    const float* b_out    = (const float*)d_in[9];
    const float* w_ment   = (const float*)d_in[10];
    const float* b_ment   = (const float*)d_in[11];
    const float* W1       = (const float*)d_in[12];
    const float* b1       = (const float*)d_in[13];
    const float* ln_g     = (const float*)d_in[14];
    const float* ln_b     = (const float*)d_in[15];
    const float* W2       = (const float*)d_in[16];
    const float* b2       = (const float*)d_in[17];
    float* out = (float*)d_out;
    float* ws  = (float*)d_ws;

    float* Tt    = ws + OFF_T;
    float* biasP = ws + OFF_BIASP;
    float* WOV   = ws + OFF_WOV;
    float* av    = ws + OFF_AV;
    float* cv    = ws + OFF_CV;
    float* tw    = ws + OFF_TW;
    float* PD    = ws + OFF_PD;
    unsigned long long* CANDp = (unsigned long long*)(ws + OFF_CAND);
    int*   fsI   = (int*)(ws + OFF_FS);
    int*   feI   = (int*)(ws + OFF_FE);
    int*   widI  = (int*)(ws + OFF_WID);
    float* UVPp  = ws + OFF_UVP;
    float* GWp   = ws + OFF_GW;
    float* SCALp = ws + OFF_SCAL;
    _Float16* WFp   = (_Float16*)(ws + OFF_WF);
    _Float16* WCFp  = (_Float16*)(ws + OFF_WCF);
    _Float16* WSFp  = (_Float16*)(ws + OFF_WSF);
    _Float16* WEFp  = (_Float16*)(ws + OFF_WEF);
    _Float16* WOFp  = (_Float16*)(ws + OFF_WOF);
    _Float16* GSEHp = (_Float16*)(ws + OFF_GSEH);
    _Float16* SEHp  = (_Float16*)(ws + OFF_SEH);
    _Float16* RKHp  = (_Float16*)(ws + OFF_RKH);
    float* RKP2p = ws + OFF_RKP2;

    kA<<<1741, 256, 0, stream>>>(b_start, b_end, b_out, W_out, w_ment, W1,
                                 ln_g, ln_b, W2, b2, W_start, W_end,
                                 biasP, WOV, WFp, WCFp, WSFp, WEFp, WOFp, GWp, SCALp);
    kB<<<417, 256, 0, stream>>>(biasP, width_e, W_out, W_start, W_end, WOV, Tt, av, cv);
    k_posdots<<<2049, 256, 0, stream>>>(seq, av, cv, Tt, w_ment, b_ment, PD, tw);
    k_sort1<<<32, 256, 0, stream>>>(PD, starts, ends, tw, CANDp);
    k_sort2<<<4, 256, 0, stream>>>(CANDp, starts, ends, out, fsI, feI, widI);
    k_gath<<<256, 256, 0, stream>>>(seq, fsI, feI, GSEHp);
    k_gemm1<<<dim3(64, 6), 256, 0, stream>>>(GSEHp, WSFp, WEFp, SEHp);
    k_gemm2<<<dim3(32, 6, 2), 256, 0, stream>>>(SEHp, WOFp, RKP2p);
    k_fin<<<512, 192, 0, stream>>>(RKP2p, Tt, widI, RKHp);
    k_uv3<<<dim3(32, 2), 256, 0, stream>>>(RKHp, WCFp, UVPp);
    k_pair<<<dim3(128, 4), 256, 0, stream>>>(WFp, RKHp, UVPp, b1, GWp, SCALp,
                                             out + OFS_ANT);
}